// Round 1
// baseline (858.497 us; speedup 1.0000x reference)
//
#include <hip/hip_runtime.h>

#define D 128

// ---------------------------------------------------------------------------
// CSR build: histogram of destination ids for both edge types
// ---------------------------------------------------------------------------
__global__ void hist2(const int* __restrict__ dst_pv, const int* __restrict__ dst_vp,
                      int E, int* __restrict__ deg_q, int* __restrict__ deg_p) {
    int e = blockIdx.x * blockDim.x + threadIdx.x;
    if (e < E) {
        atomicAdd(&deg_q[dst_pv[e]], 1);
        atomicAdd(&deg_p[dst_vp[e]], 1);
    }
}

// Exclusive scan of two degree arrays (block 0 -> q, block 1 -> p).
// Single block of 256 threads, 8 elements/thread/chunk (chunk = 2048).
__global__ __launch_bounds__(256) void scan_two(const int* __restrict__ deg_q, int* __restrict__ rp_q, int nq,
                                                const int* __restrict__ deg_p, int* __restrict__ rp_p, int np) {
    const int* deg; int* rp; int n;
    if (blockIdx.x == 0) { deg = deg_q; rp = rp_q; n = nq; }
    else                 { deg = deg_p; rp = rp_p; n = np; }

    __shared__ int wsum[4];
    int tid  = threadIdx.x;
    int lane = tid & 63;
    int wid  = tid >> 6;
    int running = 0;

    for (int base = 0; base < n; base += 2048) {
        int idx0 = base + tid * 8;
        int v[8];
        int s = 0;
        #pragma unroll
        for (int j = 0; j < 8; ++j) {
            int x = (idx0 + j < n) ? deg[idx0 + j] : 0;
            v[j] = s;       // exclusive within thread
            s += x;
        }
        // wave inclusive scan of thread sums
        int inc = s;
        #pragma unroll
        for (int off = 1; off < 64; off <<= 1) {
            int t = __shfl_up(inc, off, 64);
            if (lane >= off) inc += t;
        }
        if (lane == 63) wsum[wid] = inc;
        __syncthreads();
        int wpre = 0;
        for (int w = 0; w < wid; ++w) wpre += wsum[w];
        int tot = wsum[0] + wsum[1] + wsum[2] + wsum[3];
        int tbase = running + wpre + (inc - s);   // exclusive prefix for this thread
        #pragma unroll
        for (int j = 0; j < 8; ++j)
            if (idx0 + j < n) rp[idx0 + j] = tbase + v[j];
        running += tot;
        __syncthreads();   // protect wsum before next chunk
    }
    if (tid == 0) rp[n] = running;
}

__global__ void scatter2(const int* __restrict__ src_pv, const int* __restrict__ dst_pv,
                         const int* __restrict__ src_vp, const int* __restrict__ dst_vp,
                         const int* __restrict__ rp_q, const int* __restrict__ rp_p,
                         int* __restrict__ cur_q, int* __restrict__ cur_p,
                         int* __restrict__ col_q, int* __restrict__ col_p, int E) {
    int e = blockIdx.x * blockDim.x + threadIdx.x;
    if (e < E) {
        int d = dst_pv[e];
        int p = atomicAdd(&cur_q[d], 1);
        col_q[rp_q[d] + p] = src_pv[e];
        d = dst_vp[e];
        p = atomicAdd(&cur_p[d], 1);
        col_p[rp_p[d] + p] = src_vp[e];
    }
}

// ---------------------------------------------------------------------------
// Gather-mean: one wave per destination row; lane holds float2 of the row.
// ---------------------------------------------------------------------------
__global__ __launch_bounds__(256) void agg_mean(const float* __restrict__ h,
                                                const int* __restrict__ rp,
                                                const int* __restrict__ col,
                                                float* __restrict__ agg, int n) {
    int d = blockIdx.x * 4 + (threadIdx.x >> 6);
    if (d >= n) return;
    int lane = threadIdx.x & 63;
    int beg = rp[d], end = rp[d + 1];
    float a0 = 0.f, a1 = 0.f;
    for (int i = beg; i < end; ++i) {
        int s = col[i];
        float2 v = *(const float2*)(h + (size_t)s * D + lane * 2);
        a0 += v.x; a1 += v.y;
    }
    int cnt = end - beg;
    float inv = (cnt > 0) ? 1.0f / (float)cnt : 0.f;
    float2 o; o.x = a0 * inv; o.y = a1 * inv;
    *(float2*)(agg + (size_t)d * D + lane * 2) = o;
}

// ---------------------------------------------------------------------------
// Fused dual GEMM: out = A1@W1 + A2@W2 + bias  (optionally ReLU)
// A1,A2: n x 128 row-major. W1,W2: 128 x 128 row-major. out may alias A2
// (row i of out depends only on row i of A1/A2; block barriers order
// all staging reads before epilogue writes within the owning block).
// Block: 256 threads, tile 128 rows x 128 cols, K chunked by 32.
// ---------------------------------------------------------------------------
template <bool RELU>
__global__ __launch_bounds__(256) void gemm2(const float* __restrict__ A1,
                                             const float* __restrict__ A2,
                                             const float* __restrict__ W1,
                                             const float* __restrict__ W2,
                                             const float* __restrict__ bias,
                                             float* __restrict__ out, int n) {
    __shared__ float As[32][128];  // [kk][row]
    __shared__ float Ws[32][128];  // [kk][col]

    int tid = threadIdx.x;
    int m0  = blockIdx.x * 128;
    int rg  = tid >> 5;          // 0..7  -> rows rg*16 .. rg*16+15
    int cg  = tid & 31;          // 0..31 -> cols cg*4 .. cg*4+3

    float acc[16][4];
    #pragma unroll
    for (int i = 0; i < 16; ++i)
        #pragma unroll
        for (int j = 0; j < 4; ++j) acc[i][j] = 0.f;

    int srow  = tid >> 1;          // 0..127: row this thread stages
    int scol4 = (tid & 1) * 16;    // k-offset 0 or 16 (stages 16 floats)

    for (int ks = 0; ks < 8; ++ks) {
        int k0 = ks * 32;
        const float* A = (k0 < 128) ? A1 : A2;
        const float* W = (k0 < 128) ? W1 : W2;
        int kb = k0 & 127;

        // stage A tile (transpose to [kk][row])
        int grow = m0 + srow;
        if (grow >= n) grow = n - 1;           // clamp (tail block only)
        const float* arow = A + (size_t)grow * D + kb + scol4;
        #pragma unroll
        for (int j = 0; j < 4; ++j) {
            float4 v = *(const float4*)(arow + j * 4);
            As[scol4 + j * 4 + 0][srow] = v.x;
            As[scol4 + j * 4 + 1][srow] = v.y;
            As[scol4 + j * 4 + 2][srow] = v.z;
            As[scol4 + j * 4 + 3][srow] = v.w;
        }
        // stage W tile (direct copy)
        #pragma unroll
        for (int p = 0; p < 4; ++p) {
            int f  = tid + p * 256;
            int kk = f >> 5;
            int c4 = (f & 31) << 2;
            *(float4*)&Ws[kk][c4] = *(const float4*)(W + (size_t)(kb + kk) * D + c4);
        }
        __syncthreads();

        #pragma unroll
        for (int kk = 0; kk < 32; ++kk) {
            float4 w = *(const float4*)&Ws[kk][cg << 2];
            float a[16];
            #pragma unroll
            for (int i = 0; i < 16; i += 4) {
                float4 av = *(const float4*)&As[kk][rg * 16 + i];
                a[i] = av.x; a[i + 1] = av.y; a[i + 2] = av.z; a[i + 3] = av.w;
            }
            #pragma unroll
            for (int i = 0; i < 16; ++i) {
                acc[i][0] += a[i] * w.x;
                acc[i][1] += a[i] * w.y;
                acc[i][2] += a[i] * w.z;
                acc[i][3] += a[i] * w.w;
            }
        }
        __syncthreads();
    }

    float4 bv = *(const float4*)(bias + (cg << 2));
    #pragma unroll
    for (int i = 0; i < 16; ++i) {
        int r = m0 + rg * 16 + i;
        if (r < n) {
            float4 o;
            o.x = acc[i][0] + bv.x;
            o.y = acc[i][1] + bv.y;
            o.z = acc[i][2] + bv.z;
            o.w = acc[i][3] + bv.w;
            if (RELU) {
                o.x = fmaxf(o.x, 0.f); o.y = fmaxf(o.y, 0.f);
                o.z = fmaxf(o.z, 0.f); o.w = fmaxf(o.w, 0.f);
            }
            *(float4*)(out + (size_t)r * D + (cg << 2)) = o;
        }
    }
}

// ---------------------------------------------------------------------------
extern "C" void kernel_launch(void* const* d_in, const int* in_sizes, int n_in,
                              void* d_out, int out_size, void* d_ws, size_t ws_size,
                              hipStream_t stream) {
    const float* x_p = (const float*)d_in[0];
    const float* x_q = (const float*)d_in[1];
    const int* src_pv = (const int*)d_in[2];
    const int* dst_pv = (const int*)d_in[3];
    const int* src_vp = (const int*)d_in[4];
    const int* dst_vp = (const int*)d_in[5];
    const float* Wl_pv0 = (const float*)d_in[6];
    const float* Wr_pv0 = (const float*)d_in[7];
    const float* b_pv0  = (const float*)d_in[8];
    const float* Wl_vp0 = (const float*)d_in[9];
    const float* Wr_vp0 = (const float*)d_in[10];
    const float* b_vp0  = (const float*)d_in[11];
    const float* Wl_pv1 = (const float*)d_in[12];
    const float* Wr_pv1 = (const float*)d_in[13];
    const float* b_pv1  = (const float*)d_in[14];
    const float* Wl_vp1 = (const float*)d_in[15];
    const float* Wr_vp1 = (const float*)d_in[16];
    const float* b_vp1  = (const float*)d_in[17];

    const int NP = in_sizes[0] / D;   // 100000
    const int NQ = in_sizes[1] / D;   // 50000
    const int E  = in_sizes[2];       // 600000

    float* out_p = (float*)d_out;                 // NP x 128
    float* out_q = out_p + (size_t)NP * D;        // NQ x 128

    // workspace layout
    char* ws = (char*)d_ws;
    int* rp_q  = (int*)ws;                 // NQ+1
    int* rp_p  = rp_q + (NQ + 1);          // NP+1
    int* col_q = rp_p + (NP + 1);          // E
    int* col_p = col_q + E;                // E
    int* deg_q = col_p + E;                // NQ (degree, then reused as cursor)
    int* deg_p = deg_q + NQ;               // NP
    size_t int_bytes = ((size_t)(NQ + 1) + (NP + 1) + 2 * (size_t)E + NQ + NP) * sizeof(int);
    int_bytes = (int_bytes + 511) & ~(size_t)511;
    float* agg_q = (float*)(ws + int_bytes);          // NQ x 128
    float* agg_p = agg_q + (size_t)NQ * D;            // NP x 128

    const int B = 256;
    int gridE = (E + B - 1) / B;

    // --- build CSR (shared by both layers) ---
    hipMemsetAsync(deg_q, 0, ((size_t)NQ + NP) * sizeof(int), stream);
    hist2<<<gridE, B, 0, stream>>>(dst_pv, dst_vp, E, deg_q, deg_p);
    scan_two<<<2, 256, 0, stream>>>(deg_q, rp_q, NQ, deg_p, rp_p, NP);
    hipMemsetAsync(deg_q, 0, ((size_t)NQ + NP) * sizeof(int), stream);
    scatter2<<<gridE, B, 0, stream>>>(src_pv, dst_pv, src_vp, dst_vp,
                                      rp_q, rp_p, deg_q, deg_p, col_q, col_p, E);

    int gq = (NQ + 3) / 4, gp = (NP + 3) / 4;
    int mq = (NQ + 127) / 128, mp = (NP + 127) / 128;

    // --- layer 0 ---
    agg_mean<<<gq, B, 0, stream>>>(x_p, rp_q, col_q, agg_q, NQ);
    agg_mean<<<gp, B, 0, stream>>>(x_q, rp_p, col_p, agg_p, NP);
    gemm2<true><<<mq, B, 0, stream>>>(agg_q, x_q, Wl_pv0, Wr_pv0, b_pv0, out_q, NQ);
    gemm2<true><<<mp, B, 0, stream>>>(agg_p, x_p, Wl_vp0, Wr_vp0, b_vp0, out_p, NP);

    // --- layer 1 (h1 lives in d_out; final GEMMs run in place) ---
    agg_mean<<<gq, B, 0, stream>>>(out_p, rp_q, col_q, agg_q, NQ);
    agg_mean<<<gp, B, 0, stream>>>(out_q, rp_p, col_p, agg_p, NP);
    gemm2<false><<<mq, B, 0, stream>>>(agg_q, out_q, Wl_pv1, Wr_pv1, b_pv1, out_q, NQ);
    gemm2<false><<<mp, B, 0, stream>>>(agg_p, out_p, Wl_vp1, Wr_vp1, b_vp1, out_p, NP);
}

// Round 2
// 605.241 us; speedup vs baseline: 1.4184x; 1.4184x over previous
//
#include <hip/hip_runtime.h>

#define D 128
#define PAD 40

typedef __attribute__((ext_vector_type(8))) short short8;
typedef __attribute__((ext_vector_type(4))) float f32x4;
typedef __attribute__((ext_vector_type(4))) unsigned short u16x4;

__device__ __forceinline__ unsigned short f2bf(float x) {
    union { float f; unsigned u; } v; v.f = x;
    unsigned r = v.u + 0x7fff + ((v.u >> 16) & 1);   // round-to-nearest-even
    return (unsigned short)(r >> 16);
}
__device__ __forceinline__ float bf2f(unsigned short b) {
    union { float f; unsigned u; } v; v.u = ((unsigned)b) << 16;
    return v.f;
}

// ---------------------------------------------------------------------------
// CSR build
// ---------------------------------------------------------------------------
__global__ void hist2(const int* __restrict__ dst_pv, const int* __restrict__ dst_vp,
                      int E, int* __restrict__ deg_q, int* __restrict__ deg_p) {
    int e = blockIdx.x * blockDim.x + threadIdx.x;
    if (e < E) {
        atomicAdd(&deg_q[dst_pv[e]], 1);
        atomicAdd(&deg_p[dst_vp[e]], 1);
    }
}

__global__ __launch_bounds__(256) void scan_two(const int* __restrict__ deg_q, int* __restrict__ rp_q, int nq,
                                                const int* __restrict__ deg_p, int* __restrict__ rp_p, int np) {
    const int* deg; int* rp; int n;
    if (blockIdx.x == 0) { deg = deg_q; rp = rp_q; n = nq; }
    else                 { deg = deg_p; rp = rp_p; n = np; }

    __shared__ int wsum[4];
    int tid  = threadIdx.x;
    int lane = tid & 63;
    int wid  = tid >> 6;
    int running = 0;

    for (int base = 0; base < n; base += 2048) {
        int idx0 = base + tid * 8;
        int v[8];
        int s = 0;
        #pragma unroll
        for (int j = 0; j < 8; ++j) {
            int x = (idx0 + j < n) ? deg[idx0 + j] : 0;
            v[j] = s;
            s += x;
        }
        int inc = s;
        #pragma unroll
        for (int off = 1; off < 64; off <<= 1) {
            int t = __shfl_up(inc, off, 64);
            if (lane >= off) inc += t;
        }
        if (lane == 63) wsum[wid] = inc;
        __syncthreads();
        int wpre = 0;
        for (int w = 0; w < wid; ++w) wpre += wsum[w];
        int tot = wsum[0] + wsum[1] + wsum[2] + wsum[3];
        int tbase = running + wpre + (inc - s);
        #pragma unroll
        for (int j = 0; j < 8; ++j)
            if (idx0 + j < n) rp[idx0 + j] = tbase + v[j];
        running += tot;
        __syncthreads();
    }
    if (tid == 0) rp[n] = running;
}

__global__ void scatter2(const int* __restrict__ src_pv, const int* __restrict__ dst_pv,
                         const int* __restrict__ src_vp, const int* __restrict__ dst_vp,
                         const int* __restrict__ rp_q, const int* __restrict__ rp_p,
                         int* __restrict__ cur_q, int* __restrict__ cur_p,
                         int* __restrict__ col_q, int* __restrict__ col_p, int E) {
    int e = blockIdx.x * blockDim.x + threadIdx.x;
    if (e < E) {
        int d = dst_pv[e];
        int p = atomicAdd(&cur_q[d], 1);
        col_q[rp_q[d] + p] = src_pv[e];
        d = dst_vp[e];
        p = atomicAdd(&cur_p[d], 1);
        col_p[rp_p[d] + p] = src_vp[e];
    }
}

// ---------------------------------------------------------------------------
// W prep: split f32 W[k][c] into bf16 hi/lo, transposed to [c][k]
// wt layout per matrix: hi[128*128], then lo[128*128]
// ---------------------------------------------------------------------------
__global__ __launch_bounds__(256) void wprep(const float* W0, const float* W1,
                                             const float* W2, const float* W3,
                                             const float* W4, const float* W5,
                                             const float* W6, const float* W7,
                                             unsigned short* __restrict__ wt) {
    const float* W;
    switch (blockIdx.x) {
        case 0: W = W0; break; case 1: W = W1; break;
        case 2: W = W2; break; case 3: W = W3; break;
        case 4: W = W4; break; case 5: W = W5; break;
        case 6: W = W6; break; default: W = W7; break;
    }
    unsigned short* hi = wt + (size_t)blockIdx.x * 32768;
    unsigned short* lo = hi + 16384;
    for (int i = threadIdx.x; i < 16384; i += 256) {
        int k = i >> 7, c = i & 127;
        float x = W[i];
        unsigned short h = f2bf(x);
        unsigned short l = f2bf(x - bf2f(h));
        hi[c * 128 + k] = h;
        lo[c * 128 + k] = l;
    }
}

// ---------------------------------------------------------------------------
// Gather-mean: one wave per dst row, float4 lanes, 2 neighbors per iteration
// ---------------------------------------------------------------------------
__global__ __launch_bounds__(256) void agg_mean(const float* __restrict__ h,
                                                const int* __restrict__ rp,
                                                const int* __restrict__ col,
                                                float* __restrict__ agg, int n) {
    int d = blockIdx.x * 4 + (threadIdx.x >> 6);
    if (d >= n) return;
    int lane = threadIdx.x & 63;
    int half = lane >> 5;          // which neighbor of the pair
    int q    = lane & 31;          // float4 column group
    int beg = rp[d], end = rp[d + 1];
    float4 a = make_float4(0.f, 0.f, 0.f, 0.f);
    for (int i = beg; i < end; i += 2) {
        int j = i + half;
        bool act = j < end;
        int s = col[act ? j : i];
        float4 v = *(const float4*)(h + (size_t)s * D + q * 4);
        if (act) { a.x += v.x; a.y += v.y; a.z += v.z; a.w += v.w; }
    }
    a.x += __shfl_xor(a.x, 32);
    a.y += __shfl_xor(a.y, 32);
    a.z += __shfl_xor(a.z, 32);
    a.w += __shfl_xor(a.w, 32);
    int cnt = end - beg;
    float inv = (cnt > 0) ? 1.0f / (float)cnt : 0.f;
    if (half == 0) {
        float4 o = make_float4(a.x * inv, a.y * inv, a.z * inv, a.w * inv);
        *(float4*)(agg + (size_t)d * D + q * 4) = o;
    }
}

// ---------------------------------------------------------------------------
// MFMA dual GEMM with bf16x3 split:
//   out = A1@W1 + A2@W2 + bias (+ReLU), A: n x 128 f32, Wt*: pre-split bf16
//   [col][k] hi at +0, lo at +16384. out may alias A2 (disjoint row tiles).
// Block: 256 thr (4 waves), tile 128 rows x 128 cols, K chunked by 32.
// ---------------------------------------------------------------------------
template <bool RELU>
__global__ __launch_bounds__(256) void gemm2_mfma(
    const float* __restrict__ A1, const float* __restrict__ A2,
    const unsigned short* __restrict__ Wt1, const unsigned short* __restrict__ Wt2,
    const float* __restrict__ bias, float* __restrict__ out, int n)
{
    __shared__ unsigned short As_hi[128][PAD];
    __shared__ unsigned short As_lo[128][PAD];
    __shared__ unsigned short Ws_hi[128][PAD];
    __shared__ unsigned short Ws_lo[128][PAD];

    const int tid  = threadIdx.x;
    const int lane = tid & 63;
    const int w    = tid >> 6;
    const int m0   = blockIdx.x * 128;

    f32x4 acc[2][8];
    #pragma unroll
    for (int i = 0; i < 2; ++i)
        #pragma unroll
        for (int j = 0; j < 8; ++j) acc[i][j] = (f32x4)0.f;

    const int srow  = tid >> 1;          // 0..127
    const int skoff = (tid & 1) * 16;    // 0 or 16

    for (int ks = 0; ks < 8; ++ks) {
        const int half = ks >> 2;
        const int kb   = (ks & 3) * 32;
        const float* A = half ? A2 : A1;
        const unsigned short* Wt = half ? Wt2 : Wt1;

        // stage A (f32 -> split bf16 hi/lo)
        {
            int grow = m0 + srow;
            if (grow >= n) grow = n - 1;
            const float* ap = A + (size_t)grow * D + kb + skoff;
            #pragma unroll
            for (int j = 0; j < 4; ++j) {
                float4 v = *(const float4*)(ap + j * 4);
                u16x4 hh, ll;
                hh.x = f2bf(v.x); ll.x = f2bf(v.x - bf2f(hh.x));
                hh.y = f2bf(v.y); ll.y = f2bf(v.y - bf2f(hh.y));
                hh.z = f2bf(v.z); ll.z = f2bf(v.z - bf2f(hh.z));
                hh.w = f2bf(v.w); ll.w = f2bf(v.w - bf2f(hh.w));
                *(u16x4*)&As_hi[srow][skoff + j * 4] = hh;
                *(u16x4*)&As_lo[srow][skoff + j * 4] = ll;
            }
        }
        // stage W (pre-split bf16, [col][k] layout, straight copy)
        {
            const uint4* ph = (const uint4*)(Wt + (size_t)srow * D + kb + skoff);
            ((uint4*)&Ws_hi[srow][skoff])[0] = ph[0];
            ((uint4*)&Ws_hi[srow][skoff])[1] = ph[1];
            const uint4* pl = (const uint4*)(Wt + 16384 + (size_t)srow * D + kb + skoff);
            ((uint4*)&Ws_lo[srow][skoff])[0] = pl[0];
            ((uint4*)&Ws_lo[srow][skoff])[1] = pl[1];
        }
        __syncthreads();

        const int r0 = w * 32;
        const int k8 = (lane >> 4) * 8;
        const int li = lane & 15;

        short8 ah[2], al[2];
        #pragma unroll
        for (int m = 0; m < 2; ++m) {
            int rr = r0 + m * 16 + li;
            ah[m] = *(const short8*)&As_hi[rr][k8];
            al[m] = *(const short8*)&As_lo[rr][k8];
        }
        #pragma unroll
        for (int nb = 0; nb < 8; ++nb) {
            int cc = nb * 16 + li;
            short8 bh = *(const short8*)&Ws_hi[cc][k8];
            short8 bl = *(const short8*)&Ws_lo[cc][k8];
            #pragma unroll
            for (int m = 0; m < 2; ++m) {
                acc[m][nb] = __builtin_amdgcn_mfma_f32_16x16x32_bf16(ah[m], bh, acc[m][nb], 0, 0, 0);
                acc[m][nb] = __builtin_amdgcn_mfma_f32_16x16x32_bf16(al[m], bh, acc[m][nb], 0, 0, 0);
                acc[m][nb] = __builtin_amdgcn_mfma_f32_16x16x32_bf16(ah[m], bl, acc[m][nb], 0, 0, 0);
            }
        }
        __syncthreads();
    }

    // epilogue: C/D layout col=lane&15, row=(lane>>4)*4+reg
    const int li = lane & 15;
    const int rq = (lane >> 4) * 4;
    float bv[8];
    #pragma unroll
    for (int nb = 0; nb < 8; ++nb) bv[nb] = bias[nb * 16 + li];

    #pragma unroll
    for (int m = 0; m < 2; ++m) {
        #pragma unroll
        for (int nb = 0; nb < 8; ++nb) {
            #pragma unroll
            for (int r = 0; r < 4; ++r) {
                int R = m0 + w * 32 + m * 16 + rq + r;
                if (R < n) {
                    int C = nb * 16 + li;
                    float v = acc[m][nb][r] + bv[nb];
                    if (RELU) v = fmaxf(v, 0.f);
                    out[(size_t)R * D + C] = v;
                }
            }
        }
    }
}

// ---------------------------------------------------------------------------
extern "C" void kernel_launch(void* const* d_in, const int* in_sizes, int n_in,
                              void* d_out, int out_size, void* d_ws, size_t ws_size,
                              hipStream_t stream) {
    const float* x_p = (const float*)d_in[0];
    const float* x_q = (const float*)d_in[1];
    const int* src_pv = (const int*)d_in[2];
    const int* dst_pv = (const int*)d_in[3];
    const int* src_vp = (const int*)d_in[4];
    const int* dst_vp = (const int*)d_in[5];
    const float* Wl_pv0 = (const float*)d_in[6];
    const float* Wr_pv0 = (const float*)d_in[7];
    const float* b_pv0  = (const float*)d_in[8];
    const float* Wl_vp0 = (const float*)d_in[9];
    const float* Wr_vp0 = (const float*)d_in[10];
    const float* b_vp0  = (const float*)d_in[11];
    const float* Wl_pv1 = (const float*)d_in[12];
    const float* Wr_pv1 = (const float*)d_in[13];
    const float* b_pv1  = (const float*)d_in[14];
    const float* Wl_vp1 = (const float*)d_in[15];
    const float* Wr_vp1 = (const float*)d_in[16];
    const float* b_vp1  = (const float*)d_in[17];

    const int NP = in_sizes[0] / D;
    const int NQ = in_sizes[1] / D;
    const int E  = in_sizes[2];

    float* out_p = (float*)d_out;
    float* out_q = out_p + (size_t)NP * D;

    // workspace layout
    char* ws = (char*)d_ws;
    int* rp_q  = (int*)ws;
    int* rp_p  = rp_q + (NQ + 1);
    int* col_q = rp_p + (NP + 1);
    int* col_p = col_q + E;
    int* deg_q = col_p + E;
    int* deg_p = deg_q + NQ;
    size_t int_bytes = ((size_t)(NQ + 1) + (NP + 1) + 2 * (size_t)E + NQ + NP) * sizeof(int);
    int_bytes = (int_bytes + 511) & ~(size_t)511;
    unsigned short* wt = (unsigned short*)(ws + int_bytes);   // 8 * 32768 u16 = 512KB
    size_t wt_bytes = ((size_t)8 * 32768 * sizeof(unsigned short) + 511) & ~(size_t)511;
    float* agg_q = (float*)(ws + int_bytes + wt_bytes);
    float* agg_p = agg_q + (size_t)NQ * D;

    const int B = 256;
    int gridE = (E + B - 1) / B;

    // --- CSR build ---
    hipMemsetAsync(deg_q, 0, ((size_t)NQ + NP) * sizeof(int), stream);
    hist2<<<gridE, B, 0, stream>>>(dst_pv, dst_vp, E, deg_q, deg_p);
    scan_two<<<2, 256, 0, stream>>>(deg_q, rp_q, NQ, deg_p, rp_p, NP);
    hipMemsetAsync(deg_q, 0, ((size_t)NQ + NP) * sizeof(int), stream);
    scatter2<<<gridE, B, 0, stream>>>(src_pv, dst_pv, src_vp, dst_vp,
                                      rp_q, rp_p, deg_q, deg_p, col_q, col_p, E);

    // --- W split/transpose (once, reused by all GEMMs) ---
    wprep<<<8, 256, 0, stream>>>(Wl_pv0, Wr_pv0, Wl_vp0, Wr_vp0,
                                 Wl_pv1, Wr_pv1, Wl_vp1, Wr_vp1, wt);

    int gq = (NQ + 3) / 4, gp = (NP + 3) / 4;
    int mq = (NQ + 127) / 128, mp = (NP + 127) / 128;

    // --- layer 0 ---
    agg_mean<<<gq, B, 0, stream>>>(x_p, rp_q, col_q, agg_q, NQ);
    agg_mean<<<gp, B, 0, stream>>>(x_q, rp_p, col_p, agg_p, NP);
    gemm2_mfma<true><<<mq, B, 0, stream>>>(agg_q, x_q, wt + 0 * 32768, wt + 1 * 32768, b_pv0, out_q, NQ);
    gemm2_mfma<true><<<mp, B, 0, stream>>>(agg_p, x_p, wt + 2 * 32768, wt + 3 * 32768, b_vp0, out_p, NP);

    // --- layer 1 (h1 in d_out; GEMMs in place over disjoint row tiles) ---
    agg_mean<<<gq, B, 0, stream>>>(out_p, rp_q, col_q, agg_q, NQ);
    agg_mean<<<gp, B, 0, stream>>>(out_q, rp_p, col_p, agg_p, NP);
    gemm2_mfma<false><<<mq, B, 0, stream>>>(agg_q, out_q, wt + 4 * 32768, wt + 5 * 32768, b_pv1, out_q, NQ);
    gemm2_mfma<false><<<mp, B, 0, stream>>>(agg_p, out_p, wt + 6 * 32768, wt + 7 * 32768, b_vp1, out_p, NP);
}

// Round 3
// 504.852 us; speedup vs baseline: 1.7005x; 1.1988x over previous
//
#include <hip/hip_runtime.h>

#define D 128
#define PAD 40
#define CHUNK 2048   // 256 threads * 8 elems

typedef __attribute__((ext_vector_type(8))) short short8;
typedef __attribute__((ext_vector_type(4))) float f32x4;
typedef __attribute__((ext_vector_type(4))) unsigned short u16x4;

__device__ __forceinline__ unsigned short f2bf(float x) {
    union { float f; unsigned u; } v; v.f = x;
    unsigned r = v.u + 0x7fff + ((v.u >> 16) & 1);   // round-to-nearest-even
    return (unsigned short)(r >> 16);
}
__device__ __forceinline__ float bf2f(unsigned short b) {
    union { float f; unsigned u; } v; v.u = ((unsigned)b) << 16;
    return v.f;
}

// ---------------------------------------------------------------------------
// CSR build
// ---------------------------------------------------------------------------
__global__ void hist2(const int* __restrict__ dst_pv, const int* __restrict__ dst_vp,
                      int E, int* __restrict__ deg_q, int* __restrict__ deg_p) {
    int e = blockIdx.x * blockDim.x + threadIdx.x;
    if (e < E) {
        atomicAdd(&deg_q[dst_pv[e]], 1);
        atomicAdd(&deg_p[dst_vp[e]], 1);
    }
}

// Phase 1: per-chunk totals. Blocks [0,nbq) cover deg_q, [nbq,nbq+nbp) cover deg_p.
__global__ __launch_bounds__(256) void scan_p1(const int* __restrict__ deg_q, int nq,
                                               const int* __restrict__ deg_p, int np,
                                               int nbq, int* __restrict__ part) {
    int b = blockIdx.x;
    const int* deg; int n; int base;
    if (b < nbq) { deg = deg_q; n = nq; base = b * CHUNK; }
    else         { deg = deg_p; n = np; base = (b - nbq) * CHUNK; }

    __shared__ int wsum[4];
    int tid = threadIdx.x, lane = tid & 63, wid = tid >> 6;
    int idx0 = base + tid * 8;
    int s = 0;
    #pragma unroll
    for (int j = 0; j < 8; ++j) s += (idx0 + j < n) ? deg[idx0 + j] : 0;
    #pragma unroll
    for (int off = 32; off > 0; off >>= 1) s += __shfl_down(s, off, 64);
    if (lane == 0) wsum[wid] = s;
    __syncthreads();
    if (tid == 0) part[b] = wsum[0] + wsum[1] + wsum[2] + wsum[3];
}

// Phase 2: exclusive-scan the partials in place; wave 0 -> q segment, wave 1 -> p.
__global__ __launch_bounds__(128) void scan_p2(int* __restrict__ part, int nbq, int nbp,
                                               int* __restrict__ rp_q, int nq,
                                               int* __restrict__ rp_p, int np) {
    int wid = threadIdx.x >> 6, lane = threadIdx.x & 63;
    int* seg; int nseg; int* tot;
    if (wid == 0) { seg = part;       nseg = nbq; tot = rp_q + nq; }
    else          { seg = part + nbq; nseg = nbp; tot = rp_p + np; }
    int carry = 0;
    for (int base = 0; base < nseg; base += 64) {
        int i = base + lane;
        int v = (i < nseg) ? seg[i] : 0;
        int inc = v;
        #pragma unroll
        for (int off = 1; off < 64; off <<= 1) {
            int t = __shfl_up(inc, off, 64);
            if (lane >= off) inc += t;
        }
        if (i < nseg) seg[i] = carry + inc - v;
        carry += __shfl(inc, 63, 64);
    }
    if (lane == 0) *tot = carry;
}

// Phase 3: per-chunk exclusive scan + block base -> rp.
__global__ __launch_bounds__(256) void scan_p3(const int* __restrict__ deg_q, int* __restrict__ rp_q, int nq,
                                               const int* __restrict__ deg_p, int* __restrict__ rp_p, int np,
                                               int nbq, const int* __restrict__ part) {
    int b = blockIdx.x;
    const int* deg; int* rp; int n; int base;
    if (b < nbq) { deg = deg_q; rp = rp_q; n = nq; base = b * CHUNK; }
    else         { deg = deg_p; rp = rp_p; n = np; base = (b - nbq) * CHUNK; }

    __shared__ int wsum[4];
    int tid = threadIdx.x, lane = tid & 63, wid = tid >> 6;
    int idx0 = base + tid * 8;
    int v[8]; int s = 0;
    #pragma unroll
    for (int j = 0; j < 8; ++j) {
        int x = (idx0 + j < n) ? deg[idx0 + j] : 0;
        v[j] = s; s += x;
    }
    int inc = s;
    #pragma unroll
    for (int off = 1; off < 64; off <<= 1) {
        int t = __shfl_up(inc, off, 64);
        if (lane >= off) inc += t;
    }
    if (lane == 63) wsum[wid] = inc;
    __syncthreads();
    int wpre = 0;
    for (int w2 = 0; w2 < wid; ++w2) wpre += wsum[w2];
    int tbase = part[b] + wpre + (inc - s);
    #pragma unroll
    for (int j = 0; j < 8; ++j)
        if (idx0 + j < n) rp[idx0 + j] = tbase + v[j];
}

// Scatter: deg arrays (still holding counts) serve as countdown cursors.
__global__ void scatter2(const int* __restrict__ src_pv, const int* __restrict__ dst_pv,
                         const int* __restrict__ src_vp, const int* __restrict__ dst_vp,
                         const int* __restrict__ rp_q, const int* __restrict__ rp_p,
                         int* __restrict__ cur_q, int* __restrict__ cur_p,
                         int* __restrict__ col_q, int* __restrict__ col_p, int E) {
    int e = blockIdx.x * blockDim.x + threadIdx.x;
    if (e < E) {
        int d = dst_pv[e];
        int p = atomicSub(&cur_q[d], 1) - 1;
        col_q[rp_q[d] + p] = src_pv[e];
        d = dst_vp[e];
        p = atomicSub(&cur_p[d], 1) - 1;
        col_p[rp_p[d] + p] = src_vp[e];
    }
}

// ---------------------------------------------------------------------------
// W prep: split f32 W[k][c] into bf16 hi/lo, transposed to [c][k]
// ---------------------------------------------------------------------------
__global__ __launch_bounds__(256) void wprep(const float* W0, const float* W1,
                                             const float* W2, const float* W3,
                                             const float* W4, const float* W5,
                                             const float* W6, const float* W7,
                                             unsigned short* __restrict__ wt) {
    const float* W;
    switch (blockIdx.x) {
        case 0: W = W0; break; case 1: W = W1; break;
        case 2: W = W2; break; case 3: W = W3; break;
        case 4: W = W4; break; case 5: W = W5; break;
        case 6: W = W6; break; default: W = W7; break;
    }
    unsigned short* hi = wt + (size_t)blockIdx.x * 32768;
    unsigned short* lo = hi + 16384;
    for (int i = threadIdx.x; i < 16384; i += 256) {
        int k = i >> 7, c = i & 127;
        float x = W[i];
        unsigned short h = f2bf(x);
        unsigned short l = f2bf(x - bf2f(h));
        hi[c * 128 + k] = h;
        lo[c * 128 + k] = l;
    }
}

// ---------------------------------------------------------------------------
// Gather-mean: one wave per dst row, float4 lanes, 2 neighbors per iteration
// ---------------------------------------------------------------------------
__global__ __launch_bounds__(256) void agg_mean(const float* __restrict__ h,
                                                const int* __restrict__ rp,
                                                const int* __restrict__ col,
                                                float* __restrict__ agg, int n) {
    int d = blockIdx.x * 4 + (threadIdx.x >> 6);
    if (d >= n) return;
    int lane = threadIdx.x & 63;
    int half = lane >> 5;
    int q    = lane & 31;
    int beg = rp[d], end = rp[d + 1];
    float4 a = make_float4(0.f, 0.f, 0.f, 0.f);
    for (int i = beg; i < end; i += 2) {
        int j = i + half;
        bool act = j < end;
        int s = col[act ? j : i];
        float4 v = *(const float4*)(h + (size_t)s * D + q * 4);
        if (act) { a.x += v.x; a.y += v.y; a.z += v.z; a.w += v.w; }
    }
    a.x += __shfl_xor(a.x, 32);
    a.y += __shfl_xor(a.y, 32);
    a.z += __shfl_xor(a.z, 32);
    a.w += __shfl_xor(a.w, 32);
    int cnt = end - beg;
    float inv = (cnt > 0) ? 1.0f / (float)cnt : 0.f;
    if (half == 0) {
        float4 o = make_float4(a.x * inv, a.y * inv, a.z * inv, a.w * inv);
        *(float4*)(agg + (size_t)d * D + q * 4) = o;
    }
}

// ---------------------------------------------------------------------------
// MFMA dual GEMM with bf16x3 split (unchanged from R1, verified)
// ---------------------------------------------------------------------------
template <bool RELU>
__global__ __launch_bounds__(256) void gemm2_mfma(
    const float* __restrict__ A1, const float* __restrict__ A2,
    const unsigned short* __restrict__ Wt1, const unsigned short* __restrict__ Wt2,
    const float* __restrict__ bias, float* __restrict__ out, int n)
{
    __shared__ unsigned short As_hi[128][PAD];
    __shared__ unsigned short As_lo[128][PAD];
    __shared__ unsigned short Ws_hi[128][PAD];
    __shared__ unsigned short Ws_lo[128][PAD];

    const int tid  = threadIdx.x;
    const int lane = tid & 63;
    const int w    = tid >> 6;
    const int m0   = blockIdx.x * 128;

    f32x4 acc[2][8];
    #pragma unroll
    for (int i = 0; i < 2; ++i)
        #pragma unroll
        for (int j = 0; j < 8; ++j) acc[i][j] = (f32x4)0.f;

    const int srow  = tid >> 1;
    const int skoff = (tid & 1) * 16;

    for (int ks = 0; ks < 8; ++ks) {
        const int half = ks >> 2;
        const int kb   = (ks & 3) * 32;
        const float* A = half ? A2 : A1;
        const unsigned short* Wt = half ? Wt2 : Wt1;

        {
            int grow = m0 + srow;
            if (grow >= n) grow = n - 1;
            const float* ap = A + (size_t)grow * D + kb + skoff;
            #pragma unroll
            for (int j = 0; j < 4; ++j) {
                float4 v = *(const float4*)(ap + j * 4);
                u16x4 hh, ll;
                hh.x = f2bf(v.x); ll.x = f2bf(v.x - bf2f(hh.x));
                hh.y = f2bf(v.y); ll.y = f2bf(v.y - bf2f(hh.y));
                hh.z = f2bf(v.z); ll.z = f2bf(v.z - bf2f(hh.z));
                hh.w = f2bf(v.w); ll.w = f2bf(v.w - bf2f(hh.w));
                *(u16x4*)&As_hi[srow][skoff + j * 4] = hh;
                *(u16x4*)&As_lo[srow][skoff + j * 4] = ll;
            }
        }
        {
            const uint4* ph = (const uint4*)(Wt + (size_t)srow * D + kb + skoff);
            ((uint4*)&Ws_hi[srow][skoff])[0] = ph[0];
            ((uint4*)&Ws_hi[srow][skoff])[1] = ph[1];
            const uint4* pl = (const uint4*)(Wt + 16384 + (size_t)srow * D + kb + skoff);
            ((uint4*)&Ws_lo[srow][skoff])[0] = pl[0];
            ((uint4*)&Ws_lo[srow][skoff])[1] = pl[1];
        }
        __syncthreads();

        const int r0 = w * 32;
        const int k8 = (lane >> 4) * 8;
        const int li = lane & 15;

        short8 ah[2], al[2];
        #pragma unroll
        for (int m = 0; m < 2; ++m) {
            int rr = r0 + m * 16 + li;
            ah[m] = *(const short8*)&As_hi[rr][k8];
            al[m] = *(const short8*)&As_lo[rr][k8];
        }
        #pragma unroll
        for (int nb = 0; nb < 8; ++nb) {
            int cc = nb * 16 + li;
            short8 bh = *(const short8*)&Ws_hi[cc][k8];
            short8 bl = *(const short8*)&Ws_lo[cc][k8];
            #pragma unroll
            for (int m = 0; m < 2; ++m) {
                acc[m][nb] = __builtin_amdgcn_mfma_f32_16x16x32_bf16(ah[m], bh, acc[m][nb], 0, 0, 0);
                acc[m][nb] = __builtin_amdgcn_mfma_f32_16x16x32_bf16(al[m], bh, acc[m][nb], 0, 0, 0);
                acc[m][nb] = __builtin_amdgcn_mfma_f32_16x16x32_bf16(ah[m], bl, acc[m][nb], 0, 0, 0);
            }
        }
        __syncthreads();
    }

    const int li = lane & 15;
    const int rq = (lane >> 4) * 4;
    float bv[8];
    #pragma unroll
    for (int nb = 0; nb < 8; ++nb) bv[nb] = bias[nb * 16 + li];

    #pragma unroll
    for (int m = 0; m < 2; ++m) {
        #pragma unroll
        for (int nb = 0; nb < 8; ++nb) {
            #pragma unroll
            for (int r = 0; r < 4; ++r) {
                int R = m0 + w * 32 + m * 16 + rq + r;
                if (R < n) {
                    int C = nb * 16 + li;
                    float v = acc[m][nb][r] + bv[nb];
                    if (RELU) v = fmaxf(v, 0.f);
                    out[(size_t)R * D + C] = v;
                }
            }
        }
    }
}

// ---------------------------------------------------------------------------
extern "C" void kernel_launch(void* const* d_in, const int* in_sizes, int n_in,
                              void* d_out, int out_size, void* d_ws, size_t ws_size,
                              hipStream_t stream) {
    const float* x_p = (const float*)d_in[0];
    const float* x_q = (const float*)d_in[1];
    const int* src_pv = (const int*)d_in[2];
    const int* dst_pv = (const int*)d_in[3];
    const int* src_vp = (const int*)d_in[4];
    const int* dst_vp = (const int*)d_in[5];
    const float* Wl_pv0 = (const float*)d_in[6];
    const float* Wr_pv0 = (const float*)d_in[7];
    const float* b_pv0  = (const float*)d_in[8];
    const float* Wl_vp0 = (const float*)d_in[9];
    const float* Wr_vp0 = (const float*)d_in[10];
    const float* b_vp0  = (const float*)d_in[11];
    const float* Wl_pv1 = (const float*)d_in[12];
    const float* Wr_pv1 = (const float*)d_in[13];
    const float* b_pv1  = (const float*)d_in[14];
    const float* Wl_vp1 = (const float*)d_in[15];
    const float* Wr_vp1 = (const float*)d_in[16];
    const float* b_vp1  = (const float*)d_in[17];

    const int NP = in_sizes[0] / D;
    const int NQ = in_sizes[1] / D;
    const int E  = in_sizes[2];

    float* out_p = (float*)d_out;
    float* out_q = out_p + (size_t)NP * D;

    // workspace layout
    char* ws = (char*)d_ws;
    int* rp_q  = (int*)ws;                   // NQ+1
    int* rp_p  = rp_q + (NQ + 1);            // NP+1
    int* col_q = rp_p + (NP + 1);            // E
    int* col_p = col_q + E;                  // E
    int* deg_q = col_p + E;                  // NQ
    int* deg_p = deg_q + NQ;                 // NP
    int* part  = deg_p + NP;                 // scan partials (<=128)
    size_t int_bytes = ((size_t)(NQ + 1) + (NP + 1) + 2 * (size_t)E + NQ + NP + 128) * sizeof(int);
    int_bytes = (int_bytes + 511) & ~(size_t)511;
    unsigned short* wt = (unsigned short*)(ws + int_bytes);
    size_t wt_bytes = ((size_t)8 * 32768 * sizeof(unsigned short) + 511) & ~(size_t)511;
    float* agg_q = (float*)(ws + int_bytes + wt_bytes);
    float* agg_p = agg_q + (size_t)NQ * D;

    const int B = 256;
    int gridE = (E + B - 1) / B;
    int nbq = (NQ + CHUNK - 1) / CHUNK;      // 25
    int nbp = (NP + CHUNK - 1) / CHUNK;      // 49

    // --- CSR build ---
    hipMemsetAsync(deg_q, 0, ((size_t)NQ + NP) * sizeof(int), stream);
    hist2<<<gridE, B, 0, stream>>>(dst_pv, dst_vp, E, deg_q, deg_p);
    scan_p1<<<nbq + nbp, 256, 0, stream>>>(deg_q, NQ, deg_p, NP, nbq, part);
    scan_p2<<<1, 128, 0, stream>>>(part, nbq, nbp, rp_q, NQ, rp_p, NP);
    scan_p3<<<nbq + nbp, 256, 0, stream>>>(deg_q, rp_q, NQ, deg_p, rp_p, NP, nbq, part);
    scatter2<<<gridE, B, 0, stream>>>(src_pv, dst_pv, src_vp, dst_vp,
                                      rp_q, rp_p, deg_q, deg_p, col_q, col_p, E);

    // --- W split/transpose ---
    wprep<<<8, 256, 0, stream>>>(Wl_pv0, Wr_pv0, Wl_vp0, Wr_vp0,
                                 Wl_pv1, Wr_pv1, Wl_vp1, Wr_vp1, wt);

    int gq = (NQ + 3) / 4, gp = (NP + 3) / 4;
    int mq = (NQ + 127) / 128, mp = (NP + 127) / 128;

    // --- layer 0 ---
    agg_mean<<<gq, B, 0, stream>>>(x_p, rp_q, col_q, agg_q, NQ);
    agg_mean<<<gp, B, 0, stream>>>(x_q, rp_p, col_p, agg_p, NP);
    gemm2_mfma<true><<<mq, B, 0, stream>>>(agg_q, x_q, wt + 0 * 32768, wt + 1 * 32768, b_pv0, out_q, NQ);
    gemm2_mfma<true><<<mp, B, 0, stream>>>(agg_p, x_p, wt + 2 * 32768, wt + 3 * 32768, b_vp0, out_p, NP);

    // --- layer 1 ---
    agg_mean<<<gq, B, 0, stream>>>(out_p, rp_q, col_q, agg_q, NQ);
    agg_mean<<<gp, B, 0, stream>>>(out_q, rp_p, col_p, agg_p, NP);
    gemm2_mfma<false><<<mq, B, 0, stream>>>(agg_q, out_q, wt + 4 * 32768, wt + 5 * 32768, b_pv1, out_q, NQ);
    gemm2_mfma<false><<<mp, B, 0, stream>>>(agg_p, out_p, wt + 6 * 32768, wt + 7 * 32768, b_vp1, out_p, NP);
}

// Round 4
// 453.327 us; speedup vs baseline: 1.8938x; 1.1137x over previous
//
#include <hip/hip_runtime.h>

#define D 128
#define PAD 40
#define NBMAX 1024   // max buckets per node type
#define BCAP 2048    // max edges per bucket handled in LDS fast path

typedef __attribute__((ext_vector_type(8))) short short8;
typedef __attribute__((ext_vector_type(4))) float f32x4;
typedef __attribute__((ext_vector_type(4))) unsigned short u16x4;

__device__ __forceinline__ unsigned short f2bf(float x) {
    union { float f; unsigned u; } v; v.f = x;
    unsigned r = v.u + 0x7fff + ((v.u >> 16) & 1);
    return (unsigned short)(r >> 16);
}
__device__ __forceinline__ float bf2f(unsigned short b) {
    union { float f; unsigned u; } v; v.u = ((unsigned)b) << 16;
    return v.f;
}

// ---------------------------------------------------------------------------
// Bucketed CSR build.
// ---------------------------------------------------------------------------
// Pass A: per-bucket histograms (LDS-staged)
__global__ __launch_bounds__(256) void bhist(const int* __restrict__ dst_pv,
                                             const int* __restrict__ dst_vp, int E,
                                             int shq, int shp,
                                             int* __restrict__ bq, int* __restrict__ bp) {
    __shared__ int hq[NBMAX], hp[NBMAX];
    int tid = threadIdx.x;
    for (int i = tid; i < NBMAX; i += 256) { hq[i] = 0; hp[i] = 0; }
    __syncthreads();
    for (int e = blockIdx.x * 256 + tid; e < E; e += gridDim.x * 256) {
        atomicAdd(&hq[dst_pv[e] >> shq], 1);
        atomicAdd(&hp[dst_vp[e] >> shp], 1);
    }
    __syncthreads();
    for (int i = tid; i < NBMAX; i += 256) {
        if (hq[i]) atomicAdd(&bq[i], hq[i]);
        if (hp[i]) atomicAdd(&bp[i], hp[i]);
    }
}

// Pass B0: exclusive-scan bucket counts in place (wave0=q, wave1=p); copy to cursors;
// write rp tails.
__global__ __launch_bounds__(128) void bscan(int* __restrict__ bq, int nbq,
                                             int* __restrict__ bp, int nbp,
                                             int* __restrict__ curq, int* __restrict__ curp,
                                             int* __restrict__ rp_q, int nq,
                                             int* __restrict__ rp_p, int np, int E) {
    int wid = threadIdx.x >> 6, lane = threadIdx.x & 63;
    int* seg = wid ? bp : bq;
    int* cur = wid ? curp : curq;
    int nseg = wid ? nbp : nbq;
    int carry = 0;
    for (int base = 0; base < nseg; base += 64) {
        int i = base + lane;
        int v = (i < nseg) ? seg[i] : 0;
        int inc = v;
        #pragma unroll
        for (int off = 1; off < 64; off <<= 1) {
            int t = __shfl_up(inc, off, 64);
            if (lane >= off) inc += t;
        }
        if (i < nseg) { int ex = carry + inc - v; seg[i] = ex; cur[i] = ex; }
        carry += __shfl(inc, 63, 64);
    }
    if (lane == 0) { if (wid == 0) rp_q[nq] = E; else rp_p[np] = E; }
}

// Pass B: block-batched scatter of (src,dst) pairs into bucket-ordered arrays.
__global__ __launch_bounds__(256) void bscatter(const int* __restrict__ src_pv,
                                                const int* __restrict__ dst_pv,
                                                const int* __restrict__ src_vp,
                                                const int* __restrict__ dst_vp, int E,
                                                int* __restrict__ curq, int shq,
                                                int* __restrict__ curp, int shp,
                                                int2* __restrict__ pairs_q,
                                                int2* __restrict__ pairs_p, int nblk) {
    __shared__ int cq[NBMAX], baq[NBMAX], wq[NBMAX];
    __shared__ int cp_[NBMAX], bap[NBMAX], wp_[NBMAX];
    int tid = threadIdx.x;
    int chunk = (E + nblk - 1) / nblk;
    int lo = blockIdx.x * chunk;
    int hi = min(lo + chunk, E);
    for (int i = tid; i < NBMAX; i += 256) { cq[i] = 0; cp_[i] = 0; }
    __syncthreads();
    for (int e = lo + tid; e < hi; e += 256) {
        atomicAdd(&cq[dst_pv[e] >> shq], 1);
        atomicAdd(&cp_[dst_vp[e] >> shp], 1);
    }
    __syncthreads();
    for (int i = tid; i < NBMAX; i += 256) {
        baq[i] = cq[i]  ? atomicAdd(&curq[i], cq[i])  : 0; wq[i]  = 0;
        bap[i] = cp_[i] ? atomicAdd(&curp[i], cp_[i]) : 0; wp_[i] = 0;
    }
    __syncthreads();
    for (int e = lo + tid; e < hi; e += 256) {
        int d = dst_pv[e]; int b = d >> shq;
        int off = atomicAdd(&wq[b], 1);
        pairs_q[baq[b] + off] = make_int2(src_pv[e], d);
        d = dst_vp[e]; b = d >> shp;
        off = atomicAdd(&wp_[b], 1);
        pairs_p[bap[b] + off] = make_int2(src_vp[e], d);
    }
}

// Pass C: per-bucket local CSR: degrees, local scan, LDS scatter, coalesced writeout.
__global__ __launch_bounds__(256) void bcsr(const int2* __restrict__ pairs_q,
                                            const int2* __restrict__ pairs_p,
                                            const int* __restrict__ bbq, int nbq,
                                            const int* __restrict__ bbp, int nbp,
                                            int* __restrict__ rp_q, int nq, int shq,
                                            int* __restrict__ rp_p, int np, int shp,
                                            int* __restrict__ col_q, int* __restrict__ col_p,
                                            int E) {
    int b = blockIdx.x;
    const int2* pairs; const int* bb; int* rp; int* colg; int nb, n, sh;
    if (b < nbq) { pairs = pairs_q; bb = bbq; rp = rp_q; colg = col_q; nb = nbq; n = nq; sh = shq; }
    else { b -= nbq; pairs = pairs_p; bb = bbp; rp = rp_p; colg = col_p; nb = nbp; n = np; sh = shp; }
    int base = bb[b];
    int next = (b + 1 < nb) ? bb[b + 1] : E;
    int cnt = next - base;
    int dlo = b << sh;
    int dn  = min(1 << sh, n - dlo);   // <= 128 for our shifts

    __shared__ int2 pc[BCAP];
    __shared__ int cols[BCAP];
    __shared__ int deg[128];
    __shared__ int cur[128];
    int tid = threadIdx.x;
    for (int i = tid; i < dn; i += 256) deg[i] = 0;
    __syncthreads();

    if (cnt <= BCAP) {
        for (int i = tid; i < cnt; i += 256) {
            int2 e = pairs[base + i];
            pc[i] = e;
            atomicAdd(&deg[e.y - dlo], 1);
        }
        __syncthreads();
        if (tid == 0) { int s = 0; for (int i = 0; i < dn; ++i) { int t = deg[i]; deg[i] = s; s += t; } }
        __syncthreads();
        for (int i = tid; i < dn; i += 256) { rp[dlo + i] = base + deg[i]; cur[i] = deg[i]; }
        __syncthreads();
        for (int i = tid; i < cnt; i += 256) {
            int2 e = pc[i];
            int off = atomicAdd(&cur[e.y - dlo], 1);
            cols[off] = e.x;
        }
        __syncthreads();
        for (int i = tid; i < cnt; i += 256) colg[base + i] = cols[i];
    } else {
        // fallback (statistically never): two-pass over global pairs
        for (int i = tid; i < cnt; i += 256) atomicAdd(&deg[pairs[base + i].y - dlo], 1);
        __syncthreads();
        if (tid == 0) { int s = 0; for (int i = 0; i < dn; ++i) { int t = deg[i]; deg[i] = s; s += t; } }
        __syncthreads();
        for (int i = tid; i < dn; i += 256) { rp[dlo + i] = base + deg[i]; cur[i] = deg[i]; }
        __syncthreads();
        for (int i = tid; i < cnt; i += 256) {
            int2 e = pairs[base + i];
            int off = atomicAdd(&cur[e.y - dlo], 1);
            colg[base + off] = e.x;
        }
    }
}

// ---------------------------------------------------------------------------
// W prep: split f32 W[k][c] into bf16 hi/lo, transposed to [c][k]
// ---------------------------------------------------------------------------
__global__ __launch_bounds__(256) void wprep(const float* W0, const float* W1,
                                             const float* W2, const float* W3,
                                             const float* W4, const float* W5,
                                             const float* W6, const float* W7,
                                             unsigned short* __restrict__ wt) {
    const float* W;
    switch (blockIdx.x) {
        case 0: W = W0; break; case 1: W = W1; break;
        case 2: W = W2; break; case 3: W = W3; break;
        case 4: W = W4; break; case 5: W = W5; break;
        case 6: W = W6; break; default: W = W7; break;
    }
    unsigned short* hi = wt + (size_t)blockIdx.x * 32768;
    unsigned short* lo = hi + 16384;
    for (int i = threadIdx.x; i < 16384; i += 256) {
        int k = i >> 7, c = i & 127;
        float x = W[i];
        unsigned short h = f2bf(x);
        unsigned short l = f2bf(x - bf2f(h));
        hi[c * 128 + k] = h;
        lo[c * 128 + k] = l;
    }
}

// ---------------------------------------------------------------------------
// Gather-mean: one wave per dst row; 4 neighbor rows in flight per iteration.
// lane = sub(2b) x q(4b): row slot sub in {0..3}, 32B column group q in {0..15}.
// ---------------------------------------------------------------------------
__global__ __launch_bounds__(256) void agg_mean(const float* __restrict__ h,
                                                const int* __restrict__ rp,
                                                const int* __restrict__ col,
                                                float* __restrict__ agg, int n) {
    int d = blockIdx.x * 4 + (threadIdx.x >> 6);
    if (d >= n) return;
    int lane = threadIdx.x & 63;
    int sub  = lane >> 4;
    int q    = lane & 15;
    int beg = rp[d], end = rp[d + 1];
    float a0 = 0.f, a1 = 0.f, a2 = 0.f, a3 = 0.f;
    float a4 = 0.f, a5 = 0.f, a6 = 0.f, a7 = 0.f;
    for (int i = beg; i < end; i += 4) {
        int j = i + sub;
        bool act = j < end;
        int s = col[act ? j : beg];
        const float* row = h + (size_t)s * D + q * 8;
        float4 v0 = ((const float4*)row)[0];
        float4 v1 = ((const float4*)row)[1];
        if (act) {
            a0 += v0.x; a1 += v0.y; a2 += v0.z; a3 += v0.w;
            a4 += v1.x; a5 += v1.y; a6 += v1.z; a7 += v1.w;
        }
    }
    #pragma unroll
    for (int off = 16; off <= 32; off <<= 1) {
        a0 += __shfl_xor(a0, off); a1 += __shfl_xor(a1, off);
        a2 += __shfl_xor(a2, off); a3 += __shfl_xor(a3, off);
        a4 += __shfl_xor(a4, off); a5 += __shfl_xor(a5, off);
        a6 += __shfl_xor(a6, off); a7 += __shfl_xor(a7, off);
    }
    int cnt = end - beg;
    float inv = (cnt > 0) ? 1.0f / (float)cnt : 0.f;
    if (sub == 0) {
        float4 o0 = make_float4(a0 * inv, a1 * inv, a2 * inv, a3 * inv);
        float4 o1 = make_float4(a4 * inv, a5 * inv, a6 * inv, a7 * inv);
        float* op = agg + (size_t)d * D + q * 8;
        ((float4*)op)[0] = o0;
        ((float4*)op)[1] = o1;
    }
}

// ---------------------------------------------------------------------------
// MFMA dual GEMM with bf16x3 split (unchanged, verified)
// ---------------------------------------------------------------------------
template <bool RELU>
__global__ __launch_bounds__(256) void gemm2_mfma(
    const float* __restrict__ A1, const float* __restrict__ A2,
    const unsigned short* __restrict__ Wt1, const unsigned short* __restrict__ Wt2,
    const float* __restrict__ bias, float* __restrict__ out, int n)
{
    __shared__ unsigned short As_hi[128][PAD];
    __shared__ unsigned short As_lo[128][PAD];
    __shared__ unsigned short Ws_hi[128][PAD];
    __shared__ unsigned short Ws_lo[128][PAD];

    const int tid  = threadIdx.x;
    const int lane = tid & 63;
    const int w    = tid >> 6;
    const int m0   = blockIdx.x * 128;

    f32x4 acc[2][8];
    #pragma unroll
    for (int i = 0; i < 2; ++i)
        #pragma unroll
        for (int j = 0; j < 8; ++j) acc[i][j] = (f32x4)0.f;

    const int srow  = tid >> 1;
    const int skoff = (tid & 1) * 16;

    for (int ks = 0; ks < 8; ++ks) {
        const int half = ks >> 2;
        const int kb   = (ks & 3) * 32;
        const float* A = half ? A2 : A1;
        const unsigned short* Wt = half ? Wt2 : Wt1;

        {
            int grow = m0 + srow;
            if (grow >= n) grow = n - 1;
            const float* ap = A + (size_t)grow * D + kb + skoff;
            #pragma unroll
            for (int j = 0; j < 4; ++j) {
                float4 v = *(const float4*)(ap + j * 4);
                u16x4 hh, ll;
                hh.x = f2bf(v.x); ll.x = f2bf(v.x - bf2f(hh.x));
                hh.y = f2bf(v.y); ll.y = f2bf(v.y - bf2f(hh.y));
                hh.z = f2bf(v.z); ll.z = f2bf(v.z - bf2f(hh.z));
                hh.w = f2bf(v.w); ll.w = f2bf(v.w - bf2f(hh.w));
                *(u16x4*)&As_hi[srow][skoff + j * 4] = hh;
                *(u16x4*)&As_lo[srow][skoff + j * 4] = ll;
            }
        }
        {
            const uint4* ph = (const uint4*)(Wt + (size_t)srow * D + kb + skoff);
            ((uint4*)&Ws_hi[srow][skoff])[0] = ph[0];
            ((uint4*)&Ws_hi[srow][skoff])[1] = ph[1];
            const uint4* pl = (const uint4*)(Wt + 16384 + (size_t)srow * D + kb + skoff);
            ((uint4*)&Ws_lo[srow][skoff])[0] = pl[0];
            ((uint4*)&Ws_lo[srow][skoff])[1] = pl[1];
        }
        __syncthreads();

        const int r0 = w * 32;
        const int k8 = (lane >> 4) * 8;
        const int li = lane & 15;

        short8 ah[2], al[2];
        #pragma unroll
        for (int m = 0; m < 2; ++m) {
            int rr = r0 + m * 16 + li;
            ah[m] = *(const short8*)&As_hi[rr][k8];
            al[m] = *(const short8*)&As_lo[rr][k8];
        }
        #pragma unroll
        for (int nb = 0; nb < 8; ++nb) {
            int cc = nb * 16 + li;
            short8 bh = *(const short8*)&Ws_hi[cc][k8];
            short8 bl = *(const short8*)&Ws_lo[cc][k8];
            #pragma unroll
            for (int m = 0; m < 2; ++m) {
                acc[m][nb] = __builtin_amdgcn_mfma_f32_16x16x32_bf16(ah[m], bh, acc[m][nb], 0, 0, 0);
                acc[m][nb] = __builtin_amdgcn_mfma_f32_16x16x32_bf16(al[m], bh, acc[m][nb], 0, 0, 0);
                acc[m][nb] = __builtin_amdgcn_mfma_f32_16x16x32_bf16(ah[m], bl, acc[m][nb], 0, 0, 0);
            }
        }
        __syncthreads();
    }

    const int li = lane & 15;
    const int rq = (lane >> 4) * 4;
    float bv[8];
    #pragma unroll
    for (int nb = 0; nb < 8; ++nb) bv[nb] = bias[nb * 16 + li];

    #pragma unroll
    for (int m = 0; m < 2; ++m) {
        #pragma unroll
        for (int nb = 0; nb < 8; ++nb) {
            #pragma unroll
            for (int r = 0; r < 4; ++r) {
                int R = m0 + w * 32 + m * 16 + rq + r;
                if (R < n) {
                    int C = nb * 16 + li;
                    float v = acc[m][nb][r] + bv[nb];
                    if (RELU) v = fmaxf(v, 0.f);
                    out[(size_t)R * D + C] = v;
                }
            }
        }
    }
}

// ---------------------------------------------------------------------------
extern "C" void kernel_launch(void* const* d_in, const int* in_sizes, int n_in,
                              void* d_out, int out_size, void* d_ws, size_t ws_size,
                              hipStream_t stream) {
    const float* x_p = (const float*)d_in[0];
    const float* x_q = (const float*)d_in[1];
    const int* src_pv = (const int*)d_in[2];
    const int* dst_pv = (const int*)d_in[3];
    const int* src_vp = (const int*)d_in[4];
    const int* dst_vp = (const int*)d_in[5];
    const float* Wl_pv0 = (const float*)d_in[6];
    const float* Wr_pv0 = (const float*)d_in[7];
    const float* b_pv0  = (const float*)d_in[8];
    const float* Wl_vp0 = (const float*)d_in[9];
    const float* Wr_vp0 = (const float*)d_in[10];
    const float* b_vp0  = (const float*)d_in[11];
    const float* Wl_pv1 = (const float*)d_in[12];
    const float* Wr_pv1 = (const float*)d_in[13];
    const float* b_pv1  = (const float*)d_in[14];
    const float* Wl_vp1 = (const float*)d_in[15];
    const float* Wr_vp1 = (const float*)d_in[16];
    const float* b_vp1  = (const float*)d_in[17];

    const int NP = in_sizes[0] / D;
    const int NQ = in_sizes[1] / D;
    const int E  = in_sizes[2];

    float* out_p = (float*)d_out;
    float* out_q = out_p + (size_t)NP * D;

    // bucket shifts: smallest shift with bucket count <= NBMAX
    int shq = 0; while ((((NQ - 1) >> shq) + 1) > NBMAX) ++shq;
    if (shq < 6) shq = 6;
    int shp = 0; while ((((NP - 1) >> shp) + 1) > NBMAX) ++shp;
    if (shp < 6) shp = 6;
    int nbq = ((NQ - 1) >> shq) + 1;   // 782 for NQ=50000, shq=6
    int nbp = ((NP - 1) >> shp) + 1;   // 782 for NP=100000, shp=7

    // workspace layout
    char* ws = (char*)d_ws;
    int* rp_q  = (int*)ws;                   // NQ+1
    int* rp_p  = rp_q + (NQ + 1);            // NP+1
    int* col_q = rp_p + (NP + 1);            // E
    int* col_p = col_q + E;                  // E
    int* bq    = col_p + E;                  // NBMAX (bucket counts -> bases)
    int* bp    = bq + NBMAX;                 // NBMAX
    int* curq  = bp + NBMAX;                 // NBMAX (cursors)
    int* curp  = curq + NBMAX;               // NBMAX
    size_t int_bytes = ((size_t)(NQ + 1) + (NP + 1) + 2 * (size_t)E + 4 * NBMAX) * sizeof(int);
    int_bytes = (int_bytes + 511) & ~(size_t)511;
    unsigned short* wt = (unsigned short*)(ws + int_bytes);
    size_t wt_bytes = ((size_t)8 * 32768 * sizeof(unsigned short) + 511) & ~(size_t)511;
    float* agg_q = (float*)(ws + int_bytes + wt_bytes);
    float* agg_p = agg_q + (size_t)NQ * D;
    // pairs alias the agg region (dead before first agg_mean)
    int2* pairs_q = (int2*)agg_q;
    int2* pairs_p = pairs_q + E;

    // --- CSR build via bucketed counting sort ---
    hipMemsetAsync(bq, 0, 2 * NBMAX * sizeof(int), stream);
    bhist<<<128, 256, 0, stream>>>(dst_pv, dst_vp, E, shq, shp, bq, bp);
    bscan<<<1, 128, 0, stream>>>(bq, nbq, bp, nbp, curq, curp, rp_q, NQ, rp_p, NP, E);
    bscatter<<<64, 256, 0, stream>>>(src_pv, dst_pv, src_vp, dst_vp, E,
                                     curq, shq, curp, shp, pairs_q, pairs_p, 64);
    bcsr<<<nbq + nbp, 256, 0, stream>>>(pairs_q, pairs_p, bq, nbq, bp, nbp,
                                        rp_q, NQ, shq, rp_p, NP, shp, col_q, col_p, E);

    // --- W split/transpose ---
    wprep<<<8, 256, 0, stream>>>(Wl_pv0, Wr_pv0, Wl_vp0, Wr_vp0,
                                 Wl_pv1, Wr_pv1, Wl_vp1, Wr_vp1, wt);

    const int B = 256;
    int gq = (NQ + 3) / 4, gp = (NP + 3) / 4;
    int mq = (NQ + 127) / 128, mp = (NP + 127) / 128;

    // --- layer 0 ---
    agg_mean<<<gq, B, 0, stream>>>(x_p, rp_q, col_q, agg_q, NQ);
    agg_mean<<<gp, B, 0, stream>>>(x_q, rp_p, col_p, agg_p, NP);
    gemm2_mfma<true><<<mq, B, 0, stream>>>(agg_q, x_q, wt + 0 * 32768, wt + 1 * 32768, b_pv0, out_q, NQ);
    gemm2_mfma<true><<<mp, B, 0, stream>>>(agg_p, x_p, wt + 2 * 32768, wt + 3 * 32768, b_vp0, out_p, NP);

    // --- layer 1 ---
    agg_mean<<<gq, B, 0, stream>>>(out_p, rp_q, col_q, agg_q, NQ);
    agg_mean<<<gp, B, 0, stream>>>(out_q, rp_p, col_p, agg_p, NP);
    gemm2_mfma<false><<<mq, B, 0, stream>>>(agg_q, out_q, wt + 4 * 32768, wt + 5 * 32768, b_pv1, out_q, NQ);
    gemm2_mfma<false><<<mp, B, 0, stream>>>(agg_p, out_p, wt + 6 * 32768, wt + 7 * 32768, b_vp1, out_p, NP);
}

// Round 5
// 411.257 us; speedup vs baseline: 2.0875x; 1.1023x over previous
//
#include <hip/hip_runtime.h>

#define D 128
#define PAD 40
#define NBT 256      // max buckets per node type (nb <= 256 by shift choice)
#define DNMAX 512    // max dsts per bucket (bucket width <= 512)

typedef __attribute__((ext_vector_type(8))) short short8;
typedef __attribute__((ext_vector_type(4))) float f32x4;
typedef __attribute__((ext_vector_type(4))) unsigned short u16x4;

__device__ __forceinline__ unsigned short f2bf(float x) {
    union { float f; unsigned u; } v; v.f = x;
    unsigned r = v.u + 0x7fff + ((v.u >> 16) & 1);
    return (unsigned short)(r >> 16);
}
__device__ __forceinline__ float bf2f(unsigned short b) {
    union { float f; unsigned u; } v; v.u = ((unsigned)b) << 16;
    return v.f;
}

// ---------------------------------------------------------------------------
// Bucketed CSR build. Buckets: dst >> shq (q), dst >> shp (p); nb* <= 256.
// ---------------------------------------------------------------------------
__global__ __launch_bounds__(256) void bhist(const int* __restrict__ dst_pv,
                                             const int* __restrict__ dst_vp, int E,
                                             int shq, int shp,
                                             int* __restrict__ bq, int* __restrict__ bp) {
    __shared__ int hq[NBT], hp[NBT];
    int tid = threadIdx.x;
    if (tid < NBT) { hq[tid] = 0; hp[tid] = 0; }
    __syncthreads();
    for (int e = blockIdx.x * 256 + tid; e < E; e += gridDim.x * 256) {
        atomicAdd(&hq[dst_pv[e] >> shq], 1);
        atomicAdd(&hp[dst_vp[e] >> shp], 1);
    }
    __syncthreads();
    if (tid < NBT) {
        if (hq[tid]) atomicAdd(&bq[tid], hq[tid]);
        if (hp[tid]) atomicAdd(&bp[tid], hp[tid]);
    }
}

// Exclusive-scan bucket counts in place (wave0=q, wave1=p); copy to cursors;
// write rp tails.
__global__ __launch_bounds__(128) void bscan(int* __restrict__ bq, int nbq,
                                             int* __restrict__ bp, int nbp,
                                             int* __restrict__ curq, int* __restrict__ curp,
                                             int* __restrict__ rp_q, int nq,
                                             int* __restrict__ rp_p, int np, int E) {
    int wid = threadIdx.x >> 6, lane = threadIdx.x & 63;
    int* seg = wid ? bp : bq;
    int* cur = wid ? curp : curq;
    int nseg = wid ? nbp : nbq;
    int carry = 0;
    for (int base = 0; base < nseg; base += 64) {
        int i = base + lane;
        int v = (i < nseg) ? seg[i] : 0;
        int inc = v;
        #pragma unroll
        for (int off = 1; off < 64; off <<= 1) {
            int t = __shfl_up(inc, off, 64);
            if (lane >= off) inc += t;
        }
        if (i < nseg) { int ex = carry + inc - v; seg[i] = ex; cur[i] = ex; }
        carry += __shfl(inc, 63, 64);
    }
    if (lane == 0) { if (wid == 0) rp_q[nq] = E; else rp_p[np] = E; }
}

// Block-batched scatter of (src,dst) pairs into bucket-ordered arrays.
__global__ __launch_bounds__(256) void bscatter(const int* __restrict__ src_pv,
                                                const int* __restrict__ dst_pv,
                                                const int* __restrict__ src_vp,
                                                const int* __restrict__ dst_vp, int E,
                                                int* __restrict__ curq, int shq,
                                                int* __restrict__ curp, int shp,
                                                int2* __restrict__ pairs_q,
                                                int2* __restrict__ pairs_p) {
    __shared__ int cq[NBT], baq[NBT], wq[NBT];
    __shared__ int cp_[NBT], bap[NBT], wp_[NBT];
    int tid = threadIdx.x;
    int nblk = gridDim.x;
    int chunk = (E + nblk - 1) / nblk;
    int lo = blockIdx.x * chunk;
    int hi = min(lo + chunk, E);
    if (tid < NBT) { cq[tid] = 0; cp_[tid] = 0; }
    __syncthreads();
    for (int e = lo + tid; e < hi; e += 256) {
        atomicAdd(&cq[dst_pv[e] >> shq], 1);
        atomicAdd(&cp_[dst_vp[e] >> shp], 1);
    }
    __syncthreads();
    if (tid < NBT) {
        baq[tid] = cq[tid]  ? atomicAdd(&curq[tid], cq[tid])  : 0; wq[tid]  = 0;
        bap[tid] = cp_[tid] ? atomicAdd(&curp[tid], cp_[tid]) : 0; wp_[tid] = 0;
    }
    __syncthreads();
    for (int e = lo + tid; e < hi; e += 256) {
        int d = dst_pv[e]; int b = d >> shq;
        int off = atomicAdd(&wq[b], 1);
        pairs_q[baq[b] + off] = make_int2(src_pv[e], d);
        d = dst_vp[e]; b = d >> shp;
        off = atomicAdd(&wp_[b], 1);
        pairs_p[bap[b] + off] = make_int2(src_vp[e], d);
    }
}

// Per-bucket local CSR: parallel degree count, block scan, scatter cols.
// Bucket width <= DNMAX guaranteed; no LDS pair staging (pairs re-read, L2-hot).
__global__ __launch_bounds__(256) void bcsr(const int2* __restrict__ pairs_q,
                                            const int2* __restrict__ pairs_p,
                                            const int* __restrict__ bbq, int nbq,
                                            const int* __restrict__ bbp, int nbp,
                                            int* __restrict__ rp_q, int nq, int shq,
                                            int* __restrict__ rp_p, int np, int shp,
                                            int* __restrict__ col_q, int* __restrict__ col_p,
                                            int E) {
    int b = blockIdx.x;
    const int2* pairs; const int* bb; int* rp; int* colg; int nb, n, sh;
    if (b < nbq) { pairs = pairs_q; bb = bbq; rp = rp_q; colg = col_q; nb = nbq; n = nq; sh = shq; }
    else { b -= nbq; pairs = pairs_p; bb = bbp; rp = rp_p; colg = col_p; nb = nbp; n = np; sh = shp; }
    int base = bb[b];
    int next = (b + 1 < nb) ? bb[b + 1] : E;
    int cnt = next - base;
    int dlo = b << sh;
    int dn  = min(1 << sh, n - dlo);   // <= DNMAX

    __shared__ int deg[DNMAX];
    __shared__ int cur[DNMAX];
    __shared__ int wsum[4];
    int tid = threadIdx.x, lane = tid & 63, wid = tid >> 6;

    for (int i = tid; i < dn; i += 256) deg[i] = 0;
    __syncthreads();
    for (int i = tid; i < cnt; i += 256)
        atomicAdd(&deg[pairs[base + i].y - dlo], 1);
    __syncthreads();

    // block exclusive scan of deg[0..dn), 2 elems/thread
    int t2 = tid * 2;
    int d0 = (t2 < dn) ? deg[t2] : 0;
    int d1 = (t2 + 1 < dn) ? deg[t2 + 1] : 0;
    int s = d0 + d1;
    int inc = s;
    #pragma unroll
    for (int off = 1; off < 64; off <<= 1) {
        int t = __shfl_up(inc, off, 64);
        if (lane >= off) inc += t;
    }
    if (lane == 63) wsum[wid] = inc;
    __syncthreads();
    int wpre = 0;
    for (int w2 = 0; w2 < wid; ++w2) wpre += wsum[w2];
    int ex = wpre + inc - s;
    if (t2 < dn)     { cur[t2] = ex;           rp[dlo + t2] = base + ex; }
    if (t2 + 1 < dn) { cur[t2 + 1] = ex + d0;  rp[dlo + t2 + 1] = base + ex + d0; }
    __syncthreads();

    for (int i = tid; i < cnt; i += 256) {
        int2 e = pairs[base + i];
        int off = atomicAdd(&cur[e.y - dlo], 1);
        colg[base + off] = e.x;
    }
}

// ---------------------------------------------------------------------------
// W prep: split f32 W[k][c] into bf16 hi/lo, transposed to [c][k]
// ---------------------------------------------------------------------------
__global__ __launch_bounds__(256) void wprep(const float* W0, const float* W1,
                                             const float* W2, const float* W3,
                                             const float* W4, const float* W5,
                                             const float* W6, const float* W7,
                                             unsigned short* __restrict__ wt) {
    const float* W;
    switch (blockIdx.x) {
        case 0: W = W0; break; case 1: W = W1; break;
        case 2: W = W2; break; case 3: W = W3; break;
        case 4: W = W4; break; case 5: W = W5; break;
        case 6: W = W6; break; default: W = W7; break;
    }
    unsigned short* hi = wt + (size_t)blockIdx.x * 32768;
    unsigned short* lo = hi + 16384;
    for (int i = threadIdx.x; i < 16384; i += 256) {
        int k = i >> 7, c = i & 127;
        float x = W[i];
        unsigned short h = f2bf(x);
        unsigned short l = f2bf(x - bf2f(h));
        hi[c * 128 + k] = h;
        lo[c * 128 + k] = l;
    }
}

// ---------------------------------------------------------------------------
// Gather-mean: one wave per dst row; 4 neighbor rows in flight per iteration.
// ---------------------------------------------------------------------------
__global__ __launch_bounds__(256) void agg_mean(const float* __restrict__ h,
                                                const int* __restrict__ rp,
                                                const int* __restrict__ col,
                                                float* __restrict__ agg, int n) {
    int d = blockIdx.x * 4 + (threadIdx.x >> 6);
    if (d >= n) return;
    int lane = threadIdx.x & 63;
    int sub  = lane >> 4;
    int q    = lane & 15;
    int beg = rp[d], end = rp[d + 1];
    float a0 = 0.f, a1 = 0.f, a2 = 0.f, a3 = 0.f;
    float a4 = 0.f, a5 = 0.f, a6 = 0.f, a7 = 0.f;
    for (int i = beg; i < end; i += 4) {
        int j = i + sub;
        bool act = j < end;
        int s = col[act ? j : beg];
        const float* row = h + (size_t)s * D + q * 8;
        float4 v0 = ((const float4*)row)[0];
        float4 v1 = ((const float4*)row)[1];
        if (act) {
            a0 += v0.x; a1 += v0.y; a2 += v0.z; a3 += v0.w;
            a4 += v1.x; a5 += v1.y; a6 += v1.z; a7 += v1.w;
        }
    }
    #pragma unroll
    for (int off = 16; off <= 32; off <<= 1) {
        a0 += __shfl_xor(a0, off); a1 += __shfl_xor(a1, off);
        a2 += __shfl_xor(a2, off); a3 += __shfl_xor(a3, off);
        a4 += __shfl_xor(a4, off); a5 += __shfl_xor(a5, off);
        a6 += __shfl_xor(a6, off); a7 += __shfl_xor(a7, off);
    }
    int cnt = end - beg;
    float inv = (cnt > 0) ? 1.0f / (float)cnt : 0.f;
    if (sub == 0) {
        float4 o0 = make_float4(a0 * inv, a1 * inv, a2 * inv, a3 * inv);
        float4 o1 = make_float4(a4 * inv, a5 * inv, a6 * inv, a7 * inv);
        float* op = agg + (size_t)d * D + q * 8;
        ((float4*)op)[0] = o0;
        ((float4*)op)[1] = o1;
    }
}

// ---------------------------------------------------------------------------
// MFMA dual GEMM with bf16x3 split (unchanged, verified)
// ---------------------------------------------------------------------------
template <bool RELU>
__global__ __launch_bounds__(256) void gemm2_mfma(
    const float* __restrict__ A1, const float* __restrict__ A2,
    const unsigned short* __restrict__ Wt1, const unsigned short* __restrict__ Wt2,
    const float* __restrict__ bias, float* __restrict__ out, int n)
{
    __shared__ unsigned short As_hi[128][PAD];
    __shared__ unsigned short As_lo[128][PAD];
    __shared__ unsigned short Ws_hi[128][PAD];
    __shared__ unsigned short Ws_lo[128][PAD];

    const int tid  = threadIdx.x;
    const int lane = tid & 63;
    const int w    = tid >> 6;
    const int m0   = blockIdx.x * 128;

    f32x4 acc[2][8];
    #pragma unroll
    for (int i = 0; i < 2; ++i)
        #pragma unroll
        for (int j = 0; j < 8; ++j) acc[i][j] = (f32x4)0.f;

    const int srow  = tid >> 1;
    const int skoff = (tid & 1) * 16;

    for (int ks = 0; ks < 8; ++ks) {
        const int half = ks >> 2;
        const int kb   = (ks & 3) * 32;
        const float* A = half ? A2 : A1;
        const unsigned short* Wt = half ? Wt2 : Wt1;

        {
            int grow = m0 + srow;
            if (grow >= n) grow = n - 1;
            const float* ap = A + (size_t)grow * D + kb + skoff;
            #pragma unroll
            for (int j = 0; j < 4; ++j) {
                float4 v = *(const float4*)(ap + j * 4);
                u16x4 hh, ll;
                hh.x = f2bf(v.x); ll.x = f2bf(v.x - bf2f(hh.x));
                hh.y = f2bf(v.y); ll.y = f2bf(v.y - bf2f(hh.y));
                hh.z = f2bf(v.z); ll.z = f2bf(v.z - bf2f(hh.z));
                hh.w = f2bf(v.w); ll.w = f2bf(v.w - bf2f(hh.w));
                *(u16x4*)&As_hi[srow][skoff + j * 4] = hh;
                *(u16x4*)&As_lo[srow][skoff + j * 4] = ll;
            }
        }
        {
            const uint4* ph = (const uint4*)(Wt + (size_t)srow * D + kb + skoff);
            ((uint4*)&Ws_hi[srow][skoff])[0] = ph[0];
            ((uint4*)&Ws_hi[srow][skoff])[1] = ph[1];
            const uint4* pl = (const uint4*)(Wt + 16384 + (size_t)srow * D + kb + skoff);
            ((uint4*)&Ws_lo[srow][skoff])[0] = pl[0];
            ((uint4*)&Ws_lo[srow][skoff])[1] = pl[1];
        }
        __syncthreads();

        const int r0 = w * 32;
        const int k8 = (lane >> 4) * 8;
        const int li = lane & 15;

        short8 ah[2], al[2];
        #pragma unroll
        for (int m = 0; m < 2; ++m) {
            int rr = r0 + m * 16 + li;
            ah[m] = *(const short8*)&As_hi[rr][k8];
            al[m] = *(const short8*)&As_lo[rr][k8];
        }
        #pragma unroll
        for (int nb = 0; nb < 8; ++nb) {
            int cc = nb * 16 + li;
            short8 bh = *(const short8*)&Ws_hi[cc][k8];
            short8 bl = *(const short8*)&Ws_lo[cc][k8];
            #pragma unroll
            for (int m = 0; m < 2; ++m) {
                acc[m][nb] = __builtin_amdgcn_mfma_f32_16x16x32_bf16(ah[m], bh, acc[m][nb], 0, 0, 0);
                acc[m][nb] = __builtin_amdgcn_mfma_f32_16x16x32_bf16(al[m], bh, acc[m][nb], 0, 0, 0);
                acc[m][nb] = __builtin_amdgcn_mfma_f32_16x16x32_bf16(ah[m], bl, acc[m][nb], 0, 0, 0);
            }
        }
        __syncthreads();
    }

    const int li = lane & 15;
    const int rq = (lane >> 4) * 4;
    float bv[8];
    #pragma unroll
    for (int nb = 0; nb < 8; ++nb) bv[nb] = bias[nb * 16 + li];

    #pragma unroll
    for (int m = 0; m < 2; ++m) {
        #pragma unroll
        for (int nb = 0; nb < 8; ++nb) {
            #pragma unroll
            for (int r = 0; r < 4; ++r) {
                int R = m0 + w * 32 + m * 16 + rq + r;
                if (R < n) {
                    int C = nb * 16 + li;
                    float v = acc[m][nb][r] + bv[nb];
                    if (RELU) v = fmaxf(v, 0.f);
                    out[(size_t)R * D + C] = v;
                }
            }
        }
    }
}

// ---------------------------------------------------------------------------
extern "C" void kernel_launch(void* const* d_in, const int* in_sizes, int n_in,
                              void* d_out, int out_size, void* d_ws, size_t ws_size,
                              hipStream_t stream) {
    const float* x_p = (const float*)d_in[0];
    const float* x_q = (const float*)d_in[1];
    const int* src_pv = (const int*)d_in[2];
    const int* dst_pv = (const int*)d_in[3];
    const int* src_vp = (const int*)d_in[4];
    const int* dst_vp = (const int*)d_in[5];
    const float* Wl_pv0 = (const float*)d_in[6];
    const float* Wr_pv0 = (const float*)d_in[7];
    const float* b_pv0  = (const float*)d_in[8];
    const float* Wl_vp0 = (const float*)d_in[9];
    const float* Wr_vp0 = (const float*)d_in[10];
    const float* b_vp0  = (const float*)d_in[11];
    const float* Wl_pv1 = (const float*)d_in[12];
    const float* Wr_pv1 = (const float*)d_in[13];
    const float* b_pv1  = (const float*)d_in[14];
    const float* Wl_vp1 = (const float*)d_in[15];
    const float* Wr_vp1 = (const float*)d_in[16];
    const float* b_vp1  = (const float*)d_in[17];

    const int NP = in_sizes[0] / D;
    const int NQ = in_sizes[1] / D;
    const int E  = in_sizes[2];

    float* out_p = (float*)d_out;
    float* out_q = out_p + (size_t)NP * D;

    // bucket shifts: smallest shift with bucket count <= NBT (width <= DNMAX
    // holds for n <= NBT*DNMAX = 131072)
    int shq = 6; while ((((NQ - 1) >> shq) + 1) > NBT) ++shq;   // 8 -> 196 buckets
    int shp = 6; while ((((NP - 1) >> shp) + 1) > NBT) ++shp;   // 9 -> 196 buckets
    int nbq = ((NQ - 1) >> shq) + 1;
    int nbp = ((NP - 1) >> shp) + 1;

    // workspace layout
    char* ws = (char*)d_ws;
    int* rp_q  = (int*)ws;                   // NQ+1
    int* rp_p  = rp_q + (NQ + 1);            // NP+1
    int* col_q = rp_p + (NP + 1);            // E
    int* col_p = col_q + E;                  // E
    int* bq    = col_p + E;                  // NBT (bucket counts -> bases)
    int* bp    = bq + NBT;                   // NBT
    int* curq  = bp + NBT;                   // NBT (cursors)
    int* curp  = curq + NBT;                 // NBT
    size_t int_bytes = ((size_t)(NQ + 1) + (NP + 1) + 2 * (size_t)E + 4 * NBT) * sizeof(int);
    int_bytes = (int_bytes + 511) & ~(size_t)511;
    unsigned short* wt = (unsigned short*)(ws + int_bytes);
    size_t wt_bytes = ((size_t)8 * 32768 * sizeof(unsigned short) + 511) & ~(size_t)511;
    float* agg_q = (float*)(ws + int_bytes + wt_bytes);
    float* agg_p = agg_q + (size_t)NQ * D;
    // pairs alias the agg region (dead before first agg_mean)
    int2* pairs_q = (int2*)agg_q;
    int2* pairs_p = pairs_q + E;

    // --- CSR build via bucketed counting sort ---
    hipMemsetAsync(bq, 0, 2 * NBT * sizeof(int), stream);
    bhist<<<256, 256, 0, stream>>>(dst_pv, dst_vp, E, shq, shp, bq, bp);
    bscan<<<1, 128, 0, stream>>>(bq, nbq, bp, nbp, curq, curp, rp_q, NQ, rp_p, NP, E);
    bscatter<<<512, 256, 0, stream>>>(src_pv, dst_pv, src_vp, dst_vp, E,
                                      curq, shq, curp, shp, pairs_q, pairs_p);
    bcsr<<<nbq + nbp, 256, 0, stream>>>(pairs_q, pairs_p, bq, nbq, bp, nbp,
                                        rp_q, NQ, shq, rp_p, NP, shp, col_q, col_p, E);

    // --- W split/transpose ---
    wprep<<<8, 256, 0, stream>>>(Wl_pv0, Wr_pv0, Wl_vp0, Wr_vp0,
                                 Wl_pv1, Wr_pv1, Wl_vp1, Wr_vp1, wt);

    const int B = 256;
    int gq = (NQ + 3) / 4, gp = (NP + 3) / 4;
    int mq = (NQ + 127) / 128, mp = (NP + 127) / 128;

    // --- layer 0 ---
    agg_mean<<<gq, B, 0, stream>>>(x_p, rp_q, col_q, agg_q, NQ);
    agg_mean<<<gp, B, 0, stream>>>(x_q, rp_p, col_p, agg_p, NP);
    gemm2_mfma<true><<<mq, B, 0, stream>>>(agg_q, x_q, wt + 0 * 32768, wt + 1 * 32768, b_pv0, out_q, NQ);
    gemm2_mfma<true><<<mp, B, 0, stream>>>(agg_p, x_p, wt + 2 * 32768, wt + 3 * 32768, b_vp0, out_p, NP);

    // --- layer 1 ---
    agg_mean<<<gq, B, 0, stream>>>(out_p, rp_q, col_q, agg_q, NQ);
    agg_mean<<<gp, B, 0, stream>>>(out_q, rp_p, col_p, agg_p, NP);
    gemm2_mfma<false><<<mq, B, 0, stream>>>(agg_q, out_q, wt + 4 * 32768, wt + 5 * 32768, b_pv1, out_q, NQ);
    gemm2_mfma<false><<<mp, B, 0, stream>>>(agg_p, out_p, wt + 6 * 32768, wt + 7 * 32768, b_vp1, out_p, NP);
}

// Round 7
// 403.818 us; speedup vs baseline: 2.1260x; 1.0184x over previous
//
#include <hip/hip_runtime.h>

#define D 128
#define PAD 40
#define NBT 256      // max buckets per node type
#define DNMAX 512    // max dsts per bucket

typedef __attribute__((ext_vector_type(8))) short short8;
typedef __attribute__((ext_vector_type(4))) float f32x4;

__device__ __forceinline__ unsigned short f2bf(float x) {
    union { float f; unsigned u; } v; v.f = x;
    unsigned r = v.u + 0x7fff + ((v.u >> 16) & 1);   // RNE
    return (unsigned short)(r >> 16);
}

// ---------------------------------------------------------------------------
// Bucketed CSR build (verified R5)
// ---------------------------------------------------------------------------
__global__ __launch_bounds__(256) void bhist(const int* __restrict__ dst_pv,
                                             const int* __restrict__ dst_vp, int E,
                                             int shq, int shp,
                                             int* __restrict__ bq, int* __restrict__ bp) {
    __shared__ int hq[NBT], hp[NBT];
    int tid = threadIdx.x;
    if (tid < NBT) { hq[tid] = 0; hp[tid] = 0; }
    __syncthreads();
    for (int e = blockIdx.x * 256 + tid; e < E; e += gridDim.x * 256) {
        atomicAdd(&hq[dst_pv[e] >> shq], 1);
        atomicAdd(&hp[dst_vp[e] >> shp], 1);
    }
    __syncthreads();
    if (tid < NBT) {
        if (hq[tid]) atomicAdd(&bq[tid], hq[tid]);
        if (hp[tid]) atomicAdd(&bp[tid], hp[tid]);
    }
}

__global__ __launch_bounds__(128) void bscan(int* __restrict__ bq, int nbq,
                                             int* __restrict__ bp, int nbp,
                                             int* __restrict__ curq, int* __restrict__ curp,
                                             int* __restrict__ rp_q, int nq,
                                             int* __restrict__ rp_p, int np, int E) {
    int wid = threadIdx.x >> 6, lane = threadIdx.x & 63;
    int* seg = wid ? bp : bq;
    int* cur = wid ? curp : curq;
    int nseg = wid ? nbp : nbq;
    int carry = 0;
    for (int base = 0; base < nseg; base += 64) {
        int i = base + lane;
        int v = (i < nseg) ? seg[i] : 0;
        int inc = v;
        #pragma unroll
        for (int off = 1; off < 64; off <<= 1) {
            int t = __shfl_up(inc, off, 64);
            if (lane >= off) inc += t;
        }
        if (i < nseg) { int ex = carry + inc - v; seg[i] = ex; cur[i] = ex; }
        carry += __shfl(inc, 63, 64);
    }
    if (lane == 0) { if (wid == 0) rp_q[nq] = E; else rp_p[np] = E; }
}

__global__ __launch_bounds__(256) void bscatter(const int* __restrict__ src_pv,
                                                const int* __restrict__ dst_pv,
                                                const int* __restrict__ src_vp,
                                                const int* __restrict__ dst_vp, int E,
                                                int* __restrict__ curq, int shq,
                                                int* __restrict__ curp, int shp,
                                                int2* __restrict__ pairs_q,
                                                int2* __restrict__ pairs_p) {
    __shared__ int cq[NBT], baq[NBT], wq[NBT];
    __shared__ int cp_[NBT], bap[NBT], wp_[NBT];
    int tid = threadIdx.x;
    int nblk = gridDim.x;
    int chunk = (E + nblk - 1) / nblk;
    int lo = blockIdx.x * chunk;
    int hi = min(lo + chunk, E);
    if (tid < NBT) { cq[tid] = 0; cp_[tid] = 0; }
    __syncthreads();
    for (int e = lo + tid; e < hi; e += 256) {
        atomicAdd(&cq[dst_pv[e] >> shq], 1);
        atomicAdd(&cp_[dst_vp[e] >> shp], 1);
    }
    __syncthreads();
    if (tid < NBT) {
        baq[tid] = cq[tid]  ? atomicAdd(&curq[tid], cq[tid])  : 0; wq[tid]  = 0;
        bap[tid] = cp_[tid] ? atomicAdd(&curp[tid], cp_[tid]) : 0; wp_[tid] = 0;
    }
    __syncthreads();
    for (int e = lo + tid; e < hi; e += 256) {
        int d = dst_pv[e]; int b = d >> shq;
        int off = atomicAdd(&wq[b], 1);
        pairs_q[baq[b] + off] = make_int2(src_pv[e], d);
        d = dst_vp[e]; b = d >> shp;
        off = atomicAdd(&wp_[b], 1);
        pairs_p[bap[b] + off] = make_int2(src_vp[e], d);
    }
}

__global__ __launch_bounds__(256) void bcsr(const int2* __restrict__ pairs_q,
                                            const int2* __restrict__ pairs_p,
                                            const int* __restrict__ bbq, int nbq,
                                            const int* __restrict__ bbp, int nbp,
                                            int* __restrict__ rp_q, int nq, int shq,
                                            int* __restrict__ rp_p, int np, int shp,
                                            int* __restrict__ col_q, int* __restrict__ col_p,
                                            int E) {
    int b = blockIdx.x;
    const int2* pairs; const int* bb; int* rp; int* colg; int nb, n, sh;
    if (b < nbq) { pairs = pairs_q; bb = bbq; rp = rp_q; colg = col_q; nb = nbq; n = nq; sh = shq; }
    else { b -= nbq; pairs = pairs_p; bb = bbp; rp = rp_p; colg = col_p; nb = nbp; n = np; sh = shp; }
    int base = bb[b];
    int next = (b + 1 < nb) ? bb[b + 1] : E;
    int cnt = next - base;
    int dlo = b << sh;
    int dn  = min(1 << sh, n - dlo);

    __shared__ int deg[DNMAX];
    __shared__ int cur[DNMAX];
    __shared__ int wsum[4];
    int tid = threadIdx.x, lane = tid & 63, wid = tid >> 6;

    for (int i = tid; i < dn; i += 256) deg[i] = 0;
    __syncthreads();
    for (int i = tid; i < cnt; i += 256)
        atomicAdd(&deg[pairs[base + i].y - dlo], 1);
    __syncthreads();

    int t2 = tid * 2;
    int d0 = (t2 < dn) ? deg[t2] : 0;
    int d1 = (t2 + 1 < dn) ? deg[t2 + 1] : 0;
    int s = d0 + d1;
    int inc = s;
    #pragma unroll
    for (int off = 1; off < 64; off <<= 1) {
        int t = __shfl_up(inc, off, 64);
        if (lane >= off) inc += t;
    }
    if (lane == 63) wsum[wid] = inc;
    __syncthreads();
    int wpre = 0;
    for (int w2 = 0; w2 < wid; ++w2) wpre += wsum[w2];
    int ex = wpre + inc - s;
    if (t2 < dn)     { cur[t2] = ex;           rp[dlo + t2] = base + ex; }
    if (t2 + 1 < dn) { cur[t2 + 1] = ex + d0;  rp[dlo + t2 + 1] = base + ex + d0; }
    __syncthreads();

    for (int i = tid; i < cnt; i += 256) {
        int2 e = pairs[base + i];
        int off = atomicAdd(&cur[e.y - dlo], 1);
        colg[base + off] = e.x;
    }
}

// ---------------------------------------------------------------------------
// W prep: split f32 W[k][c] into bf16 hi/lo, transposed to [c][k]
// ---------------------------------------------------------------------------
__global__ __launch_bounds__(256) void wprep(const float* W0, const float* W1,
                                             const float* W2, const float* W3,
                                             const float* W4, const float* W5,
                                             const float* W6, const float* W7,
                                             unsigned short* __restrict__ wt) {
    const float* W;
    switch (blockIdx.x) {
        case 0: W = W0; break; case 1: W = W1; break;
        case 2: W = W2; break; case 3: W = W3; break;
        case 4: W = W4; break; case 5: W = W5; break;
        case 6: W = W6; break; default: W = W7; break;
    }
    unsigned short* hi = wt + (size_t)blockIdx.x * 32768;
    unsigned short* lo = hi + 16384;
    for (int i = threadIdx.x; i < 16384; i += 256) {
        int k = i >> 7, c = i & 127;
        float x = W[i];
        unsigned short h = f2bf(x);
        union { float f; unsigned u; } hv; hv.u = ((unsigned)h) << 16;
        unsigned short l = f2bf(x - hv.f);
        hi[c * 128 + k] = h;
        lo[c * 128 + k] = l;
    }
}

// ---------------------------------------------------------------------------
// f32 -> bf16 conversion of two arrays (element groups of 4)
// ---------------------------------------------------------------------------
__global__ __launch_bounds__(256) void tobf16(const float* __restrict__ a,
                                              unsigned short* __restrict__ oa, int na4,
                                              const float* __restrict__ b,
                                              unsigned short* __restrict__ ob, int nb4) {
    int tot = na4 + nb4;
    for (int g = blockIdx.x * 256 + threadIdx.x; g < tot; g += gridDim.x * 256) {
        const float* src; unsigned short* dst; int i;
        if (g < na4) { src = a; dst = oa; i = g; }
        else         { src = b; dst = ob; i = g - na4; }
        float4 v = ((const float4*)src)[i];
        ushort4 o;
        o.x = f2bf(v.x); o.y = f2bf(v.y); o.z = f2bf(v.z); o.w = f2bf(v.w);
        ((ushort4*)dst)[i] = o;
    }
}

// ---------------------------------------------------------------------------
// Merged gather-mean (q side + p side in one grid), bf16 rows.
// One wave per dst row: lane owns features [2*lane, 2*lane+1] (uint = 2 bf16),
// 4 neighbors in flight, f32 accumulate, bf16 output. No cross-lane reduce.
// ---------------------------------------------------------------------------
__global__ __launch_bounds__(256) void agg_all(
    const int* __restrict__ rp_q, const int* __restrict__ col_q,
    const unsigned short* __restrict__ srcq, unsigned short* __restrict__ outq, int nq,
    const int* __restrict__ rp_p, const int* __restrict__ col_p,
    const unsigned short* __restrict__ srcp, unsigned short* __restrict__ outp, int np,
    int nwq) {
    int blk = blockIdx.x;
    const int* rp; const int* col; const unsigned short* src; unsigned short* out; int n, d;
    if (blk < nwq) { rp = rp_q; col = col_q; src = srcq; out = outq; n = nq; d = blk * 4 + (threadIdx.x >> 6); }
    else { rp = rp_p; col = col_p; src = srcp; out = outp; n = np; d = (blk - nwq) * 4 + (threadIdx.x >> 6); }
    if (d >= n) return;
    int lane = threadIdx.x & 63;
    int beg = rp[d], end = rp[d + 1];
    float a0 = 0.f, a1 = 0.f;
    for (int i = beg; i < end; i += 4) {
        unsigned u[4]; bool m[4];
        #pragma unroll
        for (int j = 0; j < 4; ++j) {
            int idx = i + j;
            m[j] = idx < end;
            int s = col[m[j] ? idx : beg];
            u[j] = ((const unsigned*)(src + (size_t)s * D))[lane];
        }
        #pragma unroll
        for (int j = 0; j < 4; ++j) {
            if (m[j]) {
                union { unsigned u; float f; } lo, hi;
                lo.u = u[j] << 16;
                hi.u = u[j] & 0xffff0000u;
                a0 += lo.f; a1 += hi.f;
            }
        }
    }
    int cnt = end - beg;
    float inv = (cnt > 0) ? 1.0f / (float)cnt : 0.f;
    unsigned o = (unsigned)f2bf(a0 * inv) | ((unsigned)f2bf(a1 * inv) << 16);
    ((unsigned*)(out + (size_t)d * D))[lane] = o;
}

// ---------------------------------------------------------------------------
// MFMA dual GEMM, all-bf16 A: out = A1@W1 + A2@W2 + bias (+ReLU)
// A1,A2: n x 128 bf16. Wt: pre-split hi/lo [col][k] bf16. 2 MFMAs per k-step.
// WHB: also emit bf16 copy of out to hb (layer-0 h1 for layer-1 gather).
// hb may alias A2 (each block reads/writes only its own 128-row tile).
// NOTE: each staging thread owns 16 bf16 = TWO uint4 stores (R6 bug: had one).
// ---------------------------------------------------------------------------
template <bool RELU, bool WHB>
__global__ __launch_bounds__(256) void gemm2_bf16(
    const unsigned short* __restrict__ A1, const unsigned short* __restrict__ A2,
    const unsigned short* __restrict__ Wt1, const unsigned short* __restrict__ Wt2,
    const float* __restrict__ bias, float* __restrict__ out,
    unsigned short* hb, int n)
{
    __shared__ unsigned short As[128][PAD];
    __shared__ unsigned short Ws_hi[128][PAD];
    __shared__ unsigned short Ws_lo[128][PAD];

    const int tid  = threadIdx.x;
    const int lane = tid & 63;
    const int w    = tid >> 6;
    const int m0   = blockIdx.x * 128;

    f32x4 acc[2][8];
    #pragma unroll
    for (int i = 0; i < 2; ++i)
        #pragma unroll
        for (int j = 0; j < 8; ++j) acc[i][j] = (f32x4)0.f;

    const int srow  = tid >> 1;          // 0..127
    const int skoff = (tid & 1) * 16;    // 0 or 16 (owns 16 bf16)

    for (int ks = 0; ks < 8; ++ks) {
        const int half = ks >> 2;
        const int kb   = (ks & 3) * 32;
        const unsigned short* A  = half ? A2 : A1;
        const unsigned short* Wt = half ? Wt2 : Wt1;

        {
            int grow = m0 + srow;
            if (grow >= n) grow = n - 1;
            const uint4* pa = (const uint4*)(A + (size_t)grow * D + kb + skoff);
            ((uint4*)&As[srow][skoff])[0] = pa[0];
            ((uint4*)&As[srow][skoff])[1] = pa[1];
        }
        {
            const uint4* ph = (const uint4*)(Wt + (size_t)srow * D + kb + skoff);
            ((uint4*)&Ws_hi[srow][skoff])[0] = ph[0];
            ((uint4*)&Ws_hi[srow][skoff])[1] = ph[1];
            const uint4* pl = (const uint4*)(Wt + 16384 + (size_t)srow * D + kb + skoff);
            ((uint4*)&Ws_lo[srow][skoff])[0] = pl[0];
            ((uint4*)&Ws_lo[srow][skoff])[1] = pl[1];
        }
        __syncthreads();

        const int r0 = w * 32;
        const int k8 = (lane >> 4) * 8;
        const int li = lane & 15;

        short8 ah[2];
        #pragma unroll
        for (int m = 0; m < 2; ++m)
            ah[m] = *(const short8*)&As[r0 + m * 16 + li][k8];
        #pragma unroll
        for (int nb = 0; nb < 8; ++nb) {
            int cc = nb * 16 + li;
            short8 bh = *(const short8*)&Ws_hi[cc][k8];
            short8 bl = *(const short8*)&Ws_lo[cc][k8];
            #pragma unroll
            for (int m = 0; m < 2; ++m) {
                acc[m][nb] = __builtin_amdgcn_mfma_f32_16x16x32_bf16(ah[m], bh, acc[m][nb], 0, 0, 0);
                acc[m][nb] = __builtin_amdgcn_mfma_f32_16x16x32_bf16(ah[m], bl, acc[m][nb], 0, 0, 0);
            }
        }
        __syncthreads();
    }

    const int li = lane & 15;
    const int rq = (lane >> 4) * 4;
    float bv[8];
    #pragma unroll
    for (int nb = 0; nb < 8; ++nb) bv[nb] = bias[nb * 16 + li];

    #pragma unroll
    for (int m = 0; m < 2; ++m) {
        #pragma unroll
        for (int nb = 0; nb < 8; ++nb) {
            #pragma unroll
            for (int r = 0; r < 4; ++r) {
                int R = m0 + w * 32 + m * 16 + rq + r;
                if (R < n) {
                    int C = nb * 16 + li;
                    float v = acc[m][nb][r] + bv[nb];
                    if (RELU) v = fmaxf(v, 0.f);
                    out[(size_t)R * D + C] = v;
                    if (WHB) hb[(size_t)R * D + C] = f2bf(v);
                }
            }
        }
    }
}

// ---------------------------------------------------------------------------
extern "C" void kernel_launch(void* const* d_in, const int* in_sizes, int n_in,
                              void* d_out, int out_size, void* d_ws, size_t ws_size,
                              hipStream_t stream) {
    const float* x_p = (const float*)d_in[0];
    const float* x_q = (const float*)d_in[1];
    const int* src_pv = (const int*)d_in[2];
    const int* dst_pv = (const int*)d_in[3];
    const int* src_vp = (const int*)d_in[4];
    const int* dst_vp = (const int*)d_in[5];
    const float* Wl_pv0 = (const float*)d_in[6];
    const float* Wr_pv0 = (const float*)d_in[7];
    const float* b_pv0  = (const float*)d_in[8];
    const float* Wl_vp0 = (const float*)d_in[9];
    const float* Wr_vp0 = (const float*)d_in[10];
    const float* b_vp0  = (const float*)d_in[11];
    const float* Wl_pv1 = (const float*)d_in[12];
    const float* Wr_pv1 = (const float*)d_in[13];
    const float* b_pv1  = (const float*)d_in[14];
    const float* Wl_vp1 = (const float*)d_in[15];
    const float* Wr_vp1 = (const float*)d_in[16];
    const float* b_vp1  = (const float*)d_in[17];

    const int NP = in_sizes[0] / D;
    const int NQ = in_sizes[1] / D;
    const int E  = in_sizes[2];

    float* out_p = (float*)d_out;
    float* out_q = out_p + (size_t)NP * D;

    int shq = 6; while ((((NQ - 1) >> shq) + 1) > NBT) ++shq;
    int shp = 6; while ((((NP - 1) >> shp) + 1) > NBT) ++shp;
    int nbq = ((NQ - 1) >> shq) + 1;
    int nbp = ((NP - 1) >> shp) + 1;

    // workspace layout
    char* ws = (char*)d_ws;
    int* rp_q  = (int*)ws;                   // NQ+1
    int* rp_p  = rp_q + (NQ + 1);            // NP+1
    int* col_q = rp_p + (NP + 1);            // E
    int* col_p = col_q + E;                  // E
    int* bq    = col_p + E;                  // NBT
    int* bp    = bq + NBT;                   // NBT
    int* curq  = bp + NBT;                   // NBT
    int* curp  = curq + NBT;                 // NBT
    size_t int_bytes = ((size_t)(NQ + 1) + (NP + 1) + 2 * (size_t)E + 4 * NBT) * sizeof(int);
    int_bytes = (int_bytes + 511) & ~(size_t)511;
    unsigned short* wt = (unsigned short*)(ws + int_bytes);   // 8*32768 u16
    size_t wt_bytes = ((size_t)8 * 32768 * sizeof(unsigned short) + 511) & ~(size_t)511;
    // bf16 feature tables; xb region is reused as hb (h1 bf16) after layer-0
    unsigned short* xb_p = (unsigned short*)(ws + int_bytes + wt_bytes);  // NP*128
    unsigned short* xb_q = xb_p + (size_t)NP * D;                          // NQ*128
    unsigned short* hb_p = xb_p;   // alias (block-local in-place, see gemm)
    unsigned short* hb_q = xb_q;
    unsigned short* aggb_q = xb_q + (size_t)NQ * D;                        // NQ*128
    unsigned short* aggb_p = aggb_q + (size_t)NQ * D;                      // NP*128
    // pairs alias the aggb region (dead before first agg write)
    int2* pairs_q = (int2*)aggb_q;
    int2* pairs_p = pairs_q + E;

    // --- CSR build ---
    hipMemsetAsync(bq, 0, 2 * NBT * sizeof(int), stream);
    bhist<<<256, 256, 0, stream>>>(dst_pv, dst_vp, E, shq, shp, bq, bp);
    bscan<<<1, 128, 0, stream>>>(bq, nbq, bp, nbp, curq, curp, rp_q, NQ, rp_p, NP, E);
    bscatter<<<512, 256, 0, stream>>>(src_pv, dst_pv, src_vp, dst_vp, E,
                                      curq, shq, curp, shp, pairs_q, pairs_p);
    bcsr<<<nbq + nbp, 256, 0, stream>>>(pairs_q, pairs_p, bq, nbq, bp, nbp,
                                        rp_q, NQ, shq, rp_p, NP, shp, col_q, col_p, E);

    // --- weight split + input bf16 conversion ---
    wprep<<<8, 256, 0, stream>>>(Wl_pv0, Wr_pv0, Wl_vp0, Wr_vp0,
                                 Wl_pv1, Wr_pv1, Wl_vp1, Wr_vp1, wt);
    tobf16<<<2048, 256, 0, stream>>>(x_p, xb_p, NP * D / 4, x_q, xb_q, NQ * D / 4);

    int nwq = (NQ + 3) / 4, nwp = (NP + 3) / 4;
    int mq = (NQ + 127) / 128, mp = (NP + 127) / 128;

    // --- layer 0 ---
    agg_all<<<nwq + nwp, 256, 0, stream>>>(rp_q, col_q, xb_p, aggb_q, NQ,
                                           rp_p, col_p, xb_q, aggb_p, NP, nwq);
    gemm2_bf16<true, true><<<mq, 256, 0, stream>>>(aggb_q, xb_q, wt + 0 * 32768, wt + 1 * 32768,
                                                   b_pv0, out_q, hb_q, NQ);
    gemm2_bf16<true, true><<<mp, 256, 0, stream>>>(aggb_p, xb_p, wt + 2 * 32768, wt + 3 * 32768,
                                                   b_vp0, out_p, hb_p, NP);

    // --- layer 1 ---
    agg_all<<<nwq + nwp, 256, 0, stream>>>(rp_q, col_q, hb_p, aggb_q, NQ,
                                           rp_p, col_p, hb_q, aggb_p, NP, nwq);
    gemm2_bf16<false, false><<<mq, 256, 0, stream>>>(aggb_q, hb_q, wt + 4 * 32768, wt + 5 * 32768,
                                                     b_pv1, out_q, (unsigned short*)nullptr, NQ);
    gemm2_bf16<false, false><<<mp, 256, 0, stream>>>(aggb_p, hb_p, wt + 6 * 32768, wt + 7 * 32768,
                                                     b_vp1, out_p, (unsigned short*)nullptr, NP);
}

// Round 8
// 360.985 us; speedup vs baseline: 2.3782x; 1.1187x over previous
//
#include <hip/hip_runtime.h>

#define D 128
#define PAD 40
#define NBT 256      // max buckets per node type
#define DNMAX 512    // max dsts per bucket

typedef __attribute__((ext_vector_type(8))) short short8;
typedef __attribute__((ext_vector_type(4))) float f32x4;

__device__ __forceinline__ unsigned short f2bf(float x) {
    union { float f; unsigned u; } v; v.f = x;
    unsigned r = v.u + 0x7fff + ((v.u >> 16) & 1);   // RNE
    return (unsigned short)(r >> 16);
}

// ---------------------------------------------------------------------------
// Bucketed CSR build (verified R5/R7)
// ---------------------------------------------------------------------------
__global__ __launch_bounds__(256) void bhist(const int* __restrict__ dst_pv,
                                             const int* __restrict__ dst_vp, int E,
                                             int shq, int shp,
                                             int* __restrict__ bq, int* __restrict__ bp) {
    __shared__ int hq[NBT], hp[NBT];
    int tid = threadIdx.x;
    if (tid < NBT) { hq[tid] = 0; hp[tid] = 0; }
    __syncthreads();
    for (int e = blockIdx.x * 256 + tid; e < E; e += gridDim.x * 256) {
        atomicAdd(&hq[dst_pv[e] >> shq], 1);
        atomicAdd(&hp[dst_vp[e] >> shp], 1);
    }
    __syncthreads();
    if (tid < NBT) {
        if (hq[tid]) atomicAdd(&bq[tid], hq[tid]);
        if (hp[tid]) atomicAdd(&bp[tid], hp[tid]);
    }
}

__global__ __launch_bounds__(128) void bscan(int* __restrict__ bq, int nbq,
                                             int* __restrict__ bp, int nbp,
                                             int* __restrict__ curq, int* __restrict__ curp,
                                             int* __restrict__ rp_q, int nq,
                                             int* __restrict__ rp_p, int np, int E) {
    int wid = threadIdx.x >> 6, lane = threadIdx.x & 63;
    int* seg = wid ? bp : bq;
    int* cur = wid ? curp : curq;
    int nseg = wid ? nbp : nbq;
    int carry = 0;
    for (int base = 0; base < nseg; base += 64) {
        int i = base + lane;
        int v = (i < nseg) ? seg[i] : 0;
        int inc = v;
        #pragma unroll
        for (int off = 1; off < 64; off <<= 1) {
            int t = __shfl_up(inc, off, 64);
            if (lane >= off) inc += t;
        }
        if (i < nseg) { int ex = carry + inc - v; seg[i] = ex; cur[i] = ex; }
        carry += __shfl(inc, 63, 64);
    }
    if (lane == 0) { if (wid == 0) rp_q[nq] = E; else rp_p[np] = E; }
}

__global__ __launch_bounds__(256) void bscatter(const int* __restrict__ src_pv,
                                                const int* __restrict__ dst_pv,
                                                const int* __restrict__ src_vp,
                                                const int* __restrict__ dst_vp, int E,
                                                int* __restrict__ curq, int shq,
                                                int* __restrict__ curp, int shp,
                                                int2* __restrict__ pairs_q,
                                                int2* __restrict__ pairs_p) {
    __shared__ int cq[NBT], baq[NBT], wq[NBT];
    __shared__ int cp_[NBT], bap[NBT], wp_[NBT];
    int tid = threadIdx.x;
    int nblk = gridDim.x;
    int chunk = (E + nblk - 1) / nblk;
    int lo = blockIdx.x * chunk;
    int hi = min(lo + chunk, E);
    if (tid < NBT) { cq[tid] = 0; cp_[tid] = 0; }
    __syncthreads();
    for (int e = lo + tid; e < hi; e += 256) {
        atomicAdd(&cq[dst_pv[e] >> shq], 1);
        atomicAdd(&cp_[dst_vp[e] >> shp], 1);
    }
    __syncthreads();
    if (tid < NBT) {
        baq[tid] = cq[tid]  ? atomicAdd(&curq[tid], cq[tid])  : 0; wq[tid]  = 0;
        bap[tid] = cp_[tid] ? atomicAdd(&curp[tid], cp_[tid]) : 0; wp_[tid] = 0;
    }
    __syncthreads();
    for (int e = lo + tid; e < hi; e += 256) {
        int d = dst_pv[e]; int b = d >> shq;
        int off = atomicAdd(&wq[b], 1);
        pairs_q[baq[b] + off] = make_int2(src_pv[e], d);
        d = dst_vp[e]; b = d >> shp;
        off = atomicAdd(&wp_[b], 1);
        pairs_p[bap[b] + off] = make_int2(src_vp[e], d);
    }
}

__global__ __launch_bounds__(256) void bcsr(const int2* __restrict__ pairs_q,
                                            const int2* __restrict__ pairs_p,
                                            const int* __restrict__ bbq, int nbq,
                                            const int* __restrict__ bbp, int nbp,
                                            int* __restrict__ rp_q, int nq, int shq,
                                            int* __restrict__ rp_p, int np, int shp,
                                            int* __restrict__ col_q, int* __restrict__ col_p,
                                            int E) {
    int b = blockIdx.x;
    const int2* pairs; const int* bb; int* rp; int* colg; int nb, n, sh;
    if (b < nbq) { pairs = pairs_q; bb = bbq; rp = rp_q; colg = col_q; nb = nbq; n = nq; sh = shq; }
    else { b -= nbq; pairs = pairs_p; bb = bbp; rp = rp_p; colg = col_p; nb = nbp; n = np; sh = shp; }
    int base = bb[b];
    int next = (b + 1 < nb) ? bb[b + 1] : E;
    int cnt = next - base;
    int dlo = b << sh;
    int dn  = min(1 << sh, n - dlo);

    __shared__ int deg[DNMAX];
    __shared__ int cur[DNMAX];
    __shared__ int wsum[4];
    int tid = threadIdx.x, lane = tid & 63, wid = tid >> 6;

    for (int i = tid; i < dn; i += 256) deg[i] = 0;
    __syncthreads();
    for (int i = tid; i < cnt; i += 256)
        atomicAdd(&deg[pairs[base + i].y - dlo], 1);
    __syncthreads();

    int t2 = tid * 2;
    int d0 = (t2 < dn) ? deg[t2] : 0;
    int d1 = (t2 + 1 < dn) ? deg[t2 + 1] : 0;
    int s = d0 + d1;
    int inc = s;
    #pragma unroll
    for (int off = 1; off < 64; off <<= 1) {
        int t = __shfl_up(inc, off, 64);
        if (lane >= off) inc += t;
    }
    if (lane == 63) wsum[wid] = inc;
    __syncthreads();
    int wpre = 0;
    for (int w2 = 0; w2 < wid; ++w2) wpre += wsum[w2];
    int ex = wpre + inc - s;
    if (t2 < dn)     { cur[t2] = ex;           rp[dlo + t2] = base + ex; }
    if (t2 + 1 < dn) { cur[t2 + 1] = ex + d0;  rp[dlo + t2 + 1] = base + ex + d0; }
    __syncthreads();

    for (int i = tid; i < cnt; i += 256) {
        int2 e = pairs[base + i];
        int off = atomicAdd(&cur[e.y - dlo], 1);
        colg[base + off] = e.x;
    }
}

// ---------------------------------------------------------------------------
// prep: blocks 0..7 -> W split/transpose; block 8 -> zero bucket counters;
//       blocks 9.. -> f32->bf16 conversion of x_p, x_q
// ---------------------------------------------------------------------------
__global__ __launch_bounds__(256) void prep(const float* W0, const float* W1,
                                            const float* W2, const float* W3,
                                            const float* W4, const float* W5,
                                            const float* W6, const float* W7,
                                            unsigned short* __restrict__ wt,
                                            int* __restrict__ bzero,   // bq (2*NBT ints)
                                            const float* __restrict__ xp,
                                            unsigned short* __restrict__ xbp, int np4,
                                            const float* __restrict__ xq,
                                            unsigned short* __restrict__ xbq, int nq4) {
    int blk = blockIdx.x;
    int tid = threadIdx.x;
    if (blk < 8) {
        const float* W;
        switch (blk) {
            case 0: W = W0; break; case 1: W = W1; break;
            case 2: W = W2; break; case 3: W = W3; break;
            case 4: W = W4; break; case 5: W = W5; break;
            case 6: W = W6; break; default: W = W7; break;
        }
        unsigned short* hi = wt + (size_t)blk * 32768;
        unsigned short* lo = hi + 16384;
        for (int i = tid; i < 16384; i += 256) {
            int k = i >> 7, c = i & 127;
            float x = W[i];
            unsigned short h = f2bf(x);
            union { float f; unsigned u; } hv; hv.u = ((unsigned)h) << 16;
            unsigned short l = f2bf(x - hv.f);
            hi[c * 128 + k] = h;
            lo[c * 128 + k] = l;
        }
    } else if (blk == 8) {
        for (int i = tid; i < 2 * NBT; i += 256) bzero[i] = 0;
    } else {
        int tot = np4 + nq4;
        int stride = (gridDim.x - 9) * 256;
        for (int g = (blk - 9) * 256 + tid; g < tot; g += stride) {
            const float* src; unsigned short* dst; int i;
            if (g < np4) { src = xp; dst = xbp; i = g; }
            else         { src = xq; dst = xbq; i = g - np4; }
            float4 v = ((const float4*)src)[i];
            ushort4 o;
            o.x = f2bf(v.x); o.y = f2bf(v.y); o.z = f2bf(v.z); o.w = f2bf(v.w);
            ((ushort4*)dst)[i] = o;
        }
    }
}

// ---------------------------------------------------------------------------
// Merged gather-mean, bf16 rows, 8 neighbors in flight.
// One wave per dst row: lane owns features [2*lane, 2*lane+1] (uint = 2 bf16).
// Skip branches are wave-uniform (j < nj) -> no divergence, no wasted loads.
// ---------------------------------------------------------------------------
__global__ __launch_bounds__(256) void agg_all(
    const int* __restrict__ rp_q, const int* __restrict__ col_q,
    const unsigned short* __restrict__ srcq, unsigned short* __restrict__ outq, int nq,
    const int* __restrict__ rp_p, const int* __restrict__ col_p,
    const unsigned short* __restrict__ srcp, unsigned short* __restrict__ outp, int np,
    int nwq) {
    int blk = blockIdx.x;
    const int* rp; const int* col; const unsigned short* src; unsigned short* out; int n, d;
    if (blk < nwq) { rp = rp_q; col = col_q; src = srcq; out = outq; n = nq; d = blk * 4 + (threadIdx.x >> 6); }
    else { rp = rp_p; col = col_p; src = srcp; out = outp; n = np; d = (blk - nwq) * 4 + (threadIdx.x >> 6); }
    if (d >= n) return;
    int lane = threadIdx.x & 63;
    int beg = rp[d], end = rp[d + 1];
    float a0 = 0.f, a1 = 0.f;
    for (int i = beg; i < end; i += 8) {
        int nj = end - i;   // wave-uniform
        unsigned u[8];
        #pragma unroll
        for (int j = 0; j < 8; ++j)
            if (j < nj) u[j] = ((const unsigned*)(src + (size_t)col[i + j] * D))[lane];
        #pragma unroll
        for (int j = 0; j < 8; ++j)
            if (j < nj) {
                union { unsigned u; float f; } lo, hi;
                lo.u = u[j] << 16;
                hi.u = u[j] & 0xffff0000u;
                a0 += lo.f; a1 += hi.f;
            }
    }
    int cnt = end - beg;
    float inv = (cnt > 0) ? 1.0f / (float)cnt : 0.f;
    unsigned o = (unsigned)f2bf(a0 * inv) | ((unsigned)f2bf(a1 * inv) << 16);
    ((unsigned*)(out + (size_t)d * D))[lane] = o;
}

// ---------------------------------------------------------------------------
// MFMA dual GEMM body (all-bf16 A, hi/lo split W, 2 MFMAs/k-step) — verified R7
// ---------------------------------------------------------------------------
struct GemmSide {
    const unsigned short* A1;
    const unsigned short* A2;
    const unsigned short* Wt1;
    const unsigned short* Wt2;
    const float* bias;
    float* out;
    unsigned short* hb;
    int n;
};

template <bool RELU, bool WHB>
__device__ __forceinline__ void gemm_body(const GemmSide& S, int bidx) {
    __shared__ unsigned short As[128][PAD];
    __shared__ unsigned short Ws_hi[128][PAD];
    __shared__ unsigned short Ws_lo[128][PAD];

    const int tid  = threadIdx.x;
    const int lane = tid & 63;
    const int w    = tid >> 6;
    const int m0   = bidx * 128;
    const int n    = S.n;

    f32x4 acc[2][8];
    #pragma unroll
    for (int i = 0; i < 2; ++i)
        #pragma unroll
        for (int j = 0; j < 8; ++j) acc[i][j] = (f32x4)0.f;

    const int srow  = tid >> 1;          // 0..127
    const int skoff = (tid & 1) * 16;    // 0 or 16 (owns 16 bf16 = two uint4)

    for (int ks = 0; ks < 8; ++ks) {
        const int half = ks >> 2;
        const int kb   = (ks & 3) * 32;
        const unsigned short* A  = half ? S.A2 : S.A1;
        const unsigned short* Wt = half ? S.Wt2 : S.Wt1;

        {
            int grow = m0 + srow;
            if (grow >= n) grow = n - 1;
            const uint4* pa = (const uint4*)(A + (size_t)grow * D + kb + skoff);
            ((uint4*)&As[srow][skoff])[0] = pa[0];
            ((uint4*)&As[srow][skoff])[1] = pa[1];
        }
        {
            const uint4* ph = (const uint4*)(Wt + (size_t)srow * D + kb + skoff);
            ((uint4*)&Ws_hi[srow][skoff])[0] = ph[0];
            ((uint4*)&Ws_hi[srow][skoff])[1] = ph[1];
            const uint4* pl = (const uint4*)(Wt + 16384 + (size_t)srow * D + kb + skoff);
            ((uint4*)&Ws_lo[srow][skoff])[0] = pl[0];
            ((uint4*)&Ws_lo[srow][skoff])[1] = pl[1];
        }
        __syncthreads();

        const int r0 = w * 32;
        const int k8 = (lane >> 4) * 8;
        const int li = lane & 15;

        short8 ah[2];
        #pragma unroll
        for (int m = 0; m < 2; ++m)
            ah[m] = *(const short8*)&As[r0 + m * 16 + li][k8];
        #pragma unroll
        for (int nb = 0; nb < 8; ++nb) {
            int cc = nb * 16 + li;
            short8 bh = *(const short8*)&Ws_hi[cc][k8];
            short8 bl = *(const short8*)&Ws_lo[cc][k8];
            #pragma unroll
            for (int m = 0; m < 2; ++m) {
                acc[m][nb] = __builtin_amdgcn_mfma_f32_16x16x32_bf16(ah[m], bh, acc[m][nb], 0, 0, 0);
                acc[m][nb] = __builtin_amdgcn_mfma_f32_16x16x32_bf16(ah[m], bl, acc[m][nb], 0, 0, 0);
            }
        }
        __syncthreads();
    }

    const int li = lane & 15;
    const int rq = (lane >> 4) * 4;
    float bv[8];
    #pragma unroll
    for (int nb = 0; nb < 8; ++nb) bv[nb] = S.bias[nb * 16 + li];

    #pragma unroll
    for (int m = 0; m < 2; ++m) {
        #pragma unroll
        for (int nb = 0; nb < 8; ++nb) {
            #pragma unroll
            for (int r = 0; r < 4; ++r) {
                int R = m0 + w * 32 + m * 16 + rq + r;
                if (R < n) {
                    int C = nb * 16 + li;
                    float v = acc[m][nb][r] + bv[nb];
                    if (RELU) v = fmaxf(v, 0.f);
                    S.out[(size_t)R * D + C] = v;
                    if (WHB) S.hb[(size_t)R * D + C] = f2bf(v);
                }
            }
        }
    }
}

// Merged q+p GEMM: blocks [0,mq) -> q side, [mq,mq+mp) -> p side.
template <bool RELU, bool WHB>
__global__ __launch_bounds__(256) void gemm_both(GemmSide Sq, GemmSide Sp, int mq) {
    if ((int)blockIdx.x < mq) gemm_body<RELU, WHB>(Sq, blockIdx.x);
    else                      gemm_body<RELU, WHB>(Sp, blockIdx.x - mq);
}

// ---------------------------------------------------------------------------
extern "C" void kernel_launch(void* const* d_in, const int* in_sizes, int n_in,
                              void* d_out, int out_size, void* d_ws, size_t ws_size,
                              hipStream_t stream) {
    const float* x_p = (const float*)d_in[0];
    const float* x_q = (const float*)d_in[1];
    const int* src_pv = (const int*)d_in[2];
    const int* dst_pv = (const int*)d_in[3];
    const int* src_vp = (const int*)d_in[4];
    const int* dst_vp = (const int*)d_in[5];
    const float* Wl_pv0 = (const float*)d_in[6];
    const float* Wr_pv0 = (const float*)d_in[7];
    const float* b_pv0  = (const float*)d_in[8];
    const float* Wl_vp0 = (const float*)d_in[9];
    const float* Wr_vp0 = (const float*)d_in[10];
    const float* b_vp0  = (const float*)d_in[11];
    const float* Wl_pv1 = (const float*)d_in[12];
    const float* Wr_pv1 = (const float*)d_in[13];
    const float* b_pv1  = (const float*)d_in[14];
    const float* Wl_vp1 = (const float*)d_in[15];
    const float* Wr_vp1 = (const float*)d_in[16];
    const float* b_vp1  = (const float*)d_in[17];

    const int NP = in_sizes[0] / D;
    const int NQ = in_sizes[1] / D;
    const int E  = in_sizes[2];

    float* out_p = (float*)d_out;
    float* out_q = out_p + (size_t)NP * D;

    int shq = 6; while ((((NQ - 1) >> shq) + 1) > NBT) ++shq;
    int shp = 6; while ((((NP - 1) >> shp) + 1) > NBT) ++shp;
    int nbq = ((NQ - 1) >> shq) + 1;
    int nbp = ((NP - 1) >> shp) + 1;

    // workspace layout
    char* ws = (char*)d_ws;
    int* rp_q  = (int*)ws;                   // NQ+1
    int* rp_p  = rp_q + (NQ + 1);            // NP+1
    int* col_q = rp_p + (NP + 1);            // E
    int* col_p = col_q + E;                  // E
    int* bq    = col_p + E;                  // NBT
    int* bp    = bq + NBT;                   // NBT
    int* curq  = bp + NBT;                   // NBT
    int* curp  = curq + NBT;                 // NBT
    size_t int_bytes = ((size_t)(NQ + 1) + (NP + 1) + 2 * (size_t)E + 4 * NBT) * sizeof(int);
    int_bytes = (int_bytes + 511) & ~(size_t)511;
    unsigned short* wt = (unsigned short*)(ws + int_bytes);   // 8*32768 u16
    size_t wt_bytes = ((size_t)8 * 32768 * sizeof(unsigned short) + 511) & ~(size_t)511;
    unsigned short* xb_p = (unsigned short*)(ws + int_bytes + wt_bytes);  // NP*128
    unsigned short* xb_q = xb_p + (size_t)NP * D;                          // NQ*128
    unsigned short* hb_p = xb_p;   // alias (block-local in-place, see gemm)
    unsigned short* hb_q = xb_q;
    unsigned short* aggb_q = xb_q + (size_t)NQ * D;                        // NQ*128
    unsigned short* aggb_p = aggb_q + (size_t)NQ * D;                      // NP*128
    int2* pairs_q = (int2*)aggb_q;  // alias (dead before first agg write)
    int2* pairs_p = pairs_q + E;

    // --- prep (W split, bucket zero, x->bf16) ---
    prep<<<9 + 2048, 256, 0, stream>>>(Wl_pv0, Wr_pv0, Wl_vp0, Wr_vp0,
                                       Wl_pv1, Wr_pv1, Wl_vp1, Wr_vp1, wt,
                                       bq, x_p, xb_p, NP * D / 4, x_q, xb_q, NQ * D / 4);

    // --- CSR build ---
    bhist<<<256, 256, 0, stream>>>(dst_pv, dst_vp, E, shq, shp, bq, bp);
    bscan<<<1, 128, 0, stream>>>(bq, nbq, bp, nbp, curq, curp, rp_q, NQ, rp_p, NP, E);
    bscatter<<<512, 256, 0, stream>>>(src_pv, dst_pv, src_vp, dst_vp, E,
                                      curq, shq, curp, shp, pairs_q, pairs_p);
    bcsr<<<nbq + nbp, 256, 0, stream>>>(pairs_q, pairs_p, bq, nbq, bp, nbp,
                                        rp_q, NQ, shq, rp_p, NP, shp, col_q, col_p, E);

    int nwq = (NQ + 3) / 4, nwp = (NP + 3) / 4;
    int mq = (NQ + 127) / 128, mp = (NP + 127) / 128;

    GemmSide Sq0 = { aggb_q, xb_q, wt + 0 * 32768, wt + 1 * 32768, b_pv0, out_q, hb_q, NQ };
    GemmSide Sp0 = { aggb_p, xb_p, wt + 2 * 32768, wt + 3 * 32768, b_vp0, out_p, hb_p, NP };
    GemmSide Sq1 = { aggb_q, hb_q, wt + 4 * 32768, wt + 5 * 32768, b_pv1, out_q, nullptr, NQ };
    GemmSide Sp1 = { aggb_p, hb_p, wt + 6 * 32768, wt + 7 * 32768, b_vp1, out_p, nullptr, NP };

    // --- layer 0 ---
    agg_all<<<nwq + nwp, 256, 0, stream>>>(rp_q, col_q, xb_p, aggb_q, NQ,
                                           rp_p, col_p, xb_q, aggb_p, NP, nwq);
    gemm_both<true, true><<<mq + mp, 256, 0, stream>>>(Sq0, Sp0, mq);

    // --- layer 1 ---
    agg_all<<<nwq + nwp, 256, 0, stream>>>(rp_q, col_q, hb_p, aggb_q, NQ,
                                           rp_p, col_p, hb_q, aggb_p, NP, nwq);
    gemm_both<false, false><<<mq + mp, 256, 0, stream>>>(Sq1, Sp1, mq);
}

// Round 9
// 284.779 us; speedup vs baseline: 3.0146x; 1.2676x over previous
//
#include <hip/hip_runtime.h>

#define D 128
#define PAD 40
#define NBT 256      // max buckets per node type
#define DNMAX 512    // max dsts per bucket
#define GT 32        // dst rows per gather block
#define GCAP 4096    // staged col window cap (ints)

typedef __attribute__((ext_vector_type(8))) short short8;
typedef __attribute__((ext_vector_type(4))) float f32x4;

__device__ __forceinline__ unsigned short f2bf(float x) {
    union { float f; unsigned u; } v; v.f = x;
    unsigned r = v.u + 0x7fff + ((v.u >> 16) & 1);   // RNE
    return (unsigned short)(r >> 16);
}

// ---------------------------------------------------------------------------
// Bucketed CSR build (verified R5/R7)
// ---------------------------------------------------------------------------
__global__ __launch_bounds__(256) void bhist(const int* __restrict__ dst_pv,
                                             const int* __restrict__ dst_vp, int E,
                                             int shq, int shp,
                                             int* __restrict__ bq, int* __restrict__ bp) {
    __shared__ int hq[NBT], hp[NBT];
    int tid = threadIdx.x;
    if (tid < NBT) { hq[tid] = 0; hp[tid] = 0; }
    __syncthreads();
    for (int e = blockIdx.x * 256 + tid; e < E; e += gridDim.x * 256) {
        atomicAdd(&hq[dst_pv[e] >> shq], 1);
        atomicAdd(&hp[dst_vp[e] >> shp], 1);
    }
    __syncthreads();
    if (tid < NBT) {
        if (hq[tid]) atomicAdd(&bq[tid], hq[tid]);
        if (hp[tid]) atomicAdd(&bp[tid], hp[tid]);
    }
}

__global__ __launch_bounds__(128) void bscan(int* __restrict__ bq, int nbq,
                                             int* __restrict__ bp, int nbp,
                                             int* __restrict__ curq, int* __restrict__ curp,
                                             int* __restrict__ rp_q, int nq,
                                             int* __restrict__ rp_p, int np, int E) {
    int wid = threadIdx.x >> 6, lane = threadIdx.x & 63;
    int* seg = wid ? bp : bq;
    int* cur = wid ? curp : curq;
    int nseg = wid ? nbp : nbq;
    int carry = 0;
    for (int base = 0; base < nseg; base += 64) {
        int i = base + lane;
        int v = (i < nseg) ? seg[i] : 0;
        int inc = v;
        #pragma unroll
        for (int off = 1; off < 64; off <<= 1) {
            int t = __shfl_up(inc, off, 64);
            if (lane >= off) inc += t;
        }
        if (i < nseg) { int ex = carry + inc - v; seg[i] = ex; cur[i] = ex; }
        carry += __shfl(inc, 63, 64);
    }
    if (lane == 0) { if (wid == 0) rp_q[nq] = E; else rp_p[np] = E; }
}

__global__ __launch_bounds__(256) void bscatter(const int* __restrict__ src_pv,
                                                const int* __restrict__ dst_pv,
                                                const int* __restrict__ src_vp,
                                                const int* __restrict__ dst_vp, int E,
                                                int* __restrict__ curq, int shq,
                                                int* __restrict__ curp, int shp,
                                                int2* __restrict__ pairs_q,
                                                int2* __restrict__ pairs_p) {
    __shared__ int cq[NBT], baq[NBT], wq[NBT];
    __shared__ int cp_[NBT], bap[NBT], wp_[NBT];
    int tid = threadIdx.x;
    int nblk = gridDim.x;
    int chunk = (E + nblk - 1) / nblk;
    int lo = blockIdx.x * chunk;
    int hi = min(lo + chunk, E);
    if (tid < NBT) { cq[tid] = 0; cp_[tid] = 0; }
    __syncthreads();
    for (int e = lo + tid; e < hi; e += 256) {
        atomicAdd(&cq[dst_pv[e] >> shq], 1);
        atomicAdd(&cp_[dst_vp[e] >> shp], 1);
    }
    __syncthreads();
    if (tid < NBT) {
        baq[tid] = cq[tid]  ? atomicAdd(&curq[tid], cq[tid])  : 0; wq[tid]  = 0;
        bap[tid] = cp_[tid] ? atomicAdd(&curp[tid], cp_[tid]) : 0; wp_[tid] = 0;
    }
    __syncthreads();
    for (int e = lo + tid; e < hi; e += 256) {
        int d = dst_pv[e]; int b = d >> shq;
        int off = atomicAdd(&wq[b], 1);
        pairs_q[baq[b] + off] = make_int2(src_pv[e], d);
        d = dst_vp[e]; b = d >> shp;
        off = atomicAdd(&wp_[b], 1);
        pairs_p[bap[b] + off] = make_int2(src_vp[e], d);
    }
}

__global__ __launch_bounds__(256) void bcsr(const int2* __restrict__ pairs_q,
                                            const int2* __restrict__ pairs_p,
                                            const int* __restrict__ bbq, int nbq,
                                            const int* __restrict__ bbp, int nbp,
                                            int* __restrict__ rp_q, int nq, int shq,
                                            int* __restrict__ rp_p, int np, int shp,
                                            int* __restrict__ col_q, int* __restrict__ col_p,
                                            int E) {
    int b = blockIdx.x;
    const int2* pairs; const int* bb; int* rp; int* colg; int nb, n, sh;
    if (b < nbq) { pairs = pairs_q; bb = bbq; rp = rp_q; colg = col_q; nb = nbq; n = nq; sh = shq; }
    else { b -= nbq; pairs = pairs_p; bb = bbp; rp = rp_p; colg = col_p; nb = nbp; n = np; sh = shp; }
    int base = bb[b];
    int next = (b + 1 < nb) ? bb[b + 1] : E;
    int cnt = next - base;
    int dlo = b << sh;
    int dn  = min(1 << sh, n - dlo);

    __shared__ int deg[DNMAX];
    __shared__ int cur[DNMAX];
    __shared__ int wsum[4];
    int tid = threadIdx.x, lane = tid & 63, wid = tid >> 6;

    for (int i = tid; i < dn; i += 256) deg[i] = 0;
    __syncthreads();
    for (int i = tid; i < cnt; i += 256)
        atomicAdd(&deg[pairs[base + i].y - dlo], 1);
    __syncthreads();

    int t2 = tid * 2;
    int d0 = (t2 < dn) ? deg[t2] : 0;
    int d1 = (t2 + 1 < dn) ? deg[t2 + 1] : 0;
    int s = d0 + d1;
    int inc = s;
    #pragma unroll
    for (int off = 1; off < 64; off <<= 1) {
        int t = __shfl_up(inc, off, 64);
        if (lane >= off) inc += t;
    }
    if (lane == 63) wsum[wid] = inc;
    __syncthreads();
    int wpre = 0;
    for (int w2 = 0; w2 < wid; ++w2) wpre += wsum[w2];
    int ex = wpre + inc - s;
    if (t2 < dn)     { cur[t2] = ex;           rp[dlo + t2] = base + ex; }
    if (t2 + 1 < dn) { cur[t2 + 1] = ex + d0;  rp[dlo + t2 + 1] = base + ex + d0; }
    __syncthreads();

    for (int i = tid; i < cnt; i += 256) {
        int2 e = pairs[base + i];
        int off = atomicAdd(&cur[e.y - dlo], 1);
        colg[base + off] = e.x;
    }
}

// ---------------------------------------------------------------------------
// prep: blocks 0..7 -> W split/transpose; block 8 -> zero bucket counters;
//       blocks 9.. -> f32->bf16 conversion of x_p, x_q
// ---------------------------------------------------------------------------
__global__ __launch_bounds__(256) void prep(const float* W0, const float* W1,
                                            const float* W2, const float* W3,
                                            const float* W4, const float* W5,
                                            const float* W6, const float* W7,
                                            unsigned short* __restrict__ wt,
                                            int* __restrict__ bzero,
                                            const float* __restrict__ xp,
                                            unsigned short* __restrict__ xbp, int np4,
                                            const float* __restrict__ xq,
                                            unsigned short* __restrict__ xbq, int nq4) {
    int blk = blockIdx.x;
    int tid = threadIdx.x;
    if (blk < 8) {
        const float* W;
        switch (blk) {
            case 0: W = W0; break; case 1: W = W1; break;
            case 2: W = W2; break; case 3: W = W3; break;
            case 4: W = W4; break; case 5: W = W5; break;
            case 6: W = W6; break; default: W = W7; break;
        }
        unsigned short* hi = wt + (size_t)blk * 32768;
        unsigned short* lo = hi + 16384;
        for (int i = tid; i < 16384; i += 256) {
            int k = i >> 7, c = i & 127;
            float x = W[i];
            unsigned short h = f2bf(x);
            union { float f; unsigned u; } hv; hv.u = ((unsigned)h) << 16;
            unsigned short l = f2bf(x - hv.f);
            hi[c * 128 + k] = h;
            lo[c * 128 + k] = l;
        }
    } else if (blk == 8) {
        for (int i = tid; i < 2 * NBT; i += 256) bzero[i] = 0;
    } else {
        int tot = np4 + nq4;
        int stride = (gridDim.x - 9) * 256;
        for (int g = (blk - 9) * 256 + tid; g < tot; g += stride) {
            const float* src; unsigned short* dst; int i;
            if (g < np4) { src = xp; dst = xbp; i = g; }
            else         { src = xq; dst = xbq; i = g - np4; }
            float4 v = ((const float4*)src)[i];
            ushort4 o;
            o.x = f2bf(v.x); o.y = f2bf(v.y); o.z = f2bf(v.z); o.w = f2bf(v.w);
            ((ushort4*)dst)[i] = o;
        }
    }
}

// ---------------------------------------------------------------------------
// Tiled gather-mean, bf16 rows. Block = 32 contiguous dst rows.
// Stage rp window + col window in LDS (one coalesced pass), then each wave
// processes rows round-robin. Lane = sub(2b) x chunk(4b): one wave-load
// (uint4 = 8 bf16) fetches 4 neighbor rows at once. Reduce via shfl_xor.
// ---------------------------------------------------------------------------
__global__ __launch_bounds__(256) void agg_all(
    const int* __restrict__ rp_q, const int* __restrict__ col_q,
    const unsigned short* __restrict__ srcq, unsigned short* __restrict__ outq, int nq,
    const int* __restrict__ rp_p, const int* __restrict__ col_p,
    const unsigned short* __restrict__ srcp, unsigned short* __restrict__ outp, int np,
    int ntq) {
    __shared__ int rps[GT + 1];
    __shared__ int cols[GCAP];

    int blk = blockIdx.x;
    const int* rp; const int* col; const unsigned short* src; unsigned short* out; int n, d0;
    if (blk < ntq) { rp = rp_q; col = col_q; src = srcq; out = outq; n = nq; d0 = blk * GT; }
    else { rp = rp_p; col = col_p; src = srcp; out = outp; n = np; d0 = (blk - ntq) * GT; }

    int tid = threadIdx.x;
    int nrow = min(GT, n - d0);
    if (tid <= nrow) rps[tid] = rp[d0 + tid];
    __syncthreads();
    int beg0 = rps[0];
    int cnt = rps[nrow] - beg0;
    bool useLds = cnt <= GCAP;
    if (useLds)
        for (int i = tid; i < cnt; i += 256) cols[i] = col[beg0 + i];
    __syncthreads();

    int wid = tid >> 6, lane = tid & 63;
    int sub = lane >> 4;        // neighbor slot 0..3
    int ch  = lane & 15;        // 16B chunk of the row

    for (int r = wid; r < nrow; r += 4) {
        int beg = rps[r], end = rps[r + 1];
        float a0 = 0.f, a1 = 0.f, a2 = 0.f, a3 = 0.f;
        float a4 = 0.f, a5 = 0.f, a6 = 0.f, a7 = 0.f;
        for (int i = beg; i < end; i += 8) {
            #pragma unroll
            for (int h2 = 0; h2 < 2; ++h2) {
                int j = i + h2 * 4 + sub;
                if (j < end) {   // uniform within a sub-group
                    int s = useLds ? cols[j - beg0] : col[j];
                    uint4 v = *(const uint4*)(src + (size_t)s * D + ch * 8);
                    union { unsigned u; float f; } t;
                    t.u = v.x << 16;         a0 += t.f;
                    t.u = v.x & 0xffff0000u; a1 += t.f;
                    t.u = v.y << 16;         a2 += t.f;
                    t.u = v.y & 0xffff0000u; a3 += t.f;
                    t.u = v.z << 16;         a4 += t.f;
                    t.u = v.z & 0xffff0000u; a5 += t.f;
                    t.u = v.w << 16;         a6 += t.f;
                    t.u = v.w & 0xffff0000u; a7 += t.f;
                }
            }
        }
        #pragma unroll
        for (int off = 16; off <= 32; off <<= 1) {
            a0 += __shfl_xor(a0, off); a1 += __shfl_xor(a1, off);
            a2 += __shfl_xor(a2, off); a3 += __shfl_xor(a3, off);
            a4 += __shfl_xor(a4, off); a5 += __shfl_xor(a5, off);
            a6 += __shfl_xor(a6, off); a7 += __shfl_xor(a7, off);
        }
        int deg = end - beg;
        float inv = (deg > 0) ? 1.0f / (float)deg : 0.f;
        if (sub == 0) {
            uint4 o;
            o.x = (unsigned)f2bf(a0 * inv) | ((unsigned)f2bf(a1 * inv) << 16);
            o.y = (unsigned)f2bf(a2 * inv) | ((unsigned)f2bf(a3 * inv) << 16);
            o.z = (unsigned)f2bf(a4 * inv) | ((unsigned)f2bf(a5 * inv) << 16);
            o.w = (unsigned)f2bf(a6 * inv) | ((unsigned)f2bf(a7 * inv) << 16);
            *(uint4*)(out + (size_t)(d0 + r) * D + ch * 8) = o;
        }
    }
}

// ---------------------------------------------------------------------------
// MFMA dual GEMM body (all-bf16 A, hi/lo split W, 2 MFMAs/k-step) — verified R7
// ---------------------------------------------------------------------------
struct GemmSide {
    const unsigned short* A1;
    const unsigned short* A2;
    const unsigned short* Wt1;
    const unsigned short* Wt2;
    const float* bias;
    float* out;
    unsigned short* hb;
    int n;
};

template <bool RELU, bool WHB>
__device__ __forceinline__ void gemm_body(const GemmSide& S, int bidx) {
    __shared__ unsigned short As[128][PAD];
    __shared__ unsigned short Ws_hi[128][PAD];
    __shared__ unsigned short Ws_lo[128][PAD];

    const int tid  = threadIdx.x;
    const int lane = tid & 63;
    const int w    = tid >> 6;
    const int m0   = bidx * 128;
    const int n    = S.n;

    f32x4 acc[2][8];
    #pragma unroll
    for (int i = 0; i < 2; ++i)
        #pragma unroll
        for (int j = 0; j < 8; ++j) acc[i][j] = (f32x4)0.f;

    const int srow  = tid >> 1;
    const int skoff = (tid & 1) * 16;

    for (int ks = 0; ks < 8; ++ks) {
        const int half = ks >> 2;
        const int kb   = (ks & 3) * 32;
        const unsigned short* A  = half ? S.A2 : S.A1;
        const unsigned short* Wt = half ? S.Wt2 : S.Wt1;

        {
            int grow = m0 + srow;
            if (grow >= n) grow = n - 1;
            const uint4* pa = (const uint4*)(A + (size_t)grow * D + kb + skoff);
            ((uint4*)&As[srow][skoff])[0] = pa[0];
            ((uint4*)&As[srow][skoff])[1] = pa[1];
        }
        {
            const uint4* ph = (const uint4*)(Wt + (size_t)srow * D + kb + skoff);
            ((uint4*)&Ws_hi[srow][skoff])[0] = ph[0];
            ((uint4*)&Ws_hi[srow][skoff])[1] = ph[1];
            const uint4* pl = (const uint4*)(Wt + 16384 + (size_t)srow * D + kb + skoff);
            ((uint4*)&Ws_lo[srow][skoff])[0] = pl[0];
            ((uint4*)&Ws_lo[srow][skoff])[1] = pl[1];
        }
        __syncthreads();

        const int r0 = w * 32;
        const int k8 = (lane >> 4) * 8;
        const int li = lane & 15;

        short8 ah[2];
        #pragma unroll
        for (int m = 0; m < 2; ++m)
            ah[m] = *(const short8*)&As[r0 + m * 16 + li][k8];
        #pragma unroll
        for (int nb = 0; nb < 8; ++nb) {
            int cc = nb * 16 + li;
            short8 bh = *(const short8*)&Ws_hi[cc][k8];
            short8 bl = *(const short8*)&Ws_lo[cc][k8];
            #pragma unroll
            for (int m = 0; m < 2; ++m) {
                acc[m][nb] = __builtin_amdgcn_mfma_f32_16x16x32_bf16(ah[m], bh, acc[m][nb], 0, 0, 0);
                acc[m][nb] = __builtin_amdgcn_mfma_f32_16x16x32_bf16(ah[m], bl, acc[m][nb], 0, 0, 0);
            }
        }
        __syncthreads();
    }

    const int li = lane & 15;
    const int rq = (lane >> 4) * 4;
    float bv[8];
    #pragma unroll
    for (int nb = 0; nb < 8; ++nb) bv[nb] = S.bias[nb * 16 + li];

    #pragma unroll
    for (int m = 0; m < 2; ++m) {
        #pragma unroll
        for (int nb = 0; nb < 8; ++nb) {
            #pragma unroll
            for (int r = 0; r < 4; ++r) {
                int R = m0 + w * 32 + m * 16 + rq + r;
                if (R < n) {
                    int C = nb * 16 + li;
                    float v = acc[m][nb][r] + bv[nb];
                    if (RELU) v = fmaxf(v, 0.f);
                    S.out[(size_t)R * D + C] = v;
                    if (WHB) S.hb[(size_t)R * D + C] = f2bf(v);
                }
            }
        }
    }
}

template <bool RELU, bool WHB>
__global__ __launch_bounds__(256) void gemm_both(GemmSide Sq, GemmSide Sp, int mq) {
    if ((int)blockIdx.x < mq) gemm_body<RELU, WHB>(Sq, blockIdx.x);
    else                      gemm_body<RELU, WHB>(Sp, blockIdx.x - mq);
}

// ---------------------------------------------------------------------------
extern "C" void kernel_launch(void* const* d_in, const int* in_sizes, int n_in,
                              void* d_out, int out_size, void* d_ws, size_t ws_size,
                              hipStream_t stream) {
    const float* x_p = (const float*)d_in[0];
    const float* x_q = (const float*)d_in[1];
    const int* src_pv = (const int*)d_in[2];
    const int* dst_pv = (const int*)d_in[3];
    const int* src_vp = (const int*)d_in[4];
    const int* dst_vp = (const int*)d_in[5];
    const float* Wl_pv0 = (const float*)d_in[6];
    const float* Wr_pv0 = (const float*)d_in[7];
    const float* b_pv0  = (const float*)d_in[8];
    const float* Wl_vp0 = (const float*)d_in[9];
    const float* Wr_vp0 = (const float*)d_in[10];
    const float* b_vp0  = (const float*)d_in[11];
    const float* Wl_pv1 = (const float*)d_in[12];
    const float* Wr_pv1 = (const float*)d_in[13];
    const float* b_pv1  = (const float*)d_in[14];
    const float* Wl_vp1 = (const float*)d_in[15];
    const float* Wr_vp1 = (const float*)d_in[16];
    const float* b_vp1  = (const float*)d_in[17];

    const int NP = in_sizes[0] / D;
    const int NQ = in_sizes[1] / D;
    const int E  = in_sizes[2];

    float* out_p = (float*)d_out;
    float* out_q = out_p + (size_t)NP * D;

    int shq = 6; while ((((NQ - 1) >> shq) + 1) > NBT) ++shq;
    int shp = 6; while ((((NP - 1) >> shp) + 1) > NBT) ++shp;
    int nbq = ((NQ - 1) >> shq) + 1;
    int nbp = ((NP - 1) >> shp) + 1;

    // workspace layout
    char* ws = (char*)d_ws;
    int* rp_q  = (int*)ws;
    int* rp_p  = rp_q + (NQ + 1);
    int* col_q = rp_p + (NP + 1);
    int* col_p = col_q + E;
    int* bq    = col_p + E;
    int* bp    = bq + NBT;
    int* curq  = bp + NBT;
    int* curp  = curq + NBT;
    size_t int_bytes = ((size_t)(NQ + 1) + (NP + 1) + 2 * (size_t)E + 4 * NBT) * sizeof(int);
    int_bytes = (int_bytes + 511) & ~(size_t)511;
    unsigned short* wt = (unsigned short*)(ws + int_bytes);
    size_t wt_bytes = ((size_t)8 * 32768 * sizeof(unsigned short) + 511) & ~(size_t)511;
    unsigned short* xb_p = (unsigned short*)(ws + int_bytes + wt_bytes);
    unsigned short* xb_q = xb_p + (size_t)NP * D;
    unsigned short* hb_p = xb_p;
    unsigned short* hb_q = xb_q;
    unsigned short* aggb_q = xb_q + (size_t)NQ * D;
    unsigned short* aggb_p = aggb_q + (size_t)NQ * D;
    int2* pairs_q = (int2*)aggb_q;
    int2* pairs_p = pairs_q + E;

    // --- prep (W split, bucket zero, x->bf16) ---
    prep<<<9 + 2048, 256, 0, stream>>>(Wl_pv0, Wr_pv0, Wl_vp0, Wr_vp0,
                                       Wl_pv1, Wr_pv1, Wl_vp1, Wr_vp1, wt,
                                       bq, x_p, xb_p, NP * D / 4, x_q, xb_q, NQ * D / 4);

    // --- CSR build ---
    bhist<<<256, 256, 0, stream>>>(dst_pv, dst_vp, E, shq, shp, bq, bp);
    bscan<<<1, 128, 0, stream>>>(bq, nbq, bp, nbp, curq, curp, rp_q, NQ, rp_p, NP, E);
    bscatter<<<512, 256, 0, stream>>>(src_pv, dst_pv, src_vp, dst_vp, E,
                                      curq, shq, curp, shp, pairs_q, pairs_p);
    bcsr<<<nbq + nbp, 256, 0, stream>>>(pairs_q, pairs_p, bq, nbq, bp, nbp,
                                        rp_q, NQ, shq, rp_p, NP, shp, col_q, col_p, E);

    int ntq = (NQ + GT - 1) / GT, ntp = (NP + GT - 1) / GT;
    int mq = (NQ + 127) / 128, mp = (NP + 127) / 128;

    GemmSide Sq0 = { aggb_q, xb_q, wt + 0 * 32768, wt + 1 * 32768, b_pv0, out_q, hb_q, NQ };
    GemmSide Sp0 = { aggb_p, xb_p, wt + 2 * 32768, wt + 3 * 32768, b_vp0, out_p, hb_p, NP };
    GemmSide Sq1 = { aggb_q, hb_q, wt + 4 * 32768, wt + 5 * 32768, b_pv1, out_q, nullptr, NQ };
    GemmSide Sp1 = { aggb_p, hb_p, wt + 6 * 32768, wt + 7 * 32768, b_vp1, out_p, nullptr, NP };

    // --- layer 0 ---
    agg_all<<<ntq + ntp, 256, 0, stream>>>(rp_q, col_q, xb_p, aggb_q, NQ,
                                           rp_p, col_p, xb_q, aggb_p, NP, ntq);
    gemm_both<true, true><<<mq + mp, 256, 0, stream>>>(Sq0, Sp0, mq);

    // --- layer 1 ---
    agg_all<<<ntq + ntp, 256, 0, stream>>>(rp_q, col_q, hb_p, aggb_q, NQ,
                                           rp_p, col_p, hb_q, aggb_p, NP, ntq);
    gemm_both<false, false><<<mq + mp, 256, 0, stream>>>(Sq1, Sp1, mq);
}

// Round 10
// 266.708 us; speedup vs baseline: 3.2189x; 1.0678x over previous
//
#include <hip/hip_runtime.h>

#define D 128
#define PAD 40
#define NBT 256      // max buckets per node type
#define DNMAX 512    // max dsts per bucket
#define GT 32        // dst rows per gather block
#define GCAP 4096    // staged col window cap (ints)

typedef __attribute__((ext_vector_type(8))) short short8;
typedef __attribute__((ext_vector_type(4))) float f32x4;

__device__ __forceinline__ unsigned short f2bf(float x) {
    union { float f; unsigned u; } v; v.f = x;
    unsigned r = v.u + 0x7fff + ((v.u >> 16) & 1);   // RNE
    return (unsigned short)(r >> 16);
}

// ---------------------------------------------------------------------------
// Bucketed CSR build (verified R5/R7)
// ---------------------------------------------------------------------------
__global__ __launch_bounds__(256) void bhist(const int* __restrict__ dst_pv,
                                             const int* __restrict__ dst_vp, int E,
                                             int shq, int shp,
                                             int* __restrict__ bq, int* __restrict__ bp) {
    __shared__ int hq[NBT], hp[NBT];
    int tid = threadIdx.x;
    if (tid < NBT) { hq[tid] = 0; hp[tid] = 0; }
    __syncthreads();
    for (int e = blockIdx.x * 256 + tid; e < E; e += gridDim.x * 256) {
        atomicAdd(&hq[dst_pv[e] >> shq], 1);
        atomicAdd(&hp[dst_vp[e] >> shp], 1);
    }
    __syncthreads();
    if (tid < NBT) {
        if (hq[tid]) atomicAdd(&bq[tid], hq[tid]);
        if (hp[tid]) atomicAdd(&bp[tid], hp[tid]);
    }
}

__global__ __launch_bounds__(128) void bscan(int* __restrict__ bq, int nbq,
                                             int* __restrict__ bp, int nbp,
                                             int* __restrict__ curq, int* __restrict__ curp,
                                             int* __restrict__ rp_q, int nq,
                                             int* __restrict__ rp_p, int np, int E) {
    int wid = threadIdx.x >> 6, lane = threadIdx.x & 63;
    int* seg = wid ? bp : bq;
    int* cur = wid ? curp : curq;
    int nseg = wid ? nbp : nbq;
    int carry = 0;
    for (int base = 0; base < nseg; base += 64) {
        int i = base + lane;
        int v = (i < nseg) ? seg[i] : 0;
        int inc = v;
        #pragma unroll
        for (int off = 1; off < 64; off <<= 1) {
            int t = __shfl_up(inc, off, 64);
            if (lane >= off) inc += t;
        }
        if (i < nseg) { int ex = carry + inc - v; seg[i] = ex; cur[i] = ex; }
        carry += __shfl(inc, 63, 64);
    }
    if (lane == 0) { if (wid == 0) rp_q[nq] = E; else rp_p[np] = E; }
}

__global__ __launch_bounds__(256) void bscatter(const int* __restrict__ src_pv,
                                                const int* __restrict__ dst_pv,
                                                const int* __restrict__ src_vp,
                                                const int* __restrict__ dst_vp, int E,
                                                int* __restrict__ curq, int shq,
                                                int* __restrict__ curp, int shp,
                                                int2* __restrict__ pairs_q,
                                                int2* __restrict__ pairs_p) {
    __shared__ int cq[NBT], baq[NBT], wq[NBT];
    __shared__ int cp_[NBT], bap[NBT], wp_[NBT];
    int tid = threadIdx.x;
    int nblk = gridDim.x;
    int chunk = (E + nblk - 1) / nblk;
    int lo = blockIdx.x * chunk;
    int hi = min(lo + chunk, E);
    if (tid < NBT) { cq[tid] = 0; cp_[tid] = 0; }
    __syncthreads();
    for (int e = lo + tid; e < hi; e += 256) {
        atomicAdd(&cq[dst_pv[e] >> shq], 1);
        atomicAdd(&cp_[dst_vp[e] >> shp], 1);
    }
    __syncthreads();
    if (tid < NBT) {
        baq[tid] = cq[tid]  ? atomicAdd(&curq[tid], cq[tid])  : 0; wq[tid]  = 0;
        bap[tid] = cp_[tid] ? atomicAdd(&curp[tid], cp_[tid]) : 0; wp_[tid] = 0;
    }
    __syncthreads();
    for (int e = lo + tid; e < hi; e += 256) {
        int d = dst_pv[e]; int b = d >> shq;
        int off = atomicAdd(&wq[b], 1);
        pairs_q[baq[b] + off] = make_int2(src_pv[e], d);
        d = dst_vp[e]; b = d >> shp;
        off = atomicAdd(&wp_[b], 1);
        pairs_p[bap[b] + off] = make_int2(src_vp[e], d);
    }
}

__global__ __launch_bounds__(256) void bcsr(const int2* __restrict__ pairs_q,
                                            const int2* __restrict__ pairs_p,
                                            const int* __restrict__ bbq, int nbq,
                                            const int* __restrict__ bbp, int nbp,
                                            int* __restrict__ rp_q, int nq, int shq,
                                            int* __restrict__ rp_p, int np, int shp,
                                            int* __restrict__ col_q, int* __restrict__ col_p,
                                            int E) {
    int b = blockIdx.x;
    const int2* pairs; const int* bb; int* rp; int* colg; int nb, n, sh;
    if (b < nbq) { pairs = pairs_q; bb = bbq; rp = rp_q; colg = col_q; nb = nbq; n = nq; sh = shq; }
    else { b -= nbq; pairs = pairs_p; bb = bbp; rp = rp_p; colg = col_p; nb = nbp; n = np; sh = shp; }
    int base = bb[b];
    int next = (b + 1 < nb) ? bb[b + 1] : E;
    int cnt = next - base;
    int dlo = b << sh;
    int dn  = min(1 << sh, n - dlo);

    __shared__ int deg[DNMAX];
    __shared__ int cur[DNMAX];
    __shared__ int wsum[4];
    int tid = threadIdx.x, lane = tid & 63, wid = tid >> 6;

    for (int i = tid; i < dn; i += 256) deg[i] = 0;
    __syncthreads();
    for (int i = tid; i < cnt; i += 256)
        atomicAdd(&deg[pairs[base + i].y - dlo], 1);
    __syncthreads();

    int t2 = tid * 2;
    int d0 = (t2 < dn) ? deg[t2] : 0;
    int d1 = (t2 + 1 < dn) ? deg[t2 + 1] : 0;
    int s = d0 + d1;
    int inc = s;
    #pragma unroll
    for (int off = 1; off < 64; off <<= 1) {
        int t = __shfl_up(inc, off, 64);
        if (lane >= off) inc += t;
    }
    if (lane == 63) wsum[wid] = inc;
    __syncthreads();
    int wpre = 0;
    for (int w2 = 0; w2 < wid; ++w2) wpre += wsum[w2];
    int ex = wpre + inc - s;
    if (t2 < dn)     { cur[t2] = ex;           rp[dlo + t2] = base + ex; }
    if (t2 + 1 < dn) { cur[t2 + 1] = ex + d0;  rp[dlo + t2 + 1] = base + ex + d0; }
    __syncthreads();

    for (int i = tid; i < cnt; i += 256) {
        int2 e = pairs[base + i];
        int off = atomicAdd(&cur[e.y - dlo], 1);
        colg[base + off] = e.x;
    }
}

// ---------------------------------------------------------------------------
// prep: blocks 0..63  -> W split/transpose (8 blocks per matrix, 16 cols each,
//                        LDS transpose, coalesced uint4 writes)
//       block 64      -> zero bucket counters
//       blocks 65..   -> f32->bf16 conversion of x_p, x_q
// ---------------------------------------------------------------------------
__global__ __launch_bounds__(256) void prep(const float* W0, const float* W1,
                                            const float* W2, const float* W3,
                                            const float* W4, const float* W5,
                                            const float* W6, const float* W7,
                                            unsigned short* __restrict__ wt,
                                            int* __restrict__ bzero,
                                            const float* __restrict__ xp,
                                            unsigned short* __restrict__ xbp, int np4,
                                            const float* __restrict__ xq,
                                            unsigned short* __restrict__ xbq, int nq4) {
    int blk = blockIdx.x;
    int tid = threadIdx.x;
    if (blk < 64) {
        int m = blk >> 3;
        int c0 = (blk & 7) * 16;
        const float* W;
        switch (m) {
            case 0: W = W0; break; case 1: W = W1; break;
            case 2: W = W2; break; case 3: W = W3; break;
            case 4: W = W4; break; case 5: W = W5; break;
            case 6: W = W6; break; default: W = W7; break;
        }
        unsigned short* hi = wt + (size_t)m * 32768;
        unsigned short* lo = hi + 16384;

        __shared__ unsigned short his[16][136];
        __shared__ unsigned short los[16][136];
        int cc = tid & 15;
        int kk = tid >> 4;      // 0..15
        #pragma unroll
        for (int g = 0; g < 8; ++g) {
            int k = g * 16 + kk;
            float x = W[k * 128 + c0 + cc];
            unsigned short h = f2bf(x);
            union { float f; unsigned u; } hv; hv.u = ((unsigned)h) << 16;
            his[cc][k] = h;
            los[cc][k] = f2bf(x - hv.f);
        }
        __syncthreads();
        int cidx = tid >> 4;          // 0..15 -> col
        int k8   = (tid & 15) * 8;    // 0..120
        int c = c0 + cidx;
        uint4 vh, vl;
        #pragma unroll
        for (int j = 0; j < 4; ++j) {
            ((unsigned*)&vh)[j] = *(const unsigned*)&his[cidx][k8 + j * 2];
            ((unsigned*)&vl)[j] = *(const unsigned*)&los[cidx][k8 + j * 2];
        }
        *(uint4*)(hi + (size_t)c * 128 + k8) = vh;
        *(uint4*)(lo + (size_t)c * 128 + k8) = vl;
    } else if (blk == 64) {
        for (int i = tid; i < 2 * NBT; i += 256) bzero[i] = 0;
    } else {
        int tot = np4 + nq4;
        int stride = (gridDim.x - 65) * 256;
        for (int g = (blk - 65) * 256 + tid; g < tot; g += stride) {
            const float* src; unsigned short* dst; int i;
            if (g < np4) { src = xp; dst = xbp; i = g; }
            else         { src = xq; dst = xbq; i = g - np4; }
            float4 v = ((const float4*)src)[i];
            ushort4 o;
            o.x = f2bf(v.x); o.y = f2bf(v.y); o.z = f2bf(v.z); o.w = f2bf(v.w);
            ((ushort4*)dst)[i] = o;
        }
    }
}

// ---------------------------------------------------------------------------
// Tiled gather-mean, bf16 rows (verified R9)
// ---------------------------------------------------------------------------
__global__ __launch_bounds__(256) void agg_all(
    const int* __restrict__ rp_q, const int* __restrict__ col_q,
    const unsigned short* __restrict__ srcq, unsigned short* __restrict__ outq, int nq,
    const int* __restrict__ rp_p, const int* __restrict__ col_p,
    const unsigned short* __restrict__ srcp, unsigned short* __restrict__ outp, int np,
    int ntq) {
    __shared__ int rps[GT + 1];
    __shared__ int cols[GCAP];

    int blk = blockIdx.x;
    const int* rp; const int* col; const unsigned short* src; unsigned short* out; int n, d0;
    if (blk < ntq) { rp = rp_q; col = col_q; src = srcq; out = outq; n = nq; d0 = blk * GT; }
    else { rp = rp_p; col = col_p; src = srcp; out = outp; n = np; d0 = (blk - ntq) * GT; }

    int tid = threadIdx.x;
    int nrow = min(GT, n - d0);
    if (tid <= nrow) rps[tid] = rp[d0 + tid];
    __syncthreads();
    int beg0 = rps[0];
    int cnt = rps[nrow] - beg0;
    bool useLds = cnt <= GCAP;
    if (useLds)
        for (int i = tid; i < cnt; i += 256) cols[i] = col[beg0 + i];
    __syncthreads();

    int wid = tid >> 6, lane = tid & 63;
    int sub = lane >> 4;
    int ch  = lane & 15;

    for (int r = wid; r < nrow; r += 4) {
        int beg = rps[r], end = rps[r + 1];
        float a0 = 0.f, a1 = 0.f, a2 = 0.f, a3 = 0.f;
        float a4 = 0.f, a5 = 0.f, a6 = 0.f, a7 = 0.f;
        for (int i = beg; i < end; i += 8) {
            #pragma unroll
            for (int h2 = 0; h2 < 2; ++h2) {
                int j = i + h2 * 4 + sub;
                if (j < end) {
                    int s = useLds ? cols[j - beg0] : col[j];
                    uint4 v = *(const uint4*)(src + (size_t)s * D + ch * 8);
                    union { unsigned u; float f; } t;
                    t.u = v.x << 16;         a0 += t.f;
                    t.u = v.x & 0xffff0000u; a1 += t.f;
                    t.u = v.y << 16;         a2 += t.f;
                    t.u = v.y & 0xffff0000u; a3 += t.f;
                    t.u = v.z << 16;         a4 += t.f;
                    t.u = v.z & 0xffff0000u; a5 += t.f;
                    t.u = v.w << 16;         a6 += t.f;
                    t.u = v.w & 0xffff0000u; a7 += t.f;
                }
            }
        }
        #pragma unroll
        for (int off = 16; off <= 32; off <<= 1) {
            a0 += __shfl_xor(a0, off); a1 += __shfl_xor(a1, off);
            a2 += __shfl_xor(a2, off); a3 += __shfl_xor(a3, off);
            a4 += __shfl_xor(a4, off); a5 += __shfl_xor(a5, off);
            a6 += __shfl_xor(a6, off); a7 += __shfl_xor(a7, off);
        }
        int deg = end - beg;
        float inv = (deg > 0) ? 1.0f / (float)deg : 0.f;
        if (sub == 0) {
            uint4 o;
            o.x = (unsigned)f2bf(a0 * inv) | ((unsigned)f2bf(a1 * inv) << 16);
            o.y = (unsigned)f2bf(a2 * inv) | ((unsigned)f2bf(a3 * inv) << 16);
            o.z = (unsigned)f2bf(a4 * inv) | ((unsigned)f2bf(a5 * inv) << 16);
            o.w = (unsigned)f2bf(a6 * inv) | ((unsigned)f2bf(a7 * inv) << 16);
            *(uint4*)(out + (size_t)(d0 + r) * D + ch * 8) = o;
        }
    }
}

// ---------------------------------------------------------------------------
// MFMA dual GEMM body (all-bf16 A, hi/lo split W, 2 MFMAs/k-step) — verified R7
// ---------------------------------------------------------------------------
struct GemmSide {
    const unsigned short* A1;
    const unsigned short* A2;
    const unsigned short* Wt1;
    const unsigned short* Wt2;
    const float* bias;
    float* out;
    unsigned short* hb;
    int n;
};

template <bool RELU, bool WHB>
__device__ __forceinline__ void gemm_body(const GemmSide& S, int bidx) {
    __shared__ unsigned short As[128][PAD];
    __shared__ unsigned short Ws_hi[128][PAD];
    __shared__ unsigned short Ws_lo[128][PAD];

    const int tid  = threadIdx.x;
    const int lane = tid & 63;
    const int w    = tid >> 6;
    const int m0   = bidx * 128;
    const int n    = S.n;

    f32x4 acc[2][8];
    #pragma unroll
    for (int i = 0; i < 2; ++i)
        #pragma unroll
        for (int j = 0; j < 8; ++j) acc[i][j] = (f32x4)0.f;

    const int srow  = tid >> 1;
    const int skoff = (tid & 1) * 16;

    for (int ks = 0; ks < 8; ++ks) {
        const int half = ks >> 2;
        const int kb   = (ks & 3) * 32;
        const unsigned short* A  = half ? S.A2 : S.A1;
        const unsigned short* Wt = half ? S.Wt2 : S.Wt1;

        {
            int grow = m0 + srow;
            if (grow >= n) grow = n - 1;
            const uint4* pa = (const uint4*)(A + (size_t)grow * D + kb + skoff);
            ((uint4*)&As[srow][skoff])[0] = pa[0];
            ((uint4*)&As[srow][skoff])[1] = pa[1];
        }
        {
            const uint4* ph = (const uint4*)(Wt + (size_t)srow * D + kb + skoff);
            ((uint4*)&Ws_hi[srow][skoff])[0] = ph[0];
            ((uint4*)&Ws_hi[srow][skoff])[1] = ph[1];
            const uint4* pl = (const uint4*)(Wt + 16384 + (size_t)srow * D + kb + skoff);
            ((uint4*)&Ws_lo[srow][skoff])[0] = pl[0];
            ((uint4*)&Ws_lo[srow][skoff])[1] = pl[1];
        }
        __syncthreads();

        const int r0 = w * 32;
        const int k8 = (lane >> 4) * 8;
        const int li = lane & 15;

        short8 ah[2];
        #pragma unroll
        for (int m = 0; m < 2; ++m)
            ah[m] = *(const short8*)&As[r0 + m * 16 + li][k8];
        #pragma unroll
        for (int nb = 0; nb < 8; ++nb) {
            int cc = nb * 16 + li;
            short8 bh = *(const short8*)&Ws_hi[cc][k8];
            short8 bl = *(const short8*)&Ws_lo[cc][k8];
            #pragma unroll
            for (int m = 0; m < 2; ++m) {
                acc[m][nb] = __builtin_amdgcn_mfma_f32_16x16x32_bf16(ah[m], bh, acc[m][nb], 0, 0, 0);
                acc[m][nb] = __builtin_amdgcn_mfma_f32_16x16x32_bf16(ah[m], bl, acc[m][nb], 0, 0, 0);
            }
        }
        __syncthreads();
    }

    const int li = lane & 15;
    const int rq = (lane >> 4) * 4;
    float bv[8];
    #pragma unroll
    for (int nb = 0; nb < 8; ++nb) bv[nb] = S.bias[nb * 16 + li];

    #pragma unroll
    for (int m = 0; m < 2; ++m) {
        #pragma unroll
        for (int nb = 0; nb < 8; ++nb) {
            #pragma unroll
            for (int r = 0; r < 4; ++r) {
                int R = m0 + w * 32 + m * 16 + rq + r;
                if (R < n) {
                    int C = nb * 16 + li;
                    float v = acc[m][nb][r] + bv[nb];
                    if (RELU) v = fmaxf(v, 0.f);
                    S.out[(size_t)R * D + C] = v;
                    if (WHB) S.hb[(size_t)R * D + C] = f2bf(v);
                }
            }
        }
    }
}

template <bool RELU, bool WHB>
__global__ __launch_bounds__(256) void gemm_both(GemmSide Sq, GemmSide Sp, int mq) {
    if ((int)blockIdx.x < mq) gemm_body<RELU, WHB>(Sq, blockIdx.x);
    else                      gemm_body<RELU, WHB>(Sp, blockIdx.x - mq);
}

// ---------------------------------------------------------------------------
extern "C" void kernel_launch(void* const* d_in, const int* in_sizes, int n_in,
                              void* d_out, int out_size, void* d_ws, size_t ws_size,
                              hipStream_t stream) {
    const float* x_p = (const float*)d_in[0];
    const float* x_q = (const float*)d_in[1];
    const int* src_pv = (const int*)d_in[2];
    const int* dst_pv = (const int*)d_in[3];
    const int* src_vp = (const int*)d_in[4];
    const int* dst_vp = (const int*)d_in[5];
    const float* Wl_pv0 = (const float*)d_in[6];
    const float* Wr_pv0 = (const float*)d_in[7];
    const float* b_pv0  = (const float*)d_in[8];
    const float* Wl_vp0 = (const float*)d_in[9];
    const float* Wr_vp0 = (const float*)d_in[10];
    const float* b_vp0  = (const float*)d_in[11];
    const float* Wl_pv1 = (const float*)d_in[12];
    const float* Wr_pv1 = (const float*)d_in[13];
    const float* b_pv1  = (const float*)d_in[14];
    const float* Wl_vp1 = (const float*)d_in[15];
    const float* Wr_vp1 = (const float*)d_in[16];
    const float* b_vp1  = (const float*)d_in[17];

    const int NP = in_sizes[0] / D;
    const int NQ = in_sizes[1] / D;
    const int E  = in_sizes[2];

    float* out_p = (float*)d_out;
    float* out_q = out_p + (size_t)NP * D;

    int shq = 6; while ((((NQ - 1) >> shq) + 1) > NBT) ++shq;
    int shp = 6; while ((((NP - 1) >> shp) + 1) > NBT) ++shp;
    int nbq = ((NQ - 1) >> shq) + 1;
    int nbp = ((NP - 1) >> shp) + 1;

    // workspace layout
    char* ws = (char*)d_ws;
    int* rp_q  = (int*)ws;
    int* rp_p  = rp_q + (NQ + 1);
    int* col_q = rp_p + (NP + 1);
    int* col_p = col_q + E;
    int* bq    = col_p + E;
    int* bp    = bq + NBT;
    int* curq  = bp + NBT;
    int* curp  = curq + NBT;
    size_t int_bytes = ((size_t)(NQ + 1) + (NP + 1) + 2 * (size_t)E + 4 * NBT) * sizeof(int);
    int_bytes = (int_bytes + 511) & ~(size_t)511;
    unsigned short* wt = (unsigned short*)(ws + int_bytes);
    size_t wt_bytes = ((size_t)8 * 32768 * sizeof(unsigned short) + 511) & ~(size_t)511;
    unsigned short* xb_p = (unsigned short*)(ws + int_bytes + wt_bytes);
    unsigned short* xb_q = xb_p + (size_t)NP * D;
    unsigned short* hb_p = xb_p;
    unsigned short* hb_q = xb_q;
    unsigned short* aggb_q = xb_q + (size_t)NQ * D;
    unsigned short* aggb_p = aggb_q + (size_t)NQ * D;
    int2* pairs_q = (int2*)aggb_q;
    int2* pairs_p = pairs_q + E;

    // --- prep (W split, bucket zero, x->bf16) ---
    prep<<<65 + 2048, 256, 0, stream>>>(Wl_pv0, Wr_pv0, Wl_vp0, Wr_vp0,
                                        Wl_pv1, Wr_pv1, Wl_vp1, Wr_vp1, wt,
                                        bq, x_p, xb_p, NP * D / 4, x_q, xb_q, NQ * D / 4);

    // --- CSR build ---
    bhist<<<256, 256, 0, stream>>>(dst_pv, dst_vp, E, shq, shp, bq, bp);
    bscan<<<1, 128, 0, stream>>>(bq, nbq, bp, nbp, curq, curp, rp_q, NQ, rp_p, NP, E);
    bscatter<<<512, 256, 0, stream>>>(src_pv, dst_pv, src_vp, dst_vp, E,
                                      curq, shq, curp, shp, pairs_q, pairs_p);
    bcsr<<<nbq + nbp, 256, 0, stream>>>(pairs_q, pairs_p, bq, nbq, bp, nbp,
                                        rp_q, NQ, shq, rp_p, NP, shp, col_q, col_p, E);

    int ntq = (NQ + GT - 1) / GT, ntp = (NP + GT - 1) / GT;
    int mq = (NQ + 127) / 128, mp = (NP + 127) / 128;

    GemmSide Sq0 = { aggb_q, xb_q, wt + 0 * 32768, wt + 1 * 32768, b_pv0, out_q, hb_q, NQ };
    GemmSide Sp0 = { aggb_p, xb_p, wt + 2 * 32768, wt + 3 * 32768, b_vp0, out_p, hb_p, NP };
    GemmSide Sq1 = { aggb_q, hb_q, wt + 4 * 32768, wt + 5 * 32768, b_pv1, out_q, nullptr, NQ };
    GemmSide Sp1 = { aggb_p, hb_p, wt + 6 * 32768, wt + 7 * 32768, b_vp1, out_p, nullptr, NP };

    // --- layer 0 ---
    agg_all<<<ntq + ntp, 256, 0, stream>>>(rp_q, col_q, xb_p, aggb_q, NQ,
                                           rp_p, col_p, xb_q, aggb_p, NP, ntq);
    gemm_both<true, true><<<mq + mp, 256, 0, stream>>>(Sq0, Sp0, mq);

    // --- layer 1 ---
    agg_all<<<ntq + ntp, 256, 0, stream>>>(rp_q, col_q, hb_p, aggb_q, NQ,
                                           rp_p, col_p, hb_q, aggb_p, NP, ntq);
    gemm_both<false, false><<<mq + mp, 256, 0, stream>>>(Sq1, Sp1, mq);
}

// Round 11
// 251.586 us; speedup vs baseline: 3.4123x; 1.0601x over previous
//
#include <hip/hip_runtime.h>

#define D 128
#define PAD 40
#define NBT 256      // max buckets per node type
#define DNMAX 512    // max dsts per bucket
#define GT 32        // dst rows per gather block
#define GCAP 4096    // staged col window cap (ints)

typedef __attribute__((ext_vector_type(8))) short short8;
typedef __attribute__((ext_vector_type(4))) float f32x4;

__device__ __forceinline__ unsigned short f2bf(float x) {
    union { float f; unsigned u; } v; v.f = x;
    unsigned r = v.u + 0x7fff + ((v.u >> 16) & 1);   // RNE
    return (unsigned short)(r >> 16);
}

// ---------------------------------------------------------------------------
// prep_hist: blocks 0..63    -> W split/transpose (LDS transpose, coalesced)
//            blocks 64..319  -> bucket histogram (bq/bp pre-zeroed by memset)
//            blocks 320..    -> f32->bf16 conversion of x_p, x_q
// ---------------------------------------------------------------------------
__global__ __launch_bounds__(256) void prep_hist(
    const float* W0, const float* W1, const float* W2, const float* W3,
    const float* W4, const float* W5, const float* W6, const float* W7,
    unsigned short* __restrict__ wt,
    const int* __restrict__ dst_pv, const int* __restrict__ dst_vp, int E,
    int shq, int shp, int* __restrict__ bq, int* __restrict__ bp,
    const float* __restrict__ xp, unsigned short* __restrict__ xbp, int np4,
    const float* __restrict__ xq, unsigned short* __restrict__ xbq, int nq4) {
    int blk = blockIdx.x;
    int tid = threadIdx.x;
    if (blk < 64) {
        int m = blk >> 3;
        int c0 = (blk & 7) * 16;
        const float* W;
        switch (m) {
            case 0: W = W0; break; case 1: W = W1; break;
            case 2: W = W2; break; case 3: W = W3; break;
            case 4: W = W4; break; case 5: W = W5; break;
            case 6: W = W6; break; default: W = W7; break;
        }
        unsigned short* hi = wt + (size_t)m * 32768;
        unsigned short* lo = hi + 16384;

        __shared__ unsigned short his[16][136];
        __shared__ unsigned short los[16][136];
        int cc = tid & 15;
        int kk = tid >> 4;
        #pragma unroll
        for (int g = 0; g < 8; ++g) {
            int k = g * 16 + kk;
            float x = W[k * 128 + c0 + cc];
            unsigned short h = f2bf(x);
            union { float f; unsigned u; } hv; hv.u = ((unsigned)h) << 16;
            his[cc][k] = h;
            los[cc][k] = f2bf(x - hv.f);
        }
        __syncthreads();
        int cidx = tid >> 4;
        int k8   = (tid & 15) * 8;
        int c = c0 + cidx;
        uint4 vh, vl;
        #pragma unroll
        for (int j = 0; j < 4; ++j) {
            ((unsigned*)&vh)[j] = *(const unsigned*)&his[cidx][k8 + j * 2];
            ((unsigned*)&vl)[j] = *(const unsigned*)&los[cidx][k8 + j * 2];
        }
        *(uint4*)(hi + (size_t)c * 128 + k8) = vh;
        *(uint4*)(lo + (size_t)c * 128 + k8) = vl;
    } else if (blk < 320) {
        __shared__ int hq[NBT], hp[NBT];
        if (tid < NBT) { hq[tid] = 0; hp[tid] = 0; }
        __syncthreads();
        for (int e = (blk - 64) * 256 + tid; e < E; e += 256 * 256) {
            atomicAdd(&hq[dst_pv[e] >> shq], 1);
            atomicAdd(&hp[dst_vp[e] >> shp], 1);
        }
        __syncthreads();
        if (tid < NBT) {
            if (hq[tid]) atomicAdd(&bq[tid], hq[tid]);
            if (hp[tid]) atomicAdd(&bp[tid], hp[tid]);
        }
    } else {
        int tot = np4 + nq4;
        int stride = (gridDim.x - 320) * 256;
        for (int g = (blk - 320) * 256 + tid; g < tot; g += stride) {
            const float* src; unsigned short* dst; int i;
            if (g < np4) { src = xp; dst = xbp; i = g; }
            else         { src = xq; dst = xbq; i = g - np4; }
            float4 v = ((const float4*)src)[i];
            ushort4 o;
            o.x = f2bf(v.x); o.y = f2bf(v.y); o.z = f2bf(v.z); o.w = f2bf(v.w);
            ((ushort4*)dst)[i] = o;
        }
    }
}

__global__ __launch_bounds__(128) void bscan(int* __restrict__ bq, int nbq,
                                             int* __restrict__ bp, int nbp,
                                             int* __restrict__ curq, int* __restrict__ curp,
                                             int* __restrict__ rp_q, int nq,
                                             int* __restrict__ rp_p, int np, int E) {
    int wid = threadIdx.x >> 6, lane = threadIdx.x & 63;
    int* seg = wid ? bp : bq;
    int* cur = wid ? curp : curq;
    int nseg = wid ? nbp : nbq;
    int carry = 0;
    for (int base = 0; base < nseg; base += 64) {
        int i = base + lane;
        int v = (i < nseg) ? seg[i] : 0;
        int inc = v;
        #pragma unroll
        for (int off = 1; off < 64; off <<= 1) {
            int t = __shfl_up(inc, off, 64);
            if (lane >= off) inc += t;
        }
        if (i < nseg) { int ex = carry + inc - v; seg[i] = ex; cur[i] = ex; }
        carry += __shfl(inc, 63, 64);
    }
    if (lane == 0) { if (wid == 0) rp_q[nq] = E; else rp_p[np] = E; }
}

// Block-batched scatter of packed (src<<sh | local_dst) into bucket order.
__global__ __launch_bounds__(256) void bscatter(const int* __restrict__ src_pv,
                                                const int* __restrict__ dst_pv,
                                                const int* __restrict__ src_vp,
                                                const int* __restrict__ dst_vp, int E,
                                                int* __restrict__ curq, int shq,
                                                int* __restrict__ curp, int shp,
                                                unsigned* __restrict__ pk_q,
                                                unsigned* __restrict__ pk_p) {
    __shared__ int cq[NBT], baq[NBT], wq[NBT];
    __shared__ int cp_[NBT], bap[NBT], wp_[NBT];
    int tid = threadIdx.x;
    int nblk = gridDim.x;
    int chunk = (E + nblk - 1) / nblk;
    int lo = blockIdx.x * chunk;
    int hi = min(lo + chunk, E);
    unsigned mkq = (1u << shq) - 1, mkp = (1u << shp) - 1;
    if (tid < NBT) { cq[tid] = 0; cp_[tid] = 0; }
    __syncthreads();
    for (int e = lo + tid; e < hi; e += 256) {
        atomicAdd(&cq[dst_pv[e] >> shq], 1);
        atomicAdd(&cp_[dst_vp[e] >> shp], 1);
    }
    __syncthreads();
    if (tid < NBT) {
        baq[tid] = cq[tid]  ? atomicAdd(&curq[tid], cq[tid])  : 0; wq[tid]  = 0;
        bap[tid] = cp_[tid] ? atomicAdd(&curp[tid], cp_[tid]) : 0; wp_[tid] = 0;
    }
    __syncthreads();
    for (int e = lo + tid; e < hi; e += 256) {
        int d = dst_pv[e]; int b = d >> shq;
        int off = atomicAdd(&wq[b], 1);
        pk_q[baq[b] + off] = ((unsigned)src_pv[e] << shq) | ((unsigned)d & mkq);
        d = dst_vp[e]; b = d >> shp;
        off = atomicAdd(&wp_[b], 1);
        pk_p[bap[b] + off] = ((unsigned)src_vp[e] << shp) | ((unsigned)d & mkp);
    }
}

// Per-bucket local CSR from packed entries.
__global__ __launch_bounds__(256) void bcsr(const unsigned* __restrict__ pk_q,
                                            const unsigned* __restrict__ pk_p,
                                            const int* __restrict__ bbq, int nbq,
                                            const int* __restrict__ bbp, int nbp,
                                            int* __restrict__ rp_q, int nq, int shq,
                                            int* __restrict__ rp_p, int np, int shp,
                                            int* __restrict__ col_q, int* __restrict__ col_p,
                                            int E) {
    int b = blockIdx.x;
    const unsigned* pk; const int* bb; int* rp; int* colg; int nb, n, sh;
    if (b < nbq) { pk = pk_q; bb = bbq; rp = rp_q; colg = col_q; nb = nbq; n = nq; sh = shq; }
    else { b -= nbq; pk = pk_p; bb = bbp; rp = rp_p; colg = col_p; nb = nbp; n = np; sh = shp; }
    int base = bb[b];
    int next = (b + 1 < nb) ? bb[b + 1] : E;
    int cnt = next - base;
    int dlo = b << sh;
    int dn  = min(1 << sh, n - dlo);
    unsigned mask = (1u << sh) - 1;

    __shared__ int deg[DNMAX];
    __shared__ int cur[DNMAX];
    __shared__ int wsum[4];
    int tid = threadIdx.x, lane = tid & 63, wid = tid >> 6;

    for (int i = tid; i < dn; i += 256) deg[i] = 0;
    __syncthreads();
    for (int i = tid; i < cnt; i += 256)
        atomicAdd(&deg[pk[base + i] & mask], 1);
    __syncthreads();

    int t2 = tid * 2;
    int d0 = (t2 < dn) ? deg[t2] : 0;
    int d1 = (t2 + 1 < dn) ? deg[t2 + 1] : 0;
    int s = d0 + d1;
    int inc = s;
    #pragma unroll
    for (int off = 1; off < 64; off <<= 1) {
        int t = __shfl_up(inc, off, 64);
        if (lane >= off) inc += t;
    }
    if (lane == 63) wsum[wid] = inc;
    __syncthreads();
    int wpre = 0;
    for (int w2 = 0; w2 < wid; ++w2) wpre += wsum[w2];
    int ex = wpre + inc - s;
    if (t2 < dn)     { cur[t2] = ex;           rp[dlo + t2] = base + ex; }
    if (t2 + 1 < dn) { cur[t2 + 1] = ex + d0;  rp[dlo + t2 + 1] = base + ex + d0; }
    __syncthreads();

    for (int i = tid; i < cnt; i += 256) {
        unsigned v = pk[base + i];
        int off = atomicAdd(&cur[v & mask], 1);
        colg[base + off] = (int)(v >> sh);
    }
}

// ---------------------------------------------------------------------------
// Tiled gather-mean, bf16 rows, 4 loads in flight (issue/consume split)
// ---------------------------------------------------------------------------
__global__ __launch_bounds__(256) void agg_all(
    const int* __restrict__ rp_q, const int* __restrict__ col_q,
    const unsigned short* __restrict__ srcq, unsigned short* __restrict__ outq, int nq,
    const int* __restrict__ rp_p, const int* __restrict__ col_p,
    const unsigned short* __restrict__ srcp, unsigned short* __restrict__ outp, int np,
    int ntq) {
    __shared__ int rps[GT + 1];
    __shared__ int cols[GCAP];

    int blk = blockIdx.x;
    const int* rp; const int* col; const unsigned short* src; unsigned short* out; int n, d0;
    if (blk < ntq) { rp = rp_q; col = col_q; src = srcq; out = outq; n = nq; d0 = blk * GT; }
    else { rp = rp_p; col = col_p; src = srcp; out = outp; n = np; d0 = (blk - ntq) * GT; }

    int tid = threadIdx.x;
    int nrow = min(GT, n - d0);
    if (tid <= nrow) rps[tid] = rp[d0 + tid];
    __syncthreads();
    int beg0 = rps[0];
    int cnt = rps[nrow] - beg0;
    bool useLds = cnt <= GCAP;
    if (useLds)
        for (int i = tid; i < cnt; i += 256) cols[i] = col[beg0 + i];
    __syncthreads();

    int wid = tid >> 6, lane = tid & 63;
    int sub = lane >> 4;
    int ch  = lane & 15;

    for (int r = wid; r < nrow; r += 4) {
        int beg = rps[r], end = rps[r + 1];
        float a0 = 0.f, a1 = 0.f, a2 = 0.f, a3 = 0.f;
        float a4 = 0.f, a5 = 0.f, a6 = 0.f, a7 = 0.f;
        for (int i = beg; i < end; i += 16) {
            uint4 v[4]; bool act[4];
            #pragma unroll
            for (int h2 = 0; h2 < 4; ++h2) {
                int j = i + h2 * 4 + sub;
                act[h2] = j < end;
                if (act[h2]) {
                    int s = useLds ? cols[j - beg0] : col[j];
                    v[h2] = *(const uint4*)(src + (size_t)s * D + ch * 8);
                }
            }
            #pragma unroll
            for (int h2 = 0; h2 < 4; ++h2) {
                if (act[h2]) {
                    union { unsigned u; float f; } t;
                    t.u = v[h2].x << 16;         a0 += t.f;
                    t.u = v[h2].x & 0xffff0000u; a1 += t.f;
                    t.u = v[h2].y << 16;         a2 += t.f;
                    t.u = v[h2].y & 0xffff0000u; a3 += t.f;
                    t.u = v[h2].z << 16;         a4 += t.f;
                    t.u = v[h2].z & 0xffff0000u; a5 += t.f;
                    t.u = v[h2].w << 16;         a6 += t.f;
                    t.u = v[h2].w & 0xffff0000u; a7 += t.f;
                }
            }
        }
        #pragma unroll
        for (int off = 16; off <= 32; off <<= 1) {
            a0 += __shfl_xor(a0, off); a1 += __shfl_xor(a1, off);
            a2 += __shfl_xor(a2, off); a3 += __shfl_xor(a3, off);
            a4 += __shfl_xor(a4, off); a5 += __shfl_xor(a5, off);
            a6 += __shfl_xor(a6, off); a7 += __shfl_xor(a7, off);
        }
        int deg = end - beg;
        float inv = (deg > 0) ? 1.0f / (float)deg : 0.f;
        if (sub == 0) {
            uint4 o;
            o.x = (unsigned)f2bf(a0 * inv) | ((unsigned)f2bf(a1 * inv) << 16);
            o.y = (unsigned)f2bf(a2 * inv) | ((unsigned)f2bf(a3 * inv) << 16);
            o.z = (unsigned)f2bf(a4 * inv) | ((unsigned)f2bf(a5 * inv) << 16);
            o.w = (unsigned)f2bf(a6 * inv) | ((unsigned)f2bf(a7 * inv) << 16);
            *(uint4*)(out + (size_t)(d0 + r) * D + ch * 8) = o;
        }
    }
}

// ---------------------------------------------------------------------------
// MFMA dual GEMM body (all-bf16 A, hi/lo split W, 2 MFMAs/k-step)
// WF32: write f32 out. WHB: write bf16 hb. (L0: hb only — f32 store is dead,
// layer-1 overwrites out entirely and consumes only hb.)
// ---------------------------------------------------------------------------
struct GemmSide {
    const unsigned short* A1;
    const unsigned short* A2;
    const unsigned short* Wt1;
    const unsigned short* Wt2;
    const float* bias;
    float* out;
    unsigned short* hb;
    int n;
};

template <bool RELU, bool WF32, bool WHB>
__device__ __forceinline__ void gemm_body(const GemmSide& S, int bidx) {
    __shared__ unsigned short As[128][PAD];
    __shared__ unsigned short Ws_hi[128][PAD];
    __shared__ unsigned short Ws_lo[128][PAD];

    const int tid  = threadIdx.x;
    const int lane = tid & 63;
    const int w    = tid >> 6;
    const int m0   = bidx * 128;
    const int n    = S.n;

    f32x4 acc[2][8];
    #pragma unroll
    for (int i = 0; i < 2; ++i)
        #pragma unroll
        for (int j = 0; j < 8; ++j) acc[i][j] = (f32x4)0.f;

    const int srow  = tid >> 1;
    const int skoff = (tid & 1) * 16;

    for (int ks = 0; ks < 8; ++ks) {
        const int half = ks >> 2;
        const int kb   = (ks & 3) * 32;
        const unsigned short* A  = half ? S.A2 : S.A1;
        const unsigned short* Wt = half ? S.Wt2 : S.Wt1;

        {
            int grow = m0 + srow;
            if (grow >= n) grow = n - 1;
            const uint4* pa = (const uint4*)(A + (size_t)grow * D + kb + skoff);
            ((uint4*)&As[srow][skoff])[0] = pa[0];
            ((uint4*)&As[srow][skoff])[1] = pa[1];
        }
        {
            const uint4* ph = (const uint4*)(Wt + (size_t)srow * D + kb + skoff);
            ((uint4*)&Ws_hi[srow][skoff])[0] = ph[0];
            ((uint4*)&Ws_hi[srow][skoff])[1] = ph[1];
            const uint4* pl = (const uint4*)(Wt + 16384 + (size_t)srow * D + kb + skoff);
            ((uint4*)&Ws_lo[srow][skoff])[0] = pl[0];
            ((uint4*)&Ws_lo[srow][skoff])[1] = pl[1];
        }
        __syncthreads();

        const int r0 = w * 32;
        const int k8 = (lane >> 4) * 8;
        const int li = lane & 15;

        short8 ah[2];
        #pragma unroll
        for (int m = 0; m < 2; ++m)
            ah[m] = *(const short8*)&As[r0 + m * 16 + li][k8];
        #pragma unroll
        for (int nb = 0; nb < 8; ++nb) {
            int cc = nb * 16 + li;
            short8 bh = *(const short8*)&Ws_hi[cc][k8];
            short8 bl = *(const short8*)&Ws_lo[cc][k8];
            #pragma unroll
            for (int m = 0; m < 2; ++m) {
                acc[m][nb] = __builtin_amdgcn_mfma_f32_16x16x32_bf16(ah[m], bh, acc[m][nb], 0, 0, 0);
                acc[m][nb] = __builtin_amdgcn_mfma_f32_16x16x32_bf16(ah[m], bl, acc[m][nb], 0, 0, 0);
            }
        }
        __syncthreads();
    }

    const int li = lane & 15;
    const int rq = (lane >> 4) * 4;
    float bv[8];
    #pragma unroll
    for (int nb = 0; nb < 8; ++nb) bv[nb] = S.bias[nb * 16 + li];

    #pragma unroll
    for (int m = 0; m < 2; ++m) {
        #pragma unroll
        for (int nb = 0; nb < 8; ++nb) {
            #pragma unroll
            for (int r = 0; r < 4; ++r) {
                int R = m0 + w * 32 + m * 16 + rq + r;
                if (R < n) {
                    int C = nb * 16 + li;
                    float v = acc[m][nb][r] + bv[nb];
                    if (RELU) v = fmaxf(v, 0.f);
                    if (WF32) S.out[(size_t)R * D + C] = v;
                    if (WHB)  S.hb[(size_t)R * D + C] = f2bf(v);
                }
            }
        }
    }
}

template <bool RELU, bool WF32, bool WHB>
__global__ __launch_bounds__(256) void gemm_both(GemmSide Sq, GemmSide Sp, int mq) {
    if ((int)blockIdx.x < mq) gemm_body<RELU, WF32, WHB>(Sq, blockIdx.x);
    else                      gemm_body<RELU, WF32, WHB>(Sp, blockIdx.x - mq);
}

// ---------------------------------------------------------------------------
extern "C" void kernel_launch(void* const* d_in, const int* in_sizes, int n_in,
                              void* d_out, int out_size, void* d_ws, size_t ws_size,
                              hipStream_t stream) {
    const float* x_p = (const float*)d_in[0];
    const float* x_q = (const float*)d_in[1];
    const int* src_pv = (const int*)d_in[2];
    const int* dst_pv = (const int*)d_in[3];
    const int* src_vp = (const int*)d_in[4];
    const int* dst_vp = (const int*)d_in[5];
    const float* Wl_pv0 = (const float*)d_in[6];
    const float* Wr_pv0 = (const float*)d_in[7];
    const float* b_pv0  = (const float*)d_in[8];
    const float* Wl_vp0 = (const float*)d_in[9];
    const float* Wr_vp0 = (const float*)d_in[10];
    const float* b_vp0  = (const float*)d_in[11];
    const float* Wl_pv1 = (const float*)d_in[12];
    const float* Wr_pv1 = (const float*)d_in[13];
    const float* b_pv1  = (const float*)d_in[14];
    const float* Wl_vp1 = (const float*)d_in[15];
    const float* Wr_vp1 = (const float*)d_in[16];
    const float* b_vp1  = (const float*)d_in[17];

    const int NP = in_sizes[0] / D;
    const int NQ = in_sizes[1] / D;
    const int E  = in_sizes[2];

    float* out_p = (float*)d_out;
    float* out_q = out_p + (size_t)NP * D;

    int shq = 6; while ((((NQ - 1) >> shq) + 1) > NBT) ++shq;
    int shp = 6; while ((((NP - 1) >> shp) + 1) > NBT) ++shp;
    int nbq = ((NQ - 1) >> shq) + 1;
    int nbp = ((NP - 1) >> shp) + 1;

    // workspace layout
    char* ws = (char*)d_ws;
    int* rp_q  = (int*)ws;
    int* rp_p  = rp_q + (NQ + 1);
    int* col_q = rp_p + (NP + 1);
    int* col_p = col_q + E;
    int* bq    = col_p + E;
    int* bp    = bq + NBT;
    int* curq  = bp + NBT;
    int* curp  = curq + NBT;
    size_t int_bytes = ((size_t)(NQ + 1) + (NP + 1) + 2 * (size_t)E + 4 * NBT) * sizeof(int);
    int_bytes = (int_bytes + 511) & ~(size_t)511;
    unsigned short* wt = (unsigned short*)(ws + int_bytes);
    size_t wt_bytes = ((size_t)8 * 32768 * sizeof(unsigned short) + 511) & ~(size_t)511;
    unsigned short* xb_p = (unsigned short*)(ws + int_bytes + wt_bytes);
    unsigned short* xb_q = xb_p + (size_t)NP * D;
    unsigned short* hb_p = xb_p;
    unsigned short* hb_q = xb_q;
    unsigned short* aggb_q = xb_q + (size_t)NQ * D;
    unsigned short* aggb_p = aggb_q + (size_t)NQ * D;
    unsigned* pk_q = (unsigned*)aggb_q;   // alias (dead before first agg write)
    unsigned* pk_p = pk_q + E;

    // --- prep + hist (bq/bp zeroed first) ---
    hipMemsetAsync(bq, 0, 2 * NBT * sizeof(int), stream);
    prep_hist<<<320 + 2048, 256, 0, stream>>>(Wl_pv0, Wr_pv0, Wl_vp0, Wr_vp0,
                                              Wl_pv1, Wr_pv1, Wl_vp1, Wr_vp1, wt,
                                              dst_pv, dst_vp, E, shq, shp, bq, bp,
                                              x_p, xb_p, NP * D / 4, x_q, xb_q, NQ * D / 4);

    // --- CSR build ---
    bscan<<<1, 128, 0, stream>>>(bq, nbq, bp, nbp, curq, curp, rp_q, NQ, rp_p, NP, E);
    bscatter<<<512, 256, 0, stream>>>(src_pv, dst_pv, src_vp, dst_vp, E,
                                      curq, shq, curp, shp, pk_q, pk_p);
    bcsr<<<nbq + nbp, 256, 0, stream>>>(pk_q, pk_p, bq, nbq, bp, nbp,
                                        rp_q, NQ, shq, rp_p, NP, shp, col_q, col_p, E);

    int ntq = (NQ + GT - 1) / GT, ntp = (NP + GT - 1) / GT;
    int mq = (NQ + 127) / 128, mp = (NP + 127) / 128;

    GemmSide Sq0 = { aggb_q, xb_q, wt + 0 * 32768, wt + 1 * 32768, b_pv0, out_q, hb_q, NQ };
    GemmSide Sp0 = { aggb_p, xb_p, wt + 2 * 32768, wt + 3 * 32768, b_vp0, out_p, hb_p, NP };
    GemmSide Sq1 = { aggb_q, hb_q, wt + 4 * 32768, wt + 5 * 32768, b_pv1, out_q, nullptr, NQ };
    GemmSide Sp1 = { aggb_p, hb_p, wt + 6 * 32768, wt + 7 * 32768, b_vp1, out_p, nullptr, NP };

    // --- layer 0 (f32 out stores are dead; write bf16 h1 only) ---
    agg_all<<<ntq + ntp, 256, 0, stream>>>(rp_q, col_q, xb_p, aggb_q, NQ,
                                           rp_p, col_p, xb_q, aggb_p, NP, ntq);
    gemm_both<true, false, true><<<mq + mp, 256, 0, stream>>>(Sq0, Sp0, mq);

    // --- layer 1 ---
    agg_all<<<ntq + ntp, 256, 0, stream>>>(rp_q, col_q, hb_p, aggb_q, NQ,
                                           rp_p, col_p, hb_q, aggb_p, NP, ntq);
    gemm_both<false, true, false><<<mq + mp, 256, 0, stream>>>(Sq1, Sp1, mq);
}